// Round 5
// baseline (205.662 us; speedup 1.0000x reference)
//
#include <hip/hip_runtime.h>

#define BB 16384
#define NN 20
#define DD 64
#define IMGK 2048

using bf16x8 = __attribute__((ext_vector_type(8))) short;
using f32x4  = __attribute__((ext_vector_type(4))) float;

__device__ __forceinline__ float waveReduceSum(float x) {
#pragma unroll
  for (int off = 32; off > 0; off >>= 1) x += __shfl_xor(x, off, 64);
  return x;
}

__device__ __forceinline__ float fast_tanh(float x) {
  float e = __expf(2.f * x);
  return 1.f - __fdividef(2.f, e + 1.f);
}

__device__ __forceinline__ short f2bf(float f) {
  union { float f; unsigned u; } c; c.f = f;
  unsigned r = c.u + 0x7fffu + ((c.u >> 16) & 1u);
  return (short)(r >> 16);
}
__device__ __forceinline__ float bf2f(short s) {
  union { unsigned u; float f; } c; c.u = ((unsigned)(unsigned short)s) << 16;
  return c.f;
}

__device__ __forceinline__ unsigned cvt_pk_bf16(float lo, float hi) {
  unsigned r;
  asm("v_cvt_pk_bf16_f32 %0, %1, %2" : "=v"(r) : "v"(lo), "v"(hi));
  return r;
}

__device__ __forceinline__ bf16x8 pack8(float4 a, float4 b) {
  union { unsigned u[4]; bf16x8 v; } r;
  r.u[0] = cvt_pk_bf16(a.x, a.y);
  r.u[1] = cvt_pk_bf16(a.z, a.w);
  r.u[2] = cvt_pk_bf16(b.x, b.y);
  r.u[3] = cvt_pk_bf16(b.z, b.w);
  return r.v;
}

// truncation pack: top 16 bits of (a,b) -> one u32. Pure VALU, scheduler-friendly.
__device__ __forceinline__ unsigned pack_hi(float a, float b) {
  unsigned ua = __float_as_uint(a), ub = __float_as_uint(b);
  return (ub & 0xffff0000u) | (ua >> 16);
}
__device__ __forceinline__ float trunc_bf(float a) {
  return __uint_as_float(__float_as_uint(a) & 0xffff0000u);
}

// ---------------- prep: transpose + split weights to bf16 ----------------
__global__ __launch_bounds__(256)
void prep_kernel(const float* __restrict__ Wimg, const float* __restrict__ W1,
                 short* __restrict__ Wt_hi, short* __restrict__ Wt_lo,
                 short* __restrict__ W1t) {
  int i = blockIdx.x * 256 + threadIdx.x;
  if (i < IMGK * 64) {
    int k = i >> 6, n = i & 63;
    float f = Wimg[i];
    short h = f2bf(f);
    Wt_hi[n * IMGK + k] = h;
    Wt_lo[n * IMGK + k] = f2bf(f - bf2f(h));
  } else if (i < IMGK * 64 + 64 * 64) {
    int j = i - IMGK * 64;
    int k = j >> 6, n = j & 63;
    W1t[n * 64 + k] = f2bf(W1[j]);
  }
}

// ---------------- Kernel A: img GEMM, hand-pipelined (A one iter ahead) ----------------
// grid 1024 x 4 waves; wave: 16 rows x K=512 (16 steps of 32). No inline asm in chain.
__global__ __launch_bounds__(256, 4)
void img_gemm_mfma(const float* __restrict__ img_in,
                   const short* __restrict__ Wt_hi,
                   const short* __restrict__ Wt_lo,
                   const float* __restrict__ Wb,
                   const float* __restrict__ bimg,
                   float* __restrict__ img_out) {
  __shared__ float part[4][16][64];
  const int t = threadIdx.x;
  const int wave = t >> 6, lane = t & 63;
  const int r0 = blockIdx.x * 16;
  const int lr = lane & 15, lk = lane >> 4;
  const int kb = wave * 512;
  f32x4 aHH[4], aER[4];
#pragma unroll
  for (int tt = 0; tt < 4; ++tt) {
    aHH[tt] = (f32x4){0.f, 0.f, 0.f, 0.f};
    aER[tt] = (f32x4){0.f, 0.f, 0.f, 0.f};
  }
  const float* arow = img_in + (size_t)(r0 + lr) * IMGK + kb + lk * 8;
  const short* wh0 = Wt_hi + (size_t)lr * IMGK + kb + lk * 8;
  const short* wl0 = Wt_lo + (size_t)lr * IMGK + kb + lk * 8;

  // prologue: A loads for iter 0
  float4 va = reinterpret_cast<const float4*>(arow)[0];
  float4 vb = reinterpret_cast<const float4*>(arow)[1];

#pragma unroll 2
  for (int ks = 0; ks < 16; ++ks) {
    // issue next iteration's A loads first (HBM stream — hide under this iter's work)
    float4 na, nb;
    if (ks < 15) {
      const float4* apn = reinterpret_cast<const float4*>(arow + (ks + 1) * 32);
      na = apn[0];
      nb = apn[1];
    }
    // W fragments for current iter (L2-resident)
    bf16x8 wh[4], wl[4];
#pragma unroll
    for (int tt = 0; tt < 4; ++tt) {
      wh[tt] = *reinterpret_cast<const bf16x8*>(wh0 + (size_t)tt * 16 * IMGK + ks * 32);
      wl[tt] = *reinterpret_cast<const bf16x8*>(wl0 + (size_t)tt * 16 * IMGK + ks * 32);
    }
    // truncation split of current A (pure VALU)
    union { unsigned u[4]; bf16x8 v; } hi, lo;
    hi.u[0] = pack_hi(va.x, va.y);
    hi.u[1] = pack_hi(va.z, va.w);
    hi.u[2] = pack_hi(vb.x, vb.y);
    hi.u[3] = pack_hi(vb.z, vb.w);
    float4 ra, rb;
    ra.x = va.x - trunc_bf(va.x);
    ra.y = va.y - trunc_bf(va.y);
    ra.z = va.z - trunc_bf(va.z);
    ra.w = va.w - trunc_bf(va.w);
    rb.x = vb.x - trunc_bf(vb.x);
    rb.y = vb.y - trunc_bf(vb.y);
    rb.z = vb.z - trunc_bf(vb.z);
    rb.w = vb.w - trunc_bf(vb.w);
    lo.u[0] = pack_hi(ra.x, ra.y);
    lo.u[1] = pack_hi(ra.z, ra.w);
    lo.u[2] = pack_hi(rb.x, rb.y);
    lo.u[3] = pack_hi(rb.z, rb.w);
#pragma unroll
    for (int tt = 0; tt < 4; ++tt) {
      aHH[tt] = __builtin_amdgcn_mfma_f32_16x16x32_bf16(hi.v, wh[tt], aHH[tt], 0, 0, 0);
      aER[tt] = __builtin_amdgcn_mfma_f32_16x16x32_bf16(hi.v, wl[tt], aER[tt], 0, 0, 0);
      aER[tt] = __builtin_amdgcn_mfma_f32_16x16x32_bf16(lo.v, wh[tt], aER[tt], 0, 0, 0);
    }
    va = na;
    vb = nb;
  }
#pragma unroll
  for (int tt = 0; tt < 4; ++tt)
#pragma unroll
    for (int r = 0; r < 4; ++r)
      part[wave][4 * lk + r][16 * tt + lr] = aHH[tt][r] + aER[tt][r];
  __syncthreads();
  const int row = t >> 4, col = (t & 15) * 4;
  float4 s0 = *reinterpret_cast<const float4*>(&part[0][row][col]);
  float4 s1 = *reinterpret_cast<const float4*>(&part[1][row][col]);
  float4 s2 = *reinterpret_cast<const float4*>(&part[2][row][col]);
  float4 s3 = *reinterpret_cast<const float4*>(&part[3][row][col]);
  float4 wb = *reinterpret_cast<const float4*>(&Wb[col]);
  float4 bi = *reinterpret_cast<const float4*>(&bimg[col]);
  float4 o;
  o.x = s0.x + s1.x + s2.x + s3.x + wb.x + bi.x;
  o.y = s0.y + s1.y + s2.y + s3.y + wb.y + bi.y;
  o.z = s0.z + s1.z + s2.z + s3.z + wb.z + bi.z;
  o.w = s0.w + s1.w + s2.w + s3.w + wb.w + bi.w;
  *reinterpret_cast<float4*>(&img_out[(size_t)(r0 + row) * 64 + col]) = o;
}

// ---------------- Kernel A2: base[b][w] = [ue|img] @ Wi[64:192] + Wib + bai ----------------
__global__ __launch_bounds__(256, 4)
void base_kernel(const int* __restrict__ user_input,
                 const float* __restrict__ user_emb,
                 const float* __restrict__ ws_img,
                 const float* __restrict__ Wi,    // [192][64]
                 const float* __restrict__ Wib,   // [64]
                 const float* __restrict__ bai,   // [64]
                 float* __restrict__ ws_base) {
  __shared__ float W_s[128 * 64];
  __shared__ float x_s[4][128];
  const int t = threadIdx.x;
  for (int i = t; i < 128 * 64 / 4; i += 256)
    reinterpret_cast<float4*>(W_s)[i] =
        reinterpret_cast<const float4*>(Wi + 64 * 64)[i];
  __syncthreads();
  const int wave = t >> 6, lane = t & 63;
  const float bb = Wib[lane] + bai[lane];
  const int b0 = blockIdx.x * 32 + wave * 8;
#pragma unroll 1
  for (int bi = 0; bi < 8; ++bi) {
    const int b = b0 + bi;
    const int u = user_input[b];
    x_s[wave][lane] = user_emb[(size_t)u * 64 + lane];
    x_s[wave][64 + lane] = ws_img[(size_t)b * 64 + lane];
    asm volatile("s_waitcnt lgkmcnt(0)" ::: "memory");
    float acc = bb;
    const float4* x4 = reinterpret_cast<const float4*>(&x_s[wave][0]);
#pragma unroll
    for (int d0 = 0; d0 < 32; ++d0) {
      float4 q = x4[d0];
      int d = d0 * 4;
      acc = fmaf(q.x, W_s[(d + 0) * 64 + lane],
            fmaf(q.y, W_s[(d + 1) * 64 + lane],
            fmaf(q.z, W_s[(d + 2) * 64 + lane],
            fmaf(q.w, W_s[(d + 3) * 64 + lane], acc))));
    }
    ws_base[(size_t)b * 64 + lane] = acc;
    asm volatile("s_waitcnt lgkmcnt(0)" ::: "memory");
  }
}

// ---------------- Kernel B1: ingredient attention via MFMA ----------------
__global__ __launch_bounds__(256, 2)
void ingre_att_mfma(const int* __restrict__ ingre_input,
                    const int* __restrict__ ingre_num,
                    const float* __restrict__ ingre_emb,
                    const short* __restrict__ W1t,   // [64][64] bf16
                    const float* __restrict__ v,
                    const float* __restrict__ ws_base,
                    float* __restrict__ ws_ia) {
  __shared__ float sc_lds[4][32];
  const int t = threadIdx.x, wave = t >> 6, lane = t & 63;
  const int lr = lane & 15, lk = lane >> 4;
  bf16x8 wf[4][2];
#pragma unroll
  for (int wt = 0; wt < 4; ++wt)
#pragma unroll
    for (int ks = 0; ks < 2; ++ks)
      wf[wt][ks] = *reinterpret_cast<const bf16x8*>(
          W1t + (16 * wt + lr) * 64 + ks * 32 + lk * 8);
  float vv[4];
#pragma unroll
  for (int wt = 0; wt < 4; ++wt) vv[wt] = v[16 * wt + lr];
  const int b0 = blockIdx.x * 32 + wave * 8;
#pragma unroll 1
  for (int bi = 0; bi < 8; ++bi) {
    const int b = b0 + bi;
    const int n1 = 16 + lr;
    const int gi0 = ingre_input[b * NN + lr];
    const int gi1 = ingre_input[b * NN + ((n1 < NN) ? n1 : 0)];
    bf16x8 a0[2], a1[2];
#pragma unroll
    for (int ks = 0; ks < 2; ++ks) {
      const float4* p0 = reinterpret_cast<const float4*>(
          ingre_emb + (size_t)gi0 * 64 + ks * 32 + lk * 8);
      a0[ks] = pack8(p0[0], p0[1]);
      const float4* p1 = reinterpret_cast<const float4*>(
          ingre_emb + (size_t)gi1 * 64 + ks * 32 + lk * 8);
      a1[ks] = pack8(p1[0], p1[1]);
    }
    f32x4 acc[2][4];
#pragma unroll
    for (int nt = 0; nt < 2; ++nt)
#pragma unroll
      for (int wt = 0; wt < 4; ++wt) acc[nt][wt] = (f32x4){0.f, 0.f, 0.f, 0.f};
#pragma unroll
    for (int ks = 0; ks < 2; ++ks)
#pragma unroll
      for (int wt = 0; wt < 4; ++wt) {
        acc[0][wt] = __builtin_amdgcn_mfma_f32_16x16x32_bf16(a0[ks], wf[wt][ks], acc[0][wt], 0, 0, 0);
        acc[1][wt] = __builtin_amdgcn_mfma_f32_16x16x32_bf16(a1[ks], wf[wt][ks], acc[1][wt], 0, 0, 0);
      }
    float basew[4];
#pragma unroll
    for (int wt = 0; wt < 4; ++wt) basew[wt] = ws_base[(size_t)b * 64 + 16 * wt + lr];
    float sp[2][4];
#pragma unroll
    for (int nt = 0; nt < 2; ++nt)
#pragma unroll
      for (int r = 0; r < 4; ++r) {
        float s = 0.f;
#pragma unroll
        for (int wt = 0; wt < 4; ++wt) {
          float x = acc[nt][wt][r] + basew[wt];
          s = fmaf(fast_tanh(x), vv[wt], s);
        }
        sp[nt][r] = s;
      }
#pragma unroll
    for (int off = 1; off < 16; off <<= 1)
#pragma unroll
      for (int nt = 0; nt < 2; ++nt)
#pragma unroll
        for (int r = 0; r < 4; ++r) sp[nt][r] += __shfl_xor(sp[nt][r], off, 64);
    if (lr == 0) {
#pragma unroll
      for (int r = 0; r < 4; ++r) {
        sc_lds[wave][4 * lk + r] = sp[0][r];
        sc_lds[wave][16 + 4 * lk + r] = sp[1][r];
      }
    }
    asm volatile("s_waitcnt lgkmcnt(0)" ::: "memory");
    float scn[NN];
#pragma unroll
    for (int q = 0; q < 5; ++q) {
      float4 s4 = *reinterpret_cast<const float4*>(&sc_lds[wave][4 * q]);
      scn[4 * q + 0] = s4.x; scn[4 * q + 1] = s4.y;
      scn[4 * q + 2] = s4.z; scn[4 * q + 3] = s4.w;
    }
    asm volatile("s_waitcnt lgkmcnt(0)" ::: "memory");
    const int num = ingre_num[b];
    float m = -3e38f;
#pragma unroll
    for (int n = 0; n < NN; ++n) {
      scn[n] = (n < num) ? scn[n] : -1e12f;
      m = fmaxf(m, scn[n]);
    }
    float ev[NN], ssum = 0.f;
#pragma unroll
    for (int n = 0; n < NN; ++n) {
      ev[n] = __expf(scn[n] - m);
      ssum += ev[n];
    }
    const float inv = __fdividef(1.f, ssum);
    float qv[NN];
#pragma unroll
    for (int n = 0; n < NN; ++n) {
      const int gi = ingre_input[b * NN + n];
      qv[n] = ingre_emb[(size_t)gi * 64 + lane];
    }
    float ia = 0.f;
#pragma unroll
    for (int n = 0; n < NN; ++n) ia = fmaf(ev[n], qv[n], ia);
    ws_ia[(size_t)b * 64 + lane] = ia * inv;
  }
}

// ---------------- Kernel B2: component scores -> flat [3B] ----------------
__global__ __launch_bounds__(256, 4)
void com_score_kernel(const int* __restrict__ user_input,
                      const int* __restrict__ item_input,
                      const float* __restrict__ user_emb,
                      const float* __restrict__ item_emb,
                      const float* __restrict__ Wc,    // [128][64]
                      const float* __restrict__ Wcb,   // [64]
                      const float* __restrict__ bat,   // [64]
                      const float* __restrict__ vc,    // [64]
                      const float* __restrict__ ws_img,
                      const float* __restrict__ ws_ia,
                      float* __restrict__ ws_flat) {
  __shared__ float Wclds[128 * 64];
  __shared__ float x_s[4][4][64];
  const int t = threadIdx.x;
  for (int i = t; i < 128 * 64 / 4; i += 256)
    reinterpret_cast<float4*>(Wclds)[i] = reinterpret_cast<const float4*>(Wc)[i];
  __syncthreads();
  const int wave = t >> 6, lane = t & 63;
  const float bb = Wcb[lane] + bat[lane];
  const float vcl = vc[lane];
  const int b0 = blockIdx.x * 32 + wave * 8;
#pragma unroll 1
  for (int bi = 0; bi < 8; ++bi) {
    const int b = b0 + bi;
    const int u = user_input[b];
    const int it = item_input[b];
    x_s[wave][0][lane] = user_emb[(size_t)u * 64 + lane];
    x_s[wave][1][lane] = item_emb[(size_t)it * 64 + lane];
    x_s[wave][2][lane] = ws_ia[(size_t)b * 64 + lane];
    x_s[wave][3][lane] = ws_img[(size_t)b * 64 + lane];
    asm volatile("s_waitcnt lgkmcnt(0)" ::: "memory");
    const float4* u4 = reinterpret_cast<const float4*>(&x_s[wave][0][0]);
    float up = 0.f;
#pragma unroll
    for (int d0 = 0; d0 < 16; ++d0) {
      float4 q = u4[d0];
      int d = d0 * 4;
      up = fmaf(q.x, Wclds[(d + 0) * 64 + lane],
           fmaf(q.y, Wclds[(d + 1) * 64 + lane],
           fmaf(q.z, Wclds[(d + 2) * 64 + lane],
           fmaf(q.w, Wclds[(d + 3) * 64 + lane], up))));
    }
    float sc[3];
#pragma unroll
    for (int c = 0; c < 3; ++c) {
      const float4* y4 = reinterpret_cast<const float4*>(&x_s[wave][1 + c][0]);
      float s = bb + up;
#pragma unroll
      for (int d0 = 0; d0 < 16; ++d0) {
        float4 q = y4[d0];
        int d = 64 + d0 * 4;
        s = fmaf(q.x, Wclds[(d + 0) * 64 + lane],
            fmaf(q.y, Wclds[(d + 1) * 64 + lane],
            fmaf(q.z, Wclds[(d + 2) * 64 + lane],
            fmaf(q.w, Wclds[(d + 3) * 64 + lane], s))));
      }
      sc[c] = waveReduceSum(fast_tanh(s) * vcl);
    }
    if (lane == 0) {
      ws_flat[b] = sc[0];
      ws_flat[BB + b] = sc[1];
      ws_flat[2 * BB + b] = sc[2];
    }
    asm volatile("s_waitcnt lgkmcnt(0)" ::: "memory");
  }
}

// ---------------- Kernel C: head. scores[i][j] = flat[3i+j] ----------------
__global__ __launch_bounds__(256, 3)
void head_kernel(const int* __restrict__ user_input,
                 const int* __restrict__ item_input,
                 const float* __restrict__ user_emb,
                 const float* __restrict__ item_emb,
                 const float* __restrict__ Wcat,   // [192][64]
                 const float* __restrict__ Wcatb,  // [64]
                 const float* __restrict__ bcat,   // [64]
                 const float* __restrict__ hw,     // [64]
                 const float* __restrict__ hb,     // [1]
                 const float* __restrict__ ws_img,
                 const float* __restrict__ ws_ia,
                 const float* __restrict__ ws_flat,
                 float* __restrict__ out) {
  __shared__ float Wlds[192 * 64];
  __shared__ float ue_s[4][64];
  __shared__ float itt_s[4][64];
  const int t = threadIdx.x;
  for (int i = t; i < 192 * 64 / 4; i += 256)
    reinterpret_cast<float4*>(Wlds)[i] = reinterpret_cast<const float4*>(Wcat)[i];
  __syncthreads();
  const int wave = t >> 6, lane = t & 63;
  const float bb = Wcatb[lane] + bcat[lane];
  const float hwl = hw[lane];
  const float hbv = hb[0];
  const int b0 = blockIdx.x * 32 + wave * 8;
#pragma unroll 1
  for (int bi = 0; bi < 8; ++bi) {
    const int b = b0 + bi;
    const float s0 = ws_flat[3 * b + 0];
    const float s1 = ws_flat[3 * b + 1];
    const float s2 = ws_flat[3 * b + 2];
    const float m = fmaxf(s0, fmaxf(s1, s2));
    const float e0 = __expf(s0 - m), e1 = __expf(s1 - m), e2 = __expf(s2 - m);
    const float inv = 1.0f / (e0 + e1 + e2);
    const int u = user_input[b];
    const int it = item_input[b];
    const float uev = user_emb[(size_t)u * 64 + lane];
    const float itt = (e0 * item_emb[(size_t)it * 64 + lane] +
                       e1 * ws_ia[(size_t)b * 64 + lane] +
                       e2 * ws_img[(size_t)b * 64 + lane]) * inv;
    ue_s[wave][lane] = uev;
    itt_s[wave][lane] = itt;
    asm volatile("s_waitcnt lgkmcnt(0)" ::: "memory");
    const float4* u4 = reinterpret_cast<const float4*>(&ue_s[wave][0]);
    const float4* i4 = reinterpret_cast<const float4*>(&itt_s[wave][0]);
    float h = bb;
#pragma unroll
    for (int d0 = 0; d0 < 16; ++d0) {
      float4 uu = u4[d0];
      float4 ii = i4[d0];
      int d = d0 * 4;
      h = fmaf(uu.x, Wlds[(d + 0) * 64 + lane], h);
      h = fmaf(ii.x, Wlds[(64 + d + 0) * 64 + lane], h);
      h = fmaf(uu.x * ii.x, Wlds[(128 + d + 0) * 64 + lane], h);
      h = fmaf(uu.y, Wlds[(d + 1) * 64 + lane], h);
      h = fmaf(ii.y, Wlds[(64 + d + 1) * 64 + lane], h);
      h = fmaf(uu.y * ii.y, Wlds[(128 + d + 1) * 64 + lane], h);
      h = fmaf(uu.z, Wlds[(d + 2) * 64 + lane], h);
      h = fmaf(ii.z, Wlds[(64 + d + 2) * 64 + lane], h);
      h = fmaf(uu.z * ii.z, Wlds[(128 + d + 2) * 64 + lane], h);
      h = fmaf(uu.w, Wlds[(d + 3) * 64 + lane], h);
      h = fmaf(ii.w, Wlds[(64 + d + 3) * 64 + lane], h);
      h = fmaf(uu.w * ii.w, Wlds[(128 + d + 3) * 64 + lane], h);
    }
    h = fmaxf(h, 0.f) * hwl;
    float o = waveReduceSum(h);
    if (lane == 0) out[b] = o + hbv;
    asm volatile("s_waitcnt lgkmcnt(0)" ::: "memory");
  }
}

extern "C" void kernel_launch(void* const* d_in, const int* in_sizes, int n_in,
                              void* d_out, int out_size, void* d_ws, size_t ws_size,
                              hipStream_t stream) {
  (void)in_sizes; (void)n_in; (void)out_size; (void)ws_size;
  const int* user_input = (const int*)d_in[0];
  const int* item_input = (const int*)d_in[1];
  const int* ingre_input = (const int*)d_in[2];
  const float* image_input = (const float*)d_in[3];
  const int* ingre_num = (const int*)d_in[4];
  const float* user_emb = (const float*)d_in[5];
  const float* item_emb = (const float*)d_in[6];
  const float* ingre_emb = (const float*)d_in[7];
  const float* W_image_w = (const float*)d_in[8];
  const float* W_image_b = (const float*)d_in[9];
  const float* b_image = (const float*)d_in[10];
  const float* W_concat_w = (const float*)d_in[11];
  const float* W_concat_b = (const float*)d_in[12];
  const float* b_concat = (const float*)d_in[13];
  const float* h_w = (const float*)d_in[14];
  const float* h_b = (const float*)d_in[15];
  const float* W_att_ingre_w = (const float*)d_in[16];
  const float* W_att_ingre_b = (const float*)d_in[17];
  const float* b_att_ingre = (const float*)d_in[18];
  const float* v = (const float*)d_in[19];
  const float* W_att_com_w = (const float*)d_in[20];
  const float* W_att_com_b = (const float*)d_in[21];
  const float* b_att_com = (const float*)d_in[22];
  const float* v_c = (const float*)d_in[23];

  float* ws = (float*)d_ws;
  float* ws_img = ws;                              // [B*64] f32
  float* ws_ia = ws + (size_t)BB * 64;             // [B*64] f32
  float* ws_base = ws + (size_t)2 * BB * 64;       // [B*64] f32
  float* ws_flat = ws + (size_t)3 * BB * 64;       // [3B] f32
  short* Wt_hi = (short*)(ws + (size_t)3 * BB * 64 + 3 * BB);   // [64*2048] bf16
  short* Wt_lo = Wt_hi + (size_t)64 * IMGK;                     // [64*2048] bf16
  short* W1t = Wt_lo + (size_t)64 * IMGK;                       // [64*64] bf16
  float* out = (float*)d_out;

  prep_kernel<<<(IMGK * 64 + 64 * 64 + 255) / 256, 256, 0, stream>>>(
      W_image_w, W_att_ingre_w, Wt_hi, Wt_lo, W1t);
  img_gemm_mfma<<<BB / 16, 256, 0, stream>>>(image_input, Wt_hi, Wt_lo,
                                             W_image_b, b_image, ws_img);
  base_kernel<<<BB / 32, 256, 0, stream>>>(user_input, user_emb, ws_img,
                                           W_att_ingre_w, W_att_ingre_b, b_att_ingre,
                                           ws_base);
  ingre_att_mfma<<<BB / 32, 256, 0, stream>>>(ingre_input, ingre_num, ingre_emb,
                                              W1t, v, ws_base, ws_ia);
  com_score_kernel<<<BB / 32, 256, 0, stream>>>(user_input, item_input, user_emb, item_emb,
                                                W_att_com_w, W_att_com_b, b_att_com, v_c,
                                                ws_img, ws_ia, ws_flat);
  head_kernel<<<BB / 32, 256, 0, stream>>>(user_input, item_input, user_emb, item_emb,
                                           W_concat_w, W_concat_b, b_concat, h_w, h_b,
                                           ws_img, ws_ia, ws_flat, out);
}

// Round 6
// 203.438 us; speedup vs baseline: 1.0109x; 1.0109x over previous
//
#include <hip/hip_runtime.h>

#define BB 16384
#define NN 20
#define DD 64
#define IMGK 2048

using bf16x8 = __attribute__((ext_vector_type(8))) short;
using f32x4  = __attribute__((ext_vector_type(4))) float;

typedef __attribute__((address_space(1))) const unsigned int GUint;
typedef __attribute__((address_space(3))) unsigned int LUint;
__device__ __forceinline__ void gl_lds16(const float* g, float* l) {
  __builtin_amdgcn_global_load_lds((GUint*)g, (LUint*)l, 16, 0, 0);
}

__device__ __forceinline__ float waveReduceSum(float x) {
#pragma unroll
  for (int off = 32; off > 0; off >>= 1) x += __shfl_xor(x, off, 64);
  return x;
}

__device__ __forceinline__ float fast_tanh(float x) {
  float e = __expf(2.f * x);
  return 1.f - __fdividef(2.f, e + 1.f);
}

__device__ __forceinline__ short f2bf(float f) {
  union { float f; unsigned u; } c; c.f = f;
  unsigned r = c.u + 0x7fffu + ((c.u >> 16) & 1u);
  return (short)(r >> 16);
}
__device__ __forceinline__ float bf2f(short s) {
  union { unsigned u; float f; } c; c.u = ((unsigned)(unsigned short)s) << 16;
  return c.f;
}

__device__ __forceinline__ unsigned cvt_pk_bf16(float lo, float hi) {
  unsigned r;
  asm("v_cvt_pk_bf16_f32 %0, %1, %2" : "=v"(r) : "v"(lo), "v"(hi));
  return r;
}

__device__ __forceinline__ bf16x8 pack8(float4 a, float4 b) {
  union { unsigned u[4]; bf16x8 v; } r;
  r.u[0] = cvt_pk_bf16(a.x, a.y);
  r.u[1] = cvt_pk_bf16(a.z, a.w);
  r.u[2] = cvt_pk_bf16(b.x, b.y);
  r.u[3] = cvt_pk_bf16(b.z, b.w);
  return r.v;
}

// truncation pack: top 16 bits of (a,b) -> one u32. Pure VALU.
__device__ __forceinline__ unsigned pack_hi(float a, float b) {
  unsigned ua = __float_as_uint(a), ub = __float_as_uint(b);
  return (ub & 0xffff0000u) | (ua >> 16);
}
__device__ __forceinline__ float trunc_bf(float a) {
  return __uint_as_float(__float_as_uint(a) & 0xffff0000u);
}

// ---------------- prep: transpose + split weights to bf16 ----------------
__global__ __launch_bounds__(256)
void prep_kernel(const float* __restrict__ Wimg, const float* __restrict__ W1,
                 short* __restrict__ Wt_hi, short* __restrict__ Wt_lo,
                 short* __restrict__ W1t) {
  int i = blockIdx.x * 256 + threadIdx.x;
  if (i < IMGK * 64) {
    int k = i >> 6, n = i & 63;
    float f = Wimg[i];
    short h = f2bf(f);
    Wt_hi[n * IMGK + k] = h;
    Wt_lo[n * IMGK + k] = f2bf(f - bf2f(h));
  } else if (i < IMGK * 64 + 64 * 64) {
    int j = i - IMGK * 64;
    int k = j >> 6, n = j & 63;
    W1t[n * 64 + k] = f2bf(W1[j]);
  }
}

// ---------------- Kernel A: img GEMM, global_load_lds double-buffered staging ----------------
// grid 1024 x 4 waves; block = 16 rows; BK=128 f32 chunks; wave w owns k-quarter (32) of each chunk.
__global__ __launch_bounds__(256, 3)
void img_gemm_mfma(const float* __restrict__ img_in,
                   const short* __restrict__ Wt_hi,
                   const short* __restrict__ Wt_lo,
                   const float* __restrict__ Wb,
                   const float* __restrict__ bimg,
                   float* __restrict__ img_out) {
  __shared__ float lds[2][16][128];   // 16 KB staging; aliased by 'part' in epilogue
  const int t = threadIdx.x;
  const int wave = t >> 6, lane = t & 63;
  const int r0 = blockIdx.x * 16;
  const int lr = lane & 15, lk = lane >> 4;

  f32x4 aHH[4], aER[4];
#pragma unroll
  for (int tt = 0; tt < 4; ++tt) {
    aHH[tt] = (f32x4){0.f, 0.f, 0.f, 0.f};
    aER[tt] = (f32x4){0.f, 0.f, 0.f, 0.f};
  }

  // prologue: stage chunk 0 (thread t covers 16B granules j = t and 256+t of the 8KB tile)
#pragma unroll
  for (int i = 0; i < 2; ++i) {
    int j = i * 256 + t;
    gl_lds16(img_in + (size_t)(r0 + (j >> 5)) * IMGK + (j & 31) * 4,
             &lds[0][0][0] + j * 4);
  }
  asm volatile("s_waitcnt vmcnt(0)" ::: "memory");
  __syncthreads();

#pragma unroll 1
  for (int c = 0; c < 16; ++c) {
    const int kk = c * 128 + wave * 32;
    // W fragments for this chunk (L2-resident) — issued BEFORE the stage so the
    // compiler's wait for them is counted (vmcnt(2)), leaving the stage in flight.
    bf16x8 wh[4], wl[4];
#pragma unroll
    for (int tt = 0; tt < 4; ++tt) {
      wh[tt] = *reinterpret_cast<const bf16x8*>(
          Wt_hi + (size_t)(16 * tt + lr) * IMGK + kk + lk * 8);
      wl[tt] = *reinterpret_cast<const bf16x8*>(
          Wt_lo + (size_t)(16 * tt + lr) * IMGK + kk + lk * 8);
    }
    __builtin_amdgcn_sched_barrier(0);
    // stage next chunk into the other buffer (zero-VGPR async; drains at bottom barrier)
    if (c + 1 < 16) {
#pragma unroll
      for (int i = 0; i < 2; ++i) {
        int j = i * 256 + t;
        gl_lds16(img_in + (size_t)(r0 + (j >> 5)) * IMGK + (c + 1) * 128 + (j & 31) * 4,
                 &lds[(c + 1) & 1][0][0] + j * 4);
      }
    }
    // A fragment: row lr, k = wave*32 + lk*8 .. +8 (two b128 LDS reads)
    const float4* ap = reinterpret_cast<const float4*>(&lds[c & 1][lr][wave * 32 + lk * 8]);
    float4 va = ap[0], vb = ap[1];
    union { unsigned u[4]; bf16x8 v; } hi, lo;
    hi.u[0] = pack_hi(va.x, va.y);
    hi.u[1] = pack_hi(va.z, va.w);
    hi.u[2] = pack_hi(vb.x, vb.y);
    hi.u[3] = pack_hi(vb.z, vb.w);
    float4 ra, rb;
    ra.x = va.x - trunc_bf(va.x);
    ra.y = va.y - trunc_bf(va.y);
    ra.z = va.z - trunc_bf(va.z);
    ra.w = va.w - trunc_bf(va.w);
    rb.x = vb.x - trunc_bf(vb.x);
    rb.y = vb.y - trunc_bf(vb.y);
    rb.z = vb.z - trunc_bf(vb.z);
    rb.w = vb.w - trunc_bf(vb.w);
    lo.u[0] = pack_hi(ra.x, ra.y);
    lo.u[1] = pack_hi(ra.z, ra.w);
    lo.u[2] = pack_hi(rb.x, rb.y);
    lo.u[3] = pack_hi(rb.z, rb.w);
#pragma unroll
    for (int tt = 0; tt < 4; ++tt) {
      aHH[tt] = __builtin_amdgcn_mfma_f32_16x16x32_bf16(hi.v, wh[tt], aHH[tt], 0, 0, 0);
      aER[tt] = __builtin_amdgcn_mfma_f32_16x16x32_bf16(hi.v, wl[tt], aER[tt], 0, 0, 0);
      aER[tt] = __builtin_amdgcn_mfma_f32_16x16x32_bf16(lo.v, wh[tt], aER[tt], 0, 0, 0);
    }
    asm volatile("s_waitcnt vmcnt(0)" ::: "memory");
    __syncthreads();
  }

  // epilogue: combine 4 k-quarter partials via LDS (aliases staging buffers — all reads done)
  float (*part)[16][64] = reinterpret_cast<float (*)[16][64]>(&lds[0][0][0]);
#pragma unroll
  for (int tt = 0; tt < 4; ++tt)
#pragma unroll
    for (int r = 0; r < 4; ++r)
      part[wave][4 * lk + r][16 * tt + lr] = aHH[tt][r] + aER[tt][r];
  __syncthreads();
  const int row = t >> 4, col = (t & 15) * 4;
  float4 s0 = *reinterpret_cast<const float4*>(&part[0][row][col]);
  float4 s1 = *reinterpret_cast<const float4*>(&part[1][row][col]);
  float4 s2 = *reinterpret_cast<const float4*>(&part[2][row][col]);
  float4 s3 = *reinterpret_cast<const float4*>(&part[3][row][col]);
  float4 wb = *reinterpret_cast<const float4*>(&Wb[col]);
  float4 bi = *reinterpret_cast<const float4*>(&bimg[col]);
  float4 o;
  o.x = s0.x + s1.x + s2.x + s3.x + wb.x + bi.x;
  o.y = s0.y + s1.y + s2.y + s3.y + wb.y + bi.y;
  o.z = s0.z + s1.z + s2.z + s3.z + wb.z + bi.z;
  o.w = s0.w + s1.w + s2.w + s3.w + wb.w + bi.w;
  *reinterpret_cast<float4*>(&img_out[(size_t)(r0 + row) * 64 + col]) = o;
}

// ---------------- Kernel A2: base[b][w] = [ue|img] @ Wi[64:192] + Wib + bai ----------------
__global__ __launch_bounds__(256, 4)
void base_kernel(const int* __restrict__ user_input,
                 const float* __restrict__ user_emb,
                 const float* __restrict__ ws_img,
                 const float* __restrict__ Wi,    // [192][64]
                 const float* __restrict__ Wib,   // [64]
                 const float* __restrict__ bai,   // [64]
                 float* __restrict__ ws_base) {
  __shared__ float W_s[128 * 64];
  __shared__ float x_s[4][128];
  const int t = threadIdx.x;
  for (int i = t; i < 128 * 64 / 4; i += 256)
    reinterpret_cast<float4*>(W_s)[i] =
        reinterpret_cast<const float4*>(Wi + 64 * 64)[i];
  __syncthreads();
  const int wave = t >> 6, lane = t & 63;
  const float bb = Wib[lane] + bai[lane];
  const int b0 = blockIdx.x * 32 + wave * 8;
#pragma unroll 1
  for (int bi = 0; bi < 8; ++bi) {
    const int b = b0 + bi;
    const int u = user_input[b];
    x_s[wave][lane] = user_emb[(size_t)u * 64 + lane];
    x_s[wave][64 + lane] = ws_img[(size_t)b * 64 + lane];
    asm volatile("s_waitcnt lgkmcnt(0)" ::: "memory");
    float acc = bb;
    const float4* x4 = reinterpret_cast<const float4*>(&x_s[wave][0]);
#pragma unroll
    for (int d0 = 0; d0 < 32; ++d0) {
      float4 q = x4[d0];
      int d = d0 * 4;
      acc = fmaf(q.x, W_s[(d + 0) * 64 + lane],
            fmaf(q.y, W_s[(d + 1) * 64 + lane],
            fmaf(q.z, W_s[(d + 2) * 64 + lane],
            fmaf(q.w, W_s[(d + 3) * 64 + lane], acc))));
    }
    ws_base[(size_t)b * 64 + lane] = acc;
    asm volatile("s_waitcnt lgkmcnt(0)" ::: "memory");
  }
}

// ---------------- Kernel B1: ingredient attention via MFMA ----------------
__global__ __launch_bounds__(256, 2)
void ingre_att_mfma(const int* __restrict__ ingre_input,
                    const int* __restrict__ ingre_num,
                    const float* __restrict__ ingre_emb,
                    const short* __restrict__ W1t,   // [64][64] bf16
                    const float* __restrict__ v,
                    const float* __restrict__ ws_base,
                    float* __restrict__ ws_ia) {
  __shared__ float sc_lds[4][32];
  const int t = threadIdx.x, wave = t >> 6, lane = t & 63;
  const int lr = lane & 15, lk = lane >> 4;
  bf16x8 wf[4][2];
#pragma unroll
  for (int wt = 0; wt < 4; ++wt)
#pragma unroll
    for (int ks = 0; ks < 2; ++ks)
      wf[wt][ks] = *reinterpret_cast<const bf16x8*>(
          W1t + (16 * wt + lr) * 64 + ks * 32 + lk * 8);
  float vv[4];
#pragma unroll
  for (int wt = 0; wt < 4; ++wt) vv[wt] = v[16 * wt + lr];
  const int b0 = blockIdx.x * 32 + wave * 8;
#pragma unroll 1
  for (int bi = 0; bi < 8; ++bi) {
    const int b = b0 + bi;
    const int n1 = 16 + lr;
    const int gi0 = ingre_input[b * NN + lr];
    const int gi1 = ingre_input[b * NN + ((n1 < NN) ? n1 : 0)];
    bf16x8 a0[2], a1[2];
#pragma unroll
    for (int ks = 0; ks < 2; ++ks) {
      const float4* p0 = reinterpret_cast<const float4*>(
          ingre_emb + (size_t)gi0 * 64 + ks * 32 + lk * 8);
      a0[ks] = pack8(p0[0], p0[1]);
      const float4* p1 = reinterpret_cast<const float4*>(
          ingre_emb + (size_t)gi1 * 64 + ks * 32 + lk * 8);
      a1[ks] = pack8(p1[0], p1[1]);
    }
    f32x4 acc[2][4];
#pragma unroll
    for (int nt = 0; nt < 2; ++nt)
#pragma unroll
      for (int wt = 0; wt < 4; ++wt) acc[nt][wt] = (f32x4){0.f, 0.f, 0.f, 0.f};
#pragma unroll
    for (int ks = 0; ks < 2; ++ks)
#pragma unroll
      for (int wt = 0; wt < 4; ++wt) {
        acc[0][wt] = __builtin_amdgcn_mfma_f32_16x16x32_bf16(a0[ks], wf[wt][ks], acc[0][wt], 0, 0, 0);
        acc[1][wt] = __builtin_amdgcn_mfma_f32_16x16x32_bf16(a1[ks], wf[wt][ks], acc[1][wt], 0, 0, 0);
      }
    float basew[4];
#pragma unroll
    for (int wt = 0; wt < 4; ++wt) basew[wt] = ws_base[(size_t)b * 64 + 16 * wt + lr];
    float sp[2][4];
#pragma unroll
    for (int nt = 0; nt < 2; ++nt)
#pragma unroll
      for (int r = 0; r < 4; ++r) {
        float s = 0.f;
#pragma unroll
        for (int wt = 0; wt < 4; ++wt) {
          float x = acc[nt][wt][r] + basew[wt];
          s = fmaf(fast_tanh(x), vv[wt], s);
        }
        sp[nt][r] = s;
      }
#pragma unroll
    for (int off = 1; off < 16; off <<= 1)
#pragma unroll
      for (int nt = 0; nt < 2; ++nt)
#pragma unroll
        for (int r = 0; r < 4; ++r) sp[nt][r] += __shfl_xor(sp[nt][r], off, 64);
    if (lr == 0) {
#pragma unroll
      for (int r = 0; r < 4; ++r) {
        sc_lds[wave][4 * lk + r] = sp[0][r];
        sc_lds[wave][16 + 4 * lk + r] = sp[1][r];
      }
    }
    asm volatile("s_waitcnt lgkmcnt(0)" ::: "memory");
    float scn[NN];
#pragma unroll
    for (int q = 0; q < 5; ++q) {
      float4 s4 = *reinterpret_cast<const float4*>(&sc_lds[wave][4 * q]);
      scn[4 * q + 0] = s4.x; scn[4 * q + 1] = s4.y;
      scn[4 * q + 2] = s4.z; scn[4 * q + 3] = s4.w;
    }
    asm volatile("s_waitcnt lgkmcnt(0)" ::: "memory");
    const int num = ingre_num[b];
    float m = -3e38f;
#pragma unroll
    for (int n = 0; n < NN; ++n) {
      scn[n] = (n < num) ? scn[n] : -1e12f;
      m = fmaxf(m, scn[n]);
    }
    float ev[NN], ssum = 0.f;
#pragma unroll
    for (int n = 0; n < NN; ++n) {
      ev[n] = __expf(scn[n] - m);
      ssum += ev[n];
    }
    const float inv = __fdividef(1.f, ssum);
    float qv[NN];
#pragma unroll
    for (int n = 0; n < NN; ++n) {
      const int gi = ingre_input[b * NN + n];
      qv[n] = ingre_emb[(size_t)gi * 64 + lane];
    }
    float ia = 0.f;
#pragma unroll
    for (int n = 0; n < NN; ++n) ia = fmaf(ev[n], qv[n], ia);
    ws_ia[(size_t)b * 64 + lane] = ia * inv;
  }
}

// ---------------- Kernel B2: component scores -> flat [3B] ----------------
__global__ __launch_bounds__(256, 4)
void com_score_kernel(const int* __restrict__ user_input,
                      const int* __restrict__ item_input,
                      const float* __restrict__ user_emb,
                      const float* __restrict__ item_emb,
                      const float* __restrict__ Wc,    // [128][64]
                      const float* __restrict__ Wcb,   // [64]
                      const float* __restrict__ bat,   // [64]
                      const float* __restrict__ vc,    // [64]
                      const float* __restrict__ ws_img,
                      const float* __restrict__ ws_ia,
                      float* __restrict__ ws_flat) {
  __shared__ float Wclds[128 * 64];
  __shared__ float x_s[4][4][64];
  const int t = threadIdx.x;
  for (int i = t; i < 128 * 64 / 4; i += 256)
    reinterpret_cast<float4*>(Wclds)[i] = reinterpret_cast<const float4*>(Wc)[i];
  __syncthreads();
  const int wave = t >> 6, lane = t & 63;
  const float bb = Wcb[lane] + bat[lane];
  const float vcl = vc[lane];
  const int b0 = blockIdx.x * 32 + wave * 8;
#pragma unroll 1
  for (int bi = 0; bi < 8; ++bi) {
    const int b = b0 + bi;
    const int u = user_input[b];
    const int it = item_input[b];
    x_s[wave][0][lane] = user_emb[(size_t)u * 64 + lane];
    x_s[wave][1][lane] = item_emb[(size_t)it * 64 + lane];
    x_s[wave][2][lane] = ws_ia[(size_t)b * 64 + lane];
    x_s[wave][3][lane] = ws_img[(size_t)b * 64 + lane];
    asm volatile("s_waitcnt lgkmcnt(0)" ::: "memory");
    const float4* u4 = reinterpret_cast<const float4*>(&x_s[wave][0][0]);
    float up = 0.f;
#pragma unroll
    for (int d0 = 0; d0 < 16; ++d0) {
      float4 q = u4[d0];
      int d = d0 * 4;
      up = fmaf(q.x, Wclds[(d + 0) * 64 + lane],
           fmaf(q.y, Wclds[(d + 1) * 64 + lane],
           fmaf(q.z, Wclds[(d + 2) * 64 + lane],
           fmaf(q.w, Wclds[(d + 3) * 64 + lane], up))));
    }
    float sc[3];
#pragma unroll
    for (int c = 0; c < 3; ++c) {
      const float4* y4 = reinterpret_cast<const float4*>(&x_s[wave][1 + c][0]);
      float s = bb + up;
#pragma unroll
      for (int d0 = 0; d0 < 16; ++d0) {
        float4 q = y4[d0];
        int d = 64 + d0 * 4;
        s = fmaf(q.x, Wclds[(d + 0) * 64 + lane],
            fmaf(q.y, Wclds[(d + 1) * 64 + lane],
            fmaf(q.z, Wclds[(d + 2) * 64 + lane],
            fmaf(q.w, Wclds[(d + 3) * 64 + lane], s))));
      }
      sc[c] = waveReduceSum(fast_tanh(s) * vcl);
    }
    if (lane == 0) {
      ws_flat[b] = sc[0];
      ws_flat[BB + b] = sc[1];
      ws_flat[2 * BB + b] = sc[2];
    }
    asm volatile("s_waitcnt lgkmcnt(0)" ::: "memory");
  }
}

// ---------------- Kernel C: head. scores[i][j] = flat[3i+j] ----------------
__global__ __launch_bounds__(256, 3)
void head_kernel(const int* __restrict__ user_input,
                 const int* __restrict__ item_input,
                 const float* __restrict__ user_emb,
                 const float* __restrict__ item_emb,
                 const float* __restrict__ Wcat,   // [192][64]
                 const float* __restrict__ Wcatb,  // [64]
                 const float* __restrict__ bcat,   // [64]
                 const float* __restrict__ hw,     // [64]
                 const float* __restrict__ hb,     // [1]
                 const float* __restrict__ ws_img,
                 const float* __restrict__ ws_ia,
                 const float* __restrict__ ws_flat,
                 float* __restrict__ out) {
  __shared__ float Wlds[192 * 64];
  __shared__ float ue_s[4][64];
  __shared__ float itt_s[4][64];
  const int t = threadIdx.x;
  for (int i = t; i < 192 * 64 / 4; i += 256)
    reinterpret_cast<float4*>(Wlds)[i] = reinterpret_cast<const float4*>(Wcat)[i];
  __syncthreads();
  const int wave = t >> 6, lane = t & 63;
  const float bb = Wcatb[lane] + bcat[lane];
  const float hwl = hw[lane];
  const float hbv = hb[0];
  const int b0 = blockIdx.x * 32 + wave * 8;
#pragma unroll 1
  for (int bi = 0; bi < 8; ++bi) {
    const int b = b0 + bi;
    const float s0 = ws_flat[3 * b + 0];
    const float s1 = ws_flat[3 * b + 1];
    const float s2 = ws_flat[3 * b + 2];
    const float m = fmaxf(s0, fmaxf(s1, s2));
    const float e0 = __expf(s0 - m), e1 = __expf(s1 - m), e2 = __expf(s2 - m);
    const float inv = 1.0f / (e0 + e1 + e2);
    const int u = user_input[b];
    const int it = item_input[b];
    const float uev = user_emb[(size_t)u * 64 + lane];
    const float itt = (e0 * item_emb[(size_t)it * 64 + lane] +
                       e1 * ws_ia[(size_t)b * 64 + lane] +
                       e2 * ws_img[(size_t)b * 64 + lane]) * inv;
    ue_s[wave][lane] = uev;
    itt_s[wave][lane] = itt;
    asm volatile("s_waitcnt lgkmcnt(0)" ::: "memory");
    const float4* u4 = reinterpret_cast<const float4*>(&ue_s[wave][0]);
    const float4* i4 = reinterpret_cast<const float4*>(&itt_s[wave][0]);
    float h = bb;
#pragma unroll
    for (int d0 = 0; d0 < 16; ++d0) {
      float4 uu = u4[d0];
      float4 ii = i4[d0];
      int d = d0 * 4;
      h = fmaf(uu.x, Wlds[(d + 0) * 64 + lane], h);
      h = fmaf(ii.x, Wlds[(64 + d + 0) * 64 + lane], h);
      h = fmaf(uu.x * ii.x, Wlds[(128 + d + 0) * 64 + lane], h);
      h = fmaf(uu.y, Wlds[(d + 1) * 64 + lane], h);
      h = fmaf(ii.y, Wlds[(64 + d + 1) * 64 + lane], h);
      h = fmaf(uu.y * ii.y, Wlds[(128 + d + 1) * 64 + lane], h);
      h = fmaf(uu.z, Wlds[(d + 2) * 64 + lane], h);
      h = fmaf(ii.z, Wlds[(64 + d + 2) * 64 + lane], h);
      h = fmaf(uu.z * ii.z, Wlds[(128 + d + 2) * 64 + lane], h);
      h = fmaf(uu.w, Wlds[(d + 3) * 64 + lane], h);
      h = fmaf(ii.w, Wlds[(64 + d + 3) * 64 + lane], h);
      h = fmaf(uu.w * ii.w, Wlds[(128 + d + 3) * 64 + lane], h);
    }
    h = fmaxf(h, 0.f) * hwl;
    float o = waveReduceSum(h);
    if (lane == 0) out[b] = o + hbv;
    asm volatile("s_waitcnt lgkmcnt(0)" ::: "memory");
  }
}

extern "C" void kernel_launch(void* const* d_in, const int* in_sizes, int n_in,
                              void* d_out, int out_size, void* d_ws, size_t ws_size,
                              hipStream_t stream) {
  (void)in_sizes; (void)n_in; (void)out_size; (void)ws_size;
  const int* user_input = (const int*)d_in[0];
  const int* item_input = (const int*)d_in[1];
  const int* ingre_input = (const int*)d_in[2];
  const float* image_input = (const float*)d_in[3];
  const int* ingre_num = (const int*)d_in[4];
  const float* user_emb = (const float*)d_in[5];
  const float* item_emb = (const float*)d_in[6];
  const float* ingre_emb = (const float*)d_in[7];
  const float* W_image_w = (const float*)d_in[8];
  const float* W_image_b = (const float*)d_in[9];
  const float* b_image = (const float*)d_in[10];
  const float* W_concat_w = (const float*)d_in[11];
  const float* W_concat_b = (const float*)d_in[12];
  const float* b_concat = (const float*)d_in[13];
  const float* h_w = (const float*)d_in[14];
  const float* h_b = (const float*)d_in[15];
  const float* W_att_ingre_w = (const float*)d_in[16];
  const float* W_att_ingre_b = (const float*)d_in[17];
  const float* b_att_ingre = (const float*)d_in[18];
  const float* v = (const float*)d_in[19];
  const float* W_att_com_w = (const float*)d_in[20];
  const float* W_att_com_b = (const float*)d_in[21];
  const float* b_att_com = (const float*)d_in[22];
  const float* v_c = (const float*)d_in[23];

  float* ws = (float*)d_ws;
  float* ws_img = ws;                              // [B*64] f32
  float* ws_ia = ws + (size_t)BB * 64;             // [B*64] f32
  float* ws_base = ws + (size_t)2 * BB * 64;       // [B*64] f32
  float* ws_flat = ws + (size_t)3 * BB * 64;       // [3B] f32
  short* Wt_hi = (short*)(ws + (size_t)3 * BB * 64 + 3 * BB);   // [64*2048] bf16
  short* Wt_lo = Wt_hi + (size_t)64 * IMGK;                     // [64*2048] bf16
  short* W1t = Wt_lo + (size_t)64 * IMGK;                       // [64*64] bf16
  float* out = (float*)d_out;

  prep_kernel<<<(IMGK * 64 + 64 * 64 + 255) / 256, 256, 0, stream>>>(
      W_image_w, W_att_ingre_w, Wt_hi, Wt_lo, W1t);
  img_gemm_mfma<<<BB / 16, 256, 0, stream>>>(image_input, Wt_hi, Wt_lo,
                                             W_image_b, b_image, ws_img);
  base_kernel<<<BB / 32, 256, 0, stream>>>(user_input, user_emb, ws_img,
                                           W_att_ingre_w, W_att_ingre_b, b_att_ingre,
                                           ws_base);
  ingre_att_mfma<<<BB / 32, 256, 0, stream>>>(ingre_input, ingre_num, ingre_emb,
                                              W1t, v, ws_base, ws_ia);
  com_score_kernel<<<BB / 32, 256, 0, stream>>>(user_input, item_input, user_emb, item_emb,
                                                W_att_com_w, W_att_com_b, b_att_com, v_c,
                                                ws_img, ws_ia, ws_flat);
  head_kernel<<<BB / 32, 256, 0, stream>>>(user_input, item_input, user_emb, item_emb,
                                           W_concat_w, W_concat_b, b_concat, h_w, h_b,
                                           ws_img, ws_ia, ws_flat, out);
}

// Round 7
// 179.346 us; speedup vs baseline: 1.1467x; 1.1343x over previous
//
#include <hip/hip_runtime.h>

#define BB 16384
#define NN 20
#define DD 64
#define IMGK 2048

using bf16x8 = __attribute__((ext_vector_type(8))) short;
using f32x4  = __attribute__((ext_vector_type(4))) float;

__device__ __forceinline__ float waveReduceSum(float x) {
#pragma unroll
  for (int off = 32; off > 0; off >>= 1) x += __shfl_xor(x, off, 64);
  return x;
}

__device__ __forceinline__ float fast_tanh(float x) {
  float e = __expf(2.f * x);
  return 1.f - __fdividef(2.f, e + 1.f);
}

__device__ __forceinline__ short f2bf(float f) {
  union { float f; unsigned u; } c; c.f = f;
  unsigned r = c.u + 0x7fffu + ((c.u >> 16) & 1u);
  return (short)(r >> 16);
}
__device__ __forceinline__ float bf2f(short s) {
  union { unsigned u; float f; } c; c.u = ((unsigned)(unsigned short)s) << 16;
  return c.f;
}

__device__ __forceinline__ unsigned cvt_pk_bf16(float lo, float hi) {
  unsigned r;
  asm("v_cvt_pk_bf16_f32 %0, %1, %2" : "=v"(r) : "v"(lo), "v"(hi));
  return r;
}

__device__ __forceinline__ bf16x8 pack8(float4 a, float4 b) {
  union { unsigned u[4]; bf16x8 v; } r;
  r.u[0] = cvt_pk_bf16(a.x, a.y);
  r.u[1] = cvt_pk_bf16(a.z, a.w);
  r.u[2] = cvt_pk_bf16(b.x, b.y);
  r.u[3] = cvt_pk_bf16(b.z, b.w);
  return r.v;
}

// truncation pack: top 16 bits of (a,b) -> one u32. Pure VALU.
__device__ __forceinline__ unsigned pack_hi(float a, float b) {
  unsigned ua = __float_as_uint(a), ub = __float_as_uint(b);
  return (ub & 0xffff0000u) | (ua >> 16);
}
__device__ __forceinline__ float trunc_bf(float a) {
  return __uint_as_float(__float_as_uint(a) & 0xffff0000u);
}

// ---------------- prep: transpose + split weights to bf16 ----------------
__global__ __launch_bounds__(256)
void prep_kernel(const float* __restrict__ Wimg, const float* __restrict__ W1,
                 short* __restrict__ Wt_hi, short* __restrict__ Wt_lo,
                 short* __restrict__ W1t) {
  int i = blockIdx.x * 256 + threadIdx.x;
  if (i < IMGK * 64) {
    int k = i >> 6, n = i & 63;
    float f = Wimg[i];
    short h = f2bf(f);
    Wt_hi[n * IMGK + k] = h;
    Wt_lo[n * IMGK + k] = f2bf(f - bf2f(h));
  } else if (i < IMGK * 64 + 64 * 64) {
    int j = i - IMGK * 64;
    int k = j >> 6, n = j & 63;
    W1t[n * 64 + k] = f2bf(W1[j]);
  }
}

// ---------------- Kernel A: img GEMM, W register-resident, K-quarter partials ----------------
// grid 1024 = 256 row-groups x 4 kq. Block 256 thr / 4 waves. Wave owns FIXED 128-wide
// K-slice: W hi+lo frags in 128 VGPRs, loaded once. Loop 4 chunks x 16 rows; A direct
// from global (8 float4/lane/chunk); LDS tree-combine across the block's 4 waves.
__global__ __launch_bounds__(256, 2)
void img_gemm_mfma(const float* __restrict__ img_in,
                   const short* __restrict__ Wt_hi,
                   const short* __restrict__ Wt_lo,
                   float* __restrict__ p0, float* __restrict__ p1,
                   float* __restrict__ p2, float* __restrict__ p3) {
  __shared__ float part[4][16][68];
  const int t = threadIdx.x;
  const int wave = t >> 6, lane = t & 63;
  const int lr = lane & 15, lk = lane >> 4;
  const int kq = blockIdx.x & 3, rg = blockIdx.x >> 2;
  const int k0 = kq * 512 + wave * 128;
  float* pout = (kq == 0) ? p0 : (kq == 1) ? p1 : (kq == 2) ? p2 : p3;

  // W fragments: loop-invariant, hoisted to registers (32 x b128 = 128 VGPR)
  bf16x8 wh[4][4], wl[4][4];
#pragma unroll
  for (int ks = 0; ks < 4; ++ks)
#pragma unroll
    for (int tt = 0; tt < 4; ++tt) {
      wh[ks][tt] = *reinterpret_cast<const bf16x8*>(
          Wt_hi + (size_t)(16 * tt + lr) * IMGK + k0 + ks * 32 + lk * 8);
      wl[ks][tt] = *reinterpret_cast<const bf16x8*>(
          Wt_lo + (size_t)(16 * tt + lr) * IMGK + k0 + ks * 32 + lk * 8);
    }

#pragma unroll 1
  for (int c = 0; c < 4; ++c) {
    const int r0 = rg * 64 + c * 16;
    const float* ar = img_in + (size_t)(r0 + lr) * IMGK + k0 + lk * 8;
    f32x4 aHH[4], aER[4];
#pragma unroll
    for (int tt = 0; tt < 4; ++tt) {
      aHH[tt] = (f32x4){0.f, 0.f, 0.f, 0.f};
      aER[tt] = (f32x4){0.f, 0.f, 0.f, 0.f};
    }
#pragma unroll
    for (int ks = 0; ks < 4; ++ks) {
      float4 va = *reinterpret_cast<const float4*>(ar + ks * 32);
      float4 vb = *reinterpret_cast<const float4*>(ar + ks * 32 + 4);
      union { unsigned u[4]; bf16x8 v; } hi, lo;
      hi.u[0] = pack_hi(va.x, va.y);
      hi.u[1] = pack_hi(va.z, va.w);
      hi.u[2] = pack_hi(vb.x, vb.y);
      hi.u[3] = pack_hi(vb.z, vb.w);
      lo.u[0] = pack_hi(va.x - trunc_bf(va.x), va.y - trunc_bf(va.y));
      lo.u[1] = pack_hi(va.z - trunc_bf(va.z), va.w - trunc_bf(va.w));
      lo.u[2] = pack_hi(vb.x - trunc_bf(vb.x), vb.y - trunc_bf(vb.y));
      lo.u[3] = pack_hi(vb.z - trunc_bf(vb.z), vb.w - trunc_bf(vb.w));
#pragma unroll
      for (int tt = 0; tt < 4; ++tt) {
        aHH[tt] = __builtin_amdgcn_mfma_f32_16x16x32_bf16(hi.v, wh[ks][tt], aHH[tt], 0, 0, 0);
        aER[tt] = __builtin_amdgcn_mfma_f32_16x16x32_bf16(hi.v, wl[ks][tt], aER[tt], 0, 0, 0);
        aER[tt] = __builtin_amdgcn_mfma_f32_16x16x32_bf16(lo.v, wh[ks][tt], aER[tt], 0, 0, 0);
      }
    }
#pragma unroll
    for (int tt = 0; tt < 4; ++tt)
#pragma unroll
      for (int r = 0; r < 4; ++r)
        part[wave][4 * lk + r][16 * tt + lr] = aHH[tt][r] + aER[tt][r];
    __syncthreads();
    {
      const int e = t * 4;
      const int row = e >> 6, col = e & 63;
      float4 s0 = *reinterpret_cast<const float4*>(&part[0][row][col]);
      float4 s1 = *reinterpret_cast<const float4*>(&part[1][row][col]);
      float4 s2 = *reinterpret_cast<const float4*>(&part[2][row][col]);
      float4 s3 = *reinterpret_cast<const float4*>(&part[3][row][col]);
      float4 o;
      o.x = s0.x + s1.x + s2.x + s3.x;
      o.y = s0.y + s1.y + s2.y + s3.y;
      o.z = s0.z + s1.z + s2.z + s3.z;
      o.w = s0.w + s1.w + s2.w + s3.w;
      *reinterpret_cast<float4*>(&pout[(size_t)(r0 + row) * 64 + col]) = o;
    }
    __syncthreads();
  }
}

// ---------------- combine: ws_img = p0+p1+p2+p3 + Wb + bimg ----------------
__global__ __launch_bounds__(256)
void img_combine(const float* __restrict__ p0, const float* __restrict__ p1,
                 const float* __restrict__ p2, const float* __restrict__ p3,
                 const float* __restrict__ Wb, const float* __restrict__ bimg,
                 float* __restrict__ img_out) {
  const int i = blockIdx.x * 256 + threadIdx.x;   // over 16384*64/4 float4s
  const int col = (i * 4) & 63;
  float4 a = reinterpret_cast<const float4*>(p0)[i];
  float4 b = reinterpret_cast<const float4*>(p1)[i];
  float4 c = reinterpret_cast<const float4*>(p2)[i];
  float4 d = reinterpret_cast<const float4*>(p3)[i];
  float4 wb = *reinterpret_cast<const float4*>(&Wb[col]);
  float4 bi = *reinterpret_cast<const float4*>(&bimg[col]);
  float4 o;
  o.x = a.x + b.x + c.x + d.x + wb.x + bi.x;
  o.y = a.y + b.y + c.y + d.y + wb.y + bi.y;
  o.z = a.z + b.z + c.z + d.z + wb.z + bi.z;
  o.w = a.w + b.w + c.w + d.w + wb.w + bi.w;
  reinterpret_cast<float4*>(img_out)[i] = o;
}

// ---------------- Kernel A2: base[b][w] = [ue|img] @ Wi[64:192] + Wib + bai ----------------
__global__ __launch_bounds__(256, 4)
void base_kernel(const int* __restrict__ user_input,
                 const float* __restrict__ user_emb,
                 const float* __restrict__ ws_img,
                 const float* __restrict__ Wi,    // [192][64]
                 const float* __restrict__ Wib,   // [64]
                 const float* __restrict__ bai,   // [64]
                 float* __restrict__ ws_base) {
  __shared__ float W_s[128 * 64];
  __shared__ float x_s[4][128];
  const int t = threadIdx.x;
  for (int i = t; i < 128 * 64 / 4; i += 256)
    reinterpret_cast<float4*>(W_s)[i] =
        reinterpret_cast<const float4*>(Wi + 64 * 64)[i];
  __syncthreads();
  const int wave = t >> 6, lane = t & 63;
  const float bb = Wib[lane] + bai[lane];
  const int b0 = blockIdx.x * 32 + wave * 8;
#pragma unroll 1
  for (int bi = 0; bi < 8; ++bi) {
    const int b = b0 + bi;
    const int u = user_input[b];
    x_s[wave][lane] = user_emb[(size_t)u * 64 + lane];
    x_s[wave][64 + lane] = ws_img[(size_t)b * 64 + lane];
    asm volatile("s_waitcnt lgkmcnt(0)" ::: "memory");
    float acc = bb;
    const float4* x4 = reinterpret_cast<const float4*>(&x_s[wave][0]);
#pragma unroll
    for (int d0 = 0; d0 < 32; ++d0) {
      float4 q = x4[d0];
      int d = d0 * 4;
      acc = fmaf(q.x, W_s[(d + 0) * 64 + lane],
            fmaf(q.y, W_s[(d + 1) * 64 + lane],
            fmaf(q.z, W_s[(d + 2) * 64 + lane],
            fmaf(q.w, W_s[(d + 3) * 64 + lane], acc))));
    }
    ws_base[(size_t)b * 64 + lane] = acc;
    asm volatile("s_waitcnt lgkmcnt(0)" ::: "memory");
  }
}

// ---------------- Kernel B1: ingredient attention via MFMA ----------------
__global__ __launch_bounds__(256, 2)
void ingre_att_mfma(const int* __restrict__ ingre_input,
                    const int* __restrict__ ingre_num,
                    const float* __restrict__ ingre_emb,
                    const short* __restrict__ W1t,   // [64][64] bf16
                    const float* __restrict__ v,
                    const float* __restrict__ ws_base,
                    float* __restrict__ ws_ia) {
  __shared__ float sc_lds[4][32];
  const int t = threadIdx.x, wave = t >> 6, lane = t & 63;
  const int lr = lane & 15, lk = lane >> 4;
  bf16x8 wf[4][2];
#pragma unroll
  for (int wt = 0; wt < 4; ++wt)
#pragma unroll
    for (int ks = 0; ks < 2; ++ks)
      wf[wt][ks] = *reinterpret_cast<const bf16x8*>(
          W1t + (16 * wt + lr) * 64 + ks * 32 + lk * 8);
  float vv[4];
#pragma unroll
  for (int wt = 0; wt < 4; ++wt) vv[wt] = v[16 * wt + lr];
  const int b0 = blockIdx.x * 32 + wave * 8;
#pragma unroll 1
  for (int bi = 0; bi < 8; ++bi) {
    const int b = b0 + bi;
    const int n1 = 16 + lr;
    const int gi0 = ingre_input[b * NN + lr];
    const int gi1 = ingre_input[b * NN + ((n1 < NN) ? n1 : 0)];
    bf16x8 a0[2], a1[2];
#pragma unroll
    for (int ks = 0; ks < 2; ++ks) {
      const float4* p0 = reinterpret_cast<const float4*>(
          ingre_emb + (size_t)gi0 * 64 + ks * 32 + lk * 8);
      a0[ks] = pack8(p0[0], p0[1]);
      const float4* p1 = reinterpret_cast<const float4*>(
          ingre_emb + (size_t)gi1 * 64 + ks * 32 + lk * 8);
      a1[ks] = pack8(p1[0], p1[1]);
    }
    f32x4 acc[2][4];
#pragma unroll
    for (int nt = 0; nt < 2; ++nt)
#pragma unroll
      for (int wt = 0; wt < 4; ++wt) acc[nt][wt] = (f32x4){0.f, 0.f, 0.f, 0.f};
#pragma unroll
    for (int ks = 0; ks < 2; ++ks)
#pragma unroll
      for (int wt = 0; wt < 4; ++wt) {
        acc[0][wt] = __builtin_amdgcn_mfma_f32_16x16x32_bf16(a0[ks], wf[wt][ks], acc[0][wt], 0, 0, 0);
        acc[1][wt] = __builtin_amdgcn_mfma_f32_16x16x32_bf16(a1[ks], wf[wt][ks], acc[1][wt], 0, 0, 0);
      }
    float basew[4];
#pragma unroll
    for (int wt = 0; wt < 4; ++wt) basew[wt] = ws_base[(size_t)b * 64 + 16 * wt + lr];
    float sp[2][4];
#pragma unroll
    for (int nt = 0; nt < 2; ++nt)
#pragma unroll
      for (int r = 0; r < 4; ++r) {
        float s = 0.f;
#pragma unroll
        for (int wt = 0; wt < 4; ++wt) {
          float x = acc[nt][wt][r] + basew[wt];
          s = fmaf(fast_tanh(x), vv[wt], s);
        }
        sp[nt][r] = s;
      }
#pragma unroll
    for (int off = 1; off < 16; off <<= 1)
#pragma unroll
      for (int nt = 0; nt < 2; ++nt)
#pragma unroll
        for (int r = 0; r < 4; ++r) sp[nt][r] += __shfl_xor(sp[nt][r], off, 64);
    if (lr == 0) {
#pragma unroll
      for (int r = 0; r < 4; ++r) {
        sc_lds[wave][4 * lk + r] = sp[0][r];
        sc_lds[wave][16 + 4 * lk + r] = sp[1][r];
      }
    }
    asm volatile("s_waitcnt lgkmcnt(0)" ::: "memory");
    float scn[NN];
#pragma unroll
    for (int q = 0; q < 5; ++q) {
      float4 s4 = *reinterpret_cast<const float4*>(&sc_lds[wave][4 * q]);
      scn[4 * q + 0] = s4.x; scn[4 * q + 1] = s4.y;
      scn[4 * q + 2] = s4.z; scn[4 * q + 3] = s4.w;
    }
    asm volatile("s_waitcnt lgkmcnt(0)" ::: "memory");
    const int num = ingre_num[b];
    float m = -3e38f;
#pragma unroll
    for (int n = 0; n < NN; ++n) {
      scn[n] = (n < num) ? scn[n] : -1e12f;
      m = fmaxf(m, scn[n]);
    }
    float ev[NN], ssum = 0.f;
#pragma unroll
    for (int n = 0; n < NN; ++n) {
      ev[n] = __expf(scn[n] - m);
      ssum += ev[n];
    }
    const float inv = __fdividef(1.f, ssum);
    float qv[NN];
#pragma unroll
    for (int n = 0; n < NN; ++n) {
      const int gi = ingre_input[b * NN + n];
      qv[n] = ingre_emb[(size_t)gi * 64 + lane];
    }
    float ia = 0.f;
#pragma unroll
    for (int n = 0; n < NN; ++n) ia = fmaf(ev[n], qv[n], ia);
    ws_ia[(size_t)b * 64 + lane] = ia * inv;
  }
}

// ---------------- Kernel B2: component scores -> flat [3B] ----------------
__global__ __launch_bounds__(256, 4)
void com_score_kernel(const int* __restrict__ user_input,
                      const int* __restrict__ item_input,
                      const float* __restrict__ user_emb,
                      const float* __restrict__ item_emb,
                      const float* __restrict__ Wc,    // [128][64]
                      const float* __restrict__ Wcb,   // [64]
                      const float* __restrict__ bat,   // [64]
                      const float* __restrict__ vc,    // [64]
                      const float* __restrict__ ws_img,
                      const float* __restrict__ ws_ia,
                      float* __restrict__ ws_flat) {
  __shared__ float Wclds[128 * 64];
  __shared__ float x_s[4][4][64];
  const int t = threadIdx.x;
  for (int i = t; i < 128 * 64 / 4; i += 256)
    reinterpret_cast<float4*>(Wclds)[i] = reinterpret_cast<const float4*>(Wc)[i];
  __syncthreads();
  const int wave = t >> 6, lane = t & 63;
  const float bb = Wcb[lane] + bat[lane];
  const float vcl = vc[lane];
  const int b0 = blockIdx.x * 32 + wave * 8;
#pragma unroll 1
  for (int bi = 0; bi < 8; ++bi) {
    const int b = b0 + bi;
    const int u = user_input[b];
    const int it = item_input[b];
    x_s[wave][0][lane] = user_emb[(size_t)u * 64 + lane];
    x_s[wave][1][lane] = item_emb[(size_t)it * 64 + lane];
    x_s[wave][2][lane] = ws_ia[(size_t)b * 64 + lane];
    x_s[wave][3][lane] = ws_img[(size_t)b * 64 + lane];
    asm volatile("s_waitcnt lgkmcnt(0)" ::: "memory");
    const float4* u4 = reinterpret_cast<const float4*>(&x_s[wave][0][0]);
    float up = 0.f;
#pragma unroll
    for (int d0 = 0; d0 < 16; ++d0) {
      float4 q = u4[d0];
      int d = d0 * 4;
      up = fmaf(q.x, Wclds[(d + 0) * 64 + lane],
           fmaf(q.y, Wclds[(d + 1) * 64 + lane],
           fmaf(q.z, Wclds[(d + 2) * 64 + lane],
           fmaf(q.w, Wclds[(d + 3) * 64 + lane], up))));
    }
    float sc[3];
#pragma unroll
    for (int c = 0; c < 3; ++c) {
      const float4* y4 = reinterpret_cast<const float4*>(&x_s[wave][1 + c][0]);
      float s = bb + up;
#pragma unroll
      for (int d0 = 0; d0 < 16; ++d0) {
        float4 q = y4[d0];
        int d = 64 + d0 * 4;
        s = fmaf(q.x, Wclds[(d + 0) * 64 + lane],
            fmaf(q.y, Wclds[(d + 1) * 64 + lane],
            fmaf(q.z, Wclds[(d + 2) * 64 + lane],
            fmaf(q.w, Wclds[(d + 3) * 64 + lane], s))));
      }
      sc[c] = waveReduceSum(fast_tanh(s) * vcl);
    }
    if (lane == 0) {
      ws_flat[b] = sc[0];
      ws_flat[BB + b] = sc[1];
      ws_flat[2 * BB + b] = sc[2];
    }
    asm volatile("s_waitcnt lgkmcnt(0)" ::: "memory");
  }
}

// ---------------- Kernel C: head. scores[i][j] = flat[3i+j] ----------------
__global__ __launch_bounds__(256, 3)
void head_kernel(const int* __restrict__ user_input,
                 const int* __restrict__ item_input,
                 const float* __restrict__ user_emb,
                 const float* __restrict__ item_emb,
                 const float* __restrict__ Wcat,   // [192][64]
                 const float* __restrict__ Wcatb,  // [64]
                 const float* __restrict__ bcat,   // [64]
                 const float* __restrict__ hw,     // [64]
                 const float* __restrict__ hb,     // [1]
                 const float* __restrict__ ws_img,
                 const float* __restrict__ ws_ia,
                 const float* __restrict__ ws_flat,
                 float* __restrict__ out) {
  __shared__ float Wlds[192 * 64];
  __shared__ float ue_s[4][64];
  __shared__ float itt_s[4][64];
  const int t = threadIdx.x;
  for (int i = t; i < 192 * 64 / 4; i += 256)
    reinterpret_cast<float4*>(Wlds)[i] = reinterpret_cast<const float4*>(Wcat)[i];
  __syncthreads();
  const int wave = t >> 6, lane = t & 63;
  const float bb = Wcatb[lane] + bcat[lane];
  const float hwl = hw[lane];
  const float hbv = hb[0];
  const int b0 = blockIdx.x * 32 + wave * 8;
#pragma unroll 1
  for (int bi = 0; bi < 8; ++bi) {
    const int b = b0 + bi;
    const float s0 = ws_flat[3 * b + 0];
    const float s1 = ws_flat[3 * b + 1];
    const float s2 = ws_flat[3 * b + 2];
    const float m = fmaxf(s0, fmaxf(s1, s2));
    const float e0 = __expf(s0 - m), e1 = __expf(s1 - m), e2 = __expf(s2 - m);
    const float inv = 1.0f / (e0 + e1 + e2);
    const int u = user_input[b];
    const int it = item_input[b];
    const float uev = user_emb[(size_t)u * 64 + lane];
    const float itt = (e0 * item_emb[(size_t)it * 64 + lane] +
                       e1 * ws_ia[(size_t)b * 64 + lane] +
                       e2 * ws_img[(size_t)b * 64 + lane]) * inv;
    ue_s[wave][lane] = uev;
    itt_s[wave][lane] = itt;
    asm volatile("s_waitcnt lgkmcnt(0)" ::: "memory");
    const float4* u4 = reinterpret_cast<const float4*>(&ue_s[wave][0]);
    const float4* i4 = reinterpret_cast<const float4*>(&itt_s[wave][0]);
    float h = bb;
#pragma unroll
    for (int d0 = 0; d0 < 16; ++d0) {
      float4 uu = u4[d0];
      float4 ii = i4[d0];
      int d = d0 * 4;
      h = fmaf(uu.x, Wlds[(d + 0) * 64 + lane], h);
      h = fmaf(ii.x, Wlds[(64 + d + 0) * 64 + lane], h);
      h = fmaf(uu.x * ii.x, Wlds[(128 + d + 0) * 64 + lane], h);
      h = fmaf(uu.y, Wlds[(d + 1) * 64 + lane], h);
      h = fmaf(ii.y, Wlds[(64 + d + 1) * 64 + lane], h);
      h = fmaf(uu.y * ii.y, Wlds[(128 + d + 1) * 64 + lane], h);
      h = fmaf(uu.z, Wlds[(d + 2) * 64 + lane], h);
      h = fmaf(ii.z, Wlds[(64 + d + 2) * 64 + lane], h);
      h = fmaf(uu.z * ii.z, Wlds[(128 + d + 2) * 64 + lane], h);
      h = fmaf(uu.w, Wlds[(d + 3) * 64 + lane], h);
      h = fmaf(ii.w, Wlds[(64 + d + 3) * 64 + lane], h);
      h = fmaf(uu.w * ii.w, Wlds[(128 + d + 3) * 64 + lane], h);
    }
    h = fmaxf(h, 0.f) * hwl;
    float o = waveReduceSum(h);
    if (lane == 0) out[b] = o + hbv;
    asm volatile("s_waitcnt lgkmcnt(0)" ::: "memory");
  }
}

extern "C" void kernel_launch(void* const* d_in, const int* in_sizes, int n_in,
                              void* d_out, int out_size, void* d_ws, size_t ws_size,
                              hipStream_t stream) {
  (void)in_sizes; (void)n_in; (void)out_size; (void)ws_size;
  const int* user_input = (const int*)d_in[0];
  const int* item_input = (const int*)d_in[1];
  const int* ingre_input = (const int*)d_in[2];
  const float* image_input = (const float*)d_in[3];
  const int* ingre_num = (const int*)d_in[4];
  const float* user_emb = (const float*)d_in[5];
  const float* item_emb = (const float*)d_in[6];
  const float* ingre_emb = (const float*)d_in[7];
  const float* W_image_w = (const float*)d_in[8];
  const float* W_image_b = (const float*)d_in[9];
  const float* b_image = (const float*)d_in[10];
  const float* W_concat_w = (const float*)d_in[11];
  const float* W_concat_b = (const float*)d_in[12];
  const float* b_concat = (const float*)d_in[13];
  const float* h_w = (const float*)d_in[14];
  const float* h_b = (const float*)d_in[15];
  const float* W_att_ingre_w = (const float*)d_in[16];
  const float* W_att_ingre_b = (const float*)d_in[17];
  const float* b_att_ingre = (const float*)d_in[18];
  const float* v = (const float*)d_in[19];
  const float* W_att_com_w = (const float*)d_in[20];
  const float* W_att_com_b = (const float*)d_in[21];
  const float* b_att_com = (const float*)d_in[22];
  const float* v_c = (const float*)d_in[23];

  float* ws = (float*)d_ws;
  float* ws_img = ws;                              // [B*64] f32
  float* ws_ia = ws + (size_t)BB * 64;             // [B*64] f32  (aliases p1 pre-ingre)
  float* ws_base = ws + (size_t)2 * BB * 64;       // [B*64] f32  (aliases p0 pre-base)
  float* ws_flat = ws + (size_t)3 * BB * 64;       // [3B] f32
  short* Wt_hi = (short*)(ws + (size_t)3 * BB * 64 + 3 * BB);   // [64*2048] bf16
  short* Wt_lo = Wt_hi + (size_t)64 * IMGK;                     // [64*2048] bf16
  short* W1t = Wt_lo + (size_t)64 * IMGK;                       // [64*64] bf16
  float* p2 = (float*)(W1t + 64 * 64);             // [B*64] f32
  float* p3 = p2 + (size_t)BB * 64;                // [B*64] f32
  float* p0 = ws_base;                             // consumed by combine before base writes
  float* p1 = ws_ia;                               // consumed by combine before ingre writes
  float* out = (float*)d_out;

  prep_kernel<<<(IMGK * 64 + 64 * 64 + 255) / 256, 256, 0, stream>>>(
      W_image_w, W_att_ingre_w, Wt_hi, Wt_lo, W1t);
  img_gemm_mfma<<<1024, 256, 0, stream>>>(image_input, Wt_hi, Wt_lo, p0, p1, p2, p3);
  img_combine<<<BB * 64 / 4 / 256, 256, 0, stream>>>(p0, p1, p2, p3,
                                                     W_image_b, b_image, ws_img);
  base_kernel<<<BB / 32, 256, 0, stream>>>(user_input, user_emb, ws_img,
                                           W_att_ingre_w, W_att_ingre_b, b_att_ingre,
                                           ws_base);
  ingre_att_mfma<<<BB / 32, 256, 0, stream>>>(ingre_input, ingre_num, ingre_emb,
                                              W1t, v, ws_base, ws_ia);
  com_score_kernel<<<BB / 32, 256, 0, stream>>>(user_input, item_input, user_emb, item_emb,
                                                W_att_com_w, W_att_com_b, b_att_com, v_c,
                                                ws_img, ws_ia, ws_flat);
  head_kernel<<<BB / 32, 256, 0, stream>>>(user_input, item_input, user_emb, item_emb,
                                           W_concat_w, W_concat_b, b_concat, h_w, h_b,
                                           ws_img, ws_ia, ws_flat, out);
}

// Round 8
// 170.891 us; speedup vs baseline: 1.2035x; 1.0495x over previous
//
#include <hip/hip_runtime.h>

#define BB 16384
#define NN 20
#define DD 64
#define IMGK 2048

using bf16x8 = __attribute__((ext_vector_type(8))) short;
using f32x4  = __attribute__((ext_vector_type(4))) float;

__device__ __forceinline__ float waveReduceSum(float x) {
#pragma unroll
  for (int off = 32; off > 0; off >>= 1) x += __shfl_xor(x, off, 64);
  return x;
}

__device__ __forceinline__ float fast_tanh(float x) {
  float e = __expf(2.f * x);
  return 1.f - __fdividef(2.f, e + 1.f);
}

__device__ __forceinline__ short f2bf(float f) {
  union { float f; unsigned u; } c; c.f = f;
  unsigned r = c.u + 0x7fffu + ((c.u >> 16) & 1u);
  return (short)(r >> 16);
}
__device__ __forceinline__ float bf2f(short s) {
  union { unsigned u; float f; } c; c.u = ((unsigned)(unsigned short)s) << 16;
  return c.f;
}

__device__ __forceinline__ unsigned cvt_pk_bf16(float lo, float hi) {
  unsigned r;
  asm("v_cvt_pk_bf16_f32 %0, %1, %2" : "=v"(r) : "v"(lo), "v"(hi));
  return r;
}

__device__ __forceinline__ bf16x8 pack8(float4 a, float4 b) {
  union { unsigned u[4]; bf16x8 v; } r;
  r.u[0] = cvt_pk_bf16(a.x, a.y);
  r.u[1] = cvt_pk_bf16(a.z, a.w);
  r.u[2] = cvt_pk_bf16(b.x, b.y);
  r.u[3] = cvt_pk_bf16(b.z, b.w);
  return r.v;
}

// truncation pack: top 16 bits of (a,b) -> one u32. Pure VALU.
__device__ __forceinline__ unsigned pack_hi(float a, float b) {
  unsigned ua = __float_as_uint(a), ub = __float_as_uint(b);
  return (ub & 0xffff0000u) | (ua >> 16);
}
__device__ __forceinline__ float trunc_bf(float a) {
  return __uint_as_float(__float_as_uint(a) & 0xffff0000u);
}

// ---------------- prep: transpose + split weights to bf16 ----------------
__global__ __launch_bounds__(256)
void prep_kernel(const float* __restrict__ Wimg, const float* __restrict__ W1,
                 short* __restrict__ Wt_hi, short* __restrict__ Wt_lo,
                 short* __restrict__ W1t) {
  int i = blockIdx.x * 256 + threadIdx.x;
  if (i < IMGK * 64) {
    int k = i >> 6, n = i & 63;
    float f = Wimg[i];
    short h = f2bf(f);
    Wt_hi[n * IMGK + k] = h;
    Wt_lo[n * IMGK + k] = f2bf(f - bf2f(h));
  } else if (i < IMGK * 64 + 64 * 64) {
    int j = i - IMGK * 64;
    int k = j >> 6, n = j & 63;
    W1t[n * 64 + k] = f2bf(W1[j]);
  }
}

// ---------------- Kernel A: img GEMM, 8-way K-split, W register-resident ----------------
// grid 2048 = 256 row-groups x 8 kq. Wave owns FIXED 64-wide K-slice: W hi+lo frags in
// 64 VGPRs. Loop 4 chunks x 16 rows; A direct from global; LDS combine across 4 waves.
__global__ __launch_bounds__(256, 3)
void img_gemm_mfma(const float* __restrict__ img_in,
                   const short* __restrict__ Wt_hi,
                   const short* __restrict__ Wt_lo,
                   float* __restrict__ pp) {
  __shared__ float part[4][16][68];
  const int t = threadIdx.x;
  const int wave = t >> 6, lane = t & 63;
  const int lr = lane & 15, lk = lane >> 4;
  const int kq = blockIdx.x & 7, rg = blockIdx.x >> 3;
  const int k0 = kq * 256 + wave * 64;
  float* pout = pp + (size_t)kq * BB * 64;

  // W fragments: loop-invariant, register-resident (16 x b128 = 64 VGPR)
  bf16x8 wh[2][4], wl[2][4];
#pragma unroll
  for (int ks = 0; ks < 2; ++ks)
#pragma unroll
    for (int tt = 0; tt < 4; ++tt) {
      wh[ks][tt] = *reinterpret_cast<const bf16x8*>(
          Wt_hi + (size_t)(16 * tt + lr) * IMGK + k0 + ks * 32 + lk * 8);
      wl[ks][tt] = *reinterpret_cast<const bf16x8*>(
          Wt_lo + (size_t)(16 * tt + lr) * IMGK + k0 + ks * 32 + lk * 8);
    }

#pragma unroll 1
  for (int c = 0; c < 4; ++c) {
    const int r0 = rg * 64 + c * 16;
    const float* ar = img_in + (size_t)(r0 + lr) * IMGK + k0 + lk * 8;
    f32x4 aHH[4], aER[4];
#pragma unroll
    for (int tt = 0; tt < 4; ++tt) {
      aHH[tt] = (f32x4){0.f, 0.f, 0.f, 0.f};
      aER[tt] = (f32x4){0.f, 0.f, 0.f, 0.f};
    }
#pragma unroll
    for (int ks = 0; ks < 2; ++ks) {
      float4 va = *reinterpret_cast<const float4*>(ar + ks * 32);
      float4 vb = *reinterpret_cast<const float4*>(ar + ks * 32 + 4);
      union { unsigned u[4]; bf16x8 v; } hi, lo;
      hi.u[0] = pack_hi(va.x, va.y);
      hi.u[1] = pack_hi(va.z, va.w);
      hi.u[2] = pack_hi(vb.x, vb.y);
      hi.u[3] = pack_hi(vb.z, vb.w);
      lo.u[0] = pack_hi(va.x - trunc_bf(va.x), va.y - trunc_bf(va.y));
      lo.u[1] = pack_hi(va.z - trunc_bf(va.z), va.w - trunc_bf(va.w));
      lo.u[2] = pack_hi(vb.x - trunc_bf(vb.x), vb.y - trunc_bf(vb.y));
      lo.u[3] = pack_hi(vb.z - trunc_bf(vb.z), vb.w - trunc_bf(vb.w));
#pragma unroll
      for (int tt = 0; tt < 4; ++tt) {
        aHH[tt] = __builtin_amdgcn_mfma_f32_16x16x32_bf16(hi.v, wh[ks][tt], aHH[tt], 0, 0, 0);
        aER[tt] = __builtin_amdgcn_mfma_f32_16x16x32_bf16(hi.v, wl[ks][tt], aER[tt], 0, 0, 0);
        aER[tt] = __builtin_amdgcn_mfma_f32_16x16x32_bf16(lo.v, wh[ks][tt], aER[tt], 0, 0, 0);
      }
    }
#pragma unroll
    for (int tt = 0; tt < 4; ++tt)
#pragma unroll
      for (int r = 0; r < 4; ++r)
        part[wave][4 * lk + r][16 * tt + lr] = aHH[tt][r] + aER[tt][r];
    __syncthreads();
    {
      const int e = t * 4;
      const int row = e >> 6, col = e & 63;
      float4 s0 = *reinterpret_cast<const float4*>(&part[0][row][col]);
      float4 s1 = *reinterpret_cast<const float4*>(&part[1][row][col]);
      float4 s2 = *reinterpret_cast<const float4*>(&part[2][row][col]);
      float4 s3 = *reinterpret_cast<const float4*>(&part[3][row][col]);
      float4 o;
      o.x = s0.x + s1.x + s2.x + s3.x;
      o.y = s0.y + s1.y + s2.y + s3.y;
      o.z = s0.z + s1.z + s2.z + s3.z;
      o.w = s0.w + s1.w + s2.w + s3.w;
      *reinterpret_cast<float4*>(&pout[(size_t)(r0 + row) * 64 + col]) = o;
    }
    __syncthreads();
  }
}

// ---------------- combine: ws_img = sum(8 partials) + Wb + bimg ----------------
__global__ __launch_bounds__(256)
void img_combine(const float* __restrict__ pp,
                 const float* __restrict__ Wb, const float* __restrict__ bimg,
                 float* __restrict__ img_out) {
  const int i = blockIdx.x * 256 + threadIdx.x;   // over 16384*64/4 float4s
  const int col = (i * 4) & 63;
  float4 s = {0.f, 0.f, 0.f, 0.f};
#pragma unroll
  for (int kq = 0; kq < 8; ++kq) {
    float4 a = reinterpret_cast<const float4*>(pp + (size_t)kq * BB * 64)[i];
    s.x += a.x; s.y += a.y; s.z += a.z; s.w += a.w;
  }
  float4 wb = *reinterpret_cast<const float4*>(&Wb[col]);
  float4 bi = *reinterpret_cast<const float4*>(&bimg[col]);
  s.x += wb.x + bi.x;
  s.y += wb.y + bi.y;
  s.z += wb.z + bi.z;
  s.w += wb.w + bi.w;
  reinterpret_cast<float4*>(img_out)[i] = s;
}

// ---------------- Kernel A2: base[b][w] = [ue|img] @ Wi[64:192] + Wib + bai ----------------
__global__ __launch_bounds__(256, 4)
void base_kernel(const int* __restrict__ user_input,
                 const float* __restrict__ user_emb,
                 const float* __restrict__ ws_img,
                 const float* __restrict__ Wi,    // [192][64]
                 const float* __restrict__ Wib,   // [64]
                 const float* __restrict__ bai,   // [64]
                 float* __restrict__ ws_base) {
  __shared__ float W_s[128 * 64];
  __shared__ float x_s[4][128];
  const int t = threadIdx.x;
  for (int i = t; i < 128 * 64 / 4; i += 256)
    reinterpret_cast<float4*>(W_s)[i] =
        reinterpret_cast<const float4*>(Wi + 64 * 64)[i];
  __syncthreads();
  const int wave = t >> 6, lane = t & 63;
  const float bb = Wib[lane] + bai[lane];
  const int b0 = blockIdx.x * 16 + wave * 4;
#pragma unroll 1
  for (int bi = 0; bi < 4; ++bi) {
    const int b = b0 + bi;
    const int u = user_input[b];
    x_s[wave][lane] = user_emb[(size_t)u * 64 + lane];
    x_s[wave][64 + lane] = ws_img[(size_t)b * 64 + lane];
    asm volatile("s_waitcnt lgkmcnt(0)" ::: "memory");
    float acc = bb;
    const float4* x4 = reinterpret_cast<const float4*>(&x_s[wave][0]);
#pragma unroll
    for (int d0 = 0; d0 < 32; ++d0) {
      float4 q = x4[d0];
      int d = d0 * 4;
      acc = fmaf(q.x, W_s[(d + 0) * 64 + lane],
            fmaf(q.y, W_s[(d + 1) * 64 + lane],
            fmaf(q.z, W_s[(d + 2) * 64 + lane],
            fmaf(q.w, W_s[(d + 3) * 64 + lane], acc))));
    }
    ws_base[(size_t)b * 64 + lane] = acc;
    asm volatile("s_waitcnt lgkmcnt(0)" ::: "memory");
  }
}

// ---------------- Kernel B1: ingredient attention via MFMA ----------------
__global__ __launch_bounds__(256, 3)
void ingre_att_mfma(const int* __restrict__ ingre_input,
                    const int* __restrict__ ingre_num,
                    const float* __restrict__ ingre_emb,
                    const short* __restrict__ W1t,   // [64][64] bf16
                    const float* __restrict__ v,
                    const float* __restrict__ ws_base,
                    float* __restrict__ ws_ia) {
  __shared__ float sc_lds[4][32];
  const int t = threadIdx.x, wave = t >> 6, lane = t & 63;
  const int lr = lane & 15, lk = lane >> 4;
  bf16x8 wf[4][2];
#pragma unroll
  for (int wt = 0; wt < 4; ++wt)
#pragma unroll
    for (int ks = 0; ks < 2; ++ks)
      wf[wt][ks] = *reinterpret_cast<const bf16x8*>(
          W1t + (16 * wt + lr) * 64 + ks * 32 + lk * 8);
  float vv[4];
#pragma unroll
  for (int wt = 0; wt < 4; ++wt) vv[wt] = v[16 * wt + lr];
  const int b0 = blockIdx.x * 16 + wave * 4;
#pragma unroll 1
  for (int bi = 0; bi < 4; ++bi) {
    const int b = b0 + bi;
    const int n1 = 16 + lr;
    const int gi0 = ingre_input[b * NN + lr];
    const int gi1 = ingre_input[b * NN + ((n1 < NN) ? n1 : 0)];
    bf16x8 a0[2], a1[2];
#pragma unroll
    for (int ks = 0; ks < 2; ++ks) {
      const float4* p0 = reinterpret_cast<const float4*>(
          ingre_emb + (size_t)gi0 * 64 + ks * 32 + lk * 8);
      a0[ks] = pack8(p0[0], p0[1]);
      const float4* p1 = reinterpret_cast<const float4*>(
          ingre_emb + (size_t)gi1 * 64 + ks * 32 + lk * 8);
      a1[ks] = pack8(p1[0], p1[1]);
    }
    f32x4 acc[2][4];
#pragma unroll
    for (int nt = 0; nt < 2; ++nt)
#pragma unroll
      for (int wt = 0; wt < 4; ++wt) acc[nt][wt] = (f32x4){0.f, 0.f, 0.f, 0.f};
#pragma unroll
    for (int ks = 0; ks < 2; ++ks)
#pragma unroll
      for (int wt = 0; wt < 4; ++wt) {
        acc[0][wt] = __builtin_amdgcn_mfma_f32_16x16x32_bf16(a0[ks], wf[wt][ks], acc[0][wt], 0, 0, 0);
        acc[1][wt] = __builtin_amdgcn_mfma_f32_16x16x32_bf16(a1[ks], wf[wt][ks], acc[1][wt], 0, 0, 0);
      }
    float basew[4];
#pragma unroll
    for (int wt = 0; wt < 4; ++wt) basew[wt] = ws_base[(size_t)b * 64 + 16 * wt + lr];
    float sp[2][4];
#pragma unroll
    for (int nt = 0; nt < 2; ++nt)
#pragma unroll
      for (int r = 0; r < 4; ++r) {
        float s = 0.f;
#pragma unroll
        for (int wt = 0; wt < 4; ++wt) {
          float x = acc[nt][wt][r] + basew[wt];
          s = fmaf(fast_tanh(x), vv[wt], s);
        }
        sp[nt][r] = s;
      }
#pragma unroll
    for (int off = 1; off < 16; off <<= 1)
#pragma unroll
      for (int nt = 0; nt < 2; ++nt)
#pragma unroll
        for (int r = 0; r < 4; ++r) sp[nt][r] += __shfl_xor(sp[nt][r], off, 64);
    if (lr == 0) {
#pragma unroll
      for (int r = 0; r < 4; ++r) {
        sc_lds[wave][4 * lk + r] = sp[0][r];
        sc_lds[wave][16 + 4 * lk + r] = sp[1][r];
      }
    }
    asm volatile("s_waitcnt lgkmcnt(0)" ::: "memory");
    float scn[NN];
#pragma unroll
    for (int q = 0; q < 5; ++q) {
      float4 s4 = *reinterpret_cast<const float4*>(&sc_lds[wave][4 * q]);
      scn[4 * q + 0] = s4.x; scn[4 * q + 1] = s4.y;
      scn[4 * q + 2] = s4.z; scn[4 * q + 3] = s4.w;
    }
    asm volatile("s_waitcnt lgkmcnt(0)" ::: "memory");
    const int num = ingre_num[b];
    float m = -3e38f;
#pragma unroll
    for (int n = 0; n < NN; ++n) {
      scn[n] = (n < num) ? scn[n] : -1e12f;
      m = fmaxf(m, scn[n]);
    }
    float ev[NN], ssum = 0.f;
#pragma unroll
    for (int n = 0; n < NN; ++n) {
      ev[n] = __expf(scn[n] - m);
      ssum += ev[n];
    }
    const float inv = __fdividef(1.f, ssum);
    float qv[NN];
#pragma unroll
    for (int n = 0; n < NN; ++n) {
      const int gi = ingre_input[b * NN + n];
      qv[n] = ingre_emb[(size_t)gi * 64 + lane];
    }
    float ia = 0.f;
#pragma unroll
    for (int n = 0; n < NN; ++n) ia = fmaf(ev[n], qv[n], ia);
    ws_ia[(size_t)b * 64 + lane] = ia * inv;
  }
}

// ---------------- Kernel B2: component scores -> flat [3B] ----------------
__global__ __launch_bounds__(256, 4)
void com_score_kernel(const int* __restrict__ user_input,
                      const int* __restrict__ item_input,
                      const float* __restrict__ user_emb,
                      const float* __restrict__ item_emb,
                      const float* __restrict__ Wc,    // [128][64]
                      const float* __restrict__ Wcb,   // [64]
                      const float* __restrict__ bat,   // [64]
                      const float* __restrict__ vc,    // [64]
                      const float* __restrict__ ws_img,
                      const float* __restrict__ ws_ia,
                      float* __restrict__ ws_flat) {
  __shared__ float Wclds[128 * 64];
  __shared__ float x_s[4][4][64];
  const int t = threadIdx.x;
  for (int i = t; i < 128 * 64 / 4; i += 256)
    reinterpret_cast<float4*>(Wclds)[i] = reinterpret_cast<const float4*>(Wc)[i];
  __syncthreads();
  const int wave = t >> 6, lane = t & 63;
  const float bb = Wcb[lane] + bat[lane];
  const float vcl = vc[lane];
  const int b0 = blockIdx.x * 16 + wave * 4;
#pragma unroll 1
  for (int bi = 0; bi < 4; ++bi) {
    const int b = b0 + bi;
    const int u = user_input[b];
    const int it = item_input[b];
    x_s[wave][0][lane] = user_emb[(size_t)u * 64 + lane];
    x_s[wave][1][lane] = item_emb[(size_t)it * 64 + lane];
    x_s[wave][2][lane] = ws_ia[(size_t)b * 64 + lane];
    x_s[wave][3][lane] = ws_img[(size_t)b * 64 + lane];
    asm volatile("s_waitcnt lgkmcnt(0)" ::: "memory");
    const float4* u4 = reinterpret_cast<const float4*>(&x_s[wave][0][0]);
    float up = 0.f;
#pragma unroll
    for (int d0 = 0; d0 < 16; ++d0) {
      float4 q = u4[d0];
      int d = d0 * 4;
      up = fmaf(q.x, Wclds[(d + 0) * 64 + lane],
           fmaf(q.y, Wclds[(d + 1) * 64 + lane],
           fmaf(q.z, Wclds[(d + 2) * 64 + lane],
           fmaf(q.w, Wclds[(d + 3) * 64 + lane], up))));
    }
    float sc[3];
#pragma unroll
    for (int c = 0; c < 3; ++c) {
      const float4* y4 = reinterpret_cast<const float4*>(&x_s[wave][1 + c][0]);
      float s = bb + up;
#pragma unroll
      for (int d0 = 0; d0 < 16; ++d0) {
        float4 q = y4[d0];
        int d = 64 + d0 * 4;
        s = fmaf(q.x, Wclds[(d + 0) * 64 + lane],
            fmaf(q.y, Wclds[(d + 1) * 64 + lane],
            fmaf(q.z, Wclds[(d + 2) * 64 + lane],
            fmaf(q.w, Wclds[(d + 3) * 64 + lane], s))));
      }
      sc[c] = waveReduceSum(fast_tanh(s) * vcl);
    }
    if (lane == 0) {
      ws_flat[b] = sc[0];
      ws_flat[BB + b] = sc[1];
      ws_flat[2 * BB + b] = sc[2];
    }
    asm volatile("s_waitcnt lgkmcnt(0)" ::: "memory");
  }
}

// ---------------- Kernel C: head. scores[i][j] = flat[3i+j] ----------------
__global__ __launch_bounds__(256, 3)
void head_kernel(const int* __restrict__ user_input,
                 const int* __restrict__ item_input,
                 const float* __restrict__ user_emb,
                 const float* __restrict__ item_emb,
                 const float* __restrict__ Wcat,   // [192][64]
                 const float* __restrict__ Wcatb,  // [64]
                 const float* __restrict__ bcat,   // [64]
                 const float* __restrict__ hw,     // [64]
                 const float* __restrict__ hb,     // [1]
                 const float* __restrict__ ws_img,
                 const float* __restrict__ ws_ia,
                 const float* __restrict__ ws_flat,
                 float* __restrict__ out) {
  __shared__ float Wlds[192 * 64];
  __shared__ float ue_s[4][64];
  __shared__ float itt_s[4][64];
  const int t = threadIdx.x;
  for (int i = t; i < 192 * 64 / 4; i += 256)
    reinterpret_cast<float4*>(Wlds)[i] = reinterpret_cast<const float4*>(Wcat)[i];
  __syncthreads();
  const int wave = t >> 6, lane = t & 63;
  const float bb = Wcatb[lane] + bcat[lane];
  const float hwl = hw[lane];
  const float hbv = hb[0];
  const int b0 = blockIdx.x * 16 + wave * 4;
#pragma unroll 1
  for (int bi = 0; bi < 4; ++bi) {
    const int b = b0 + bi;
    const float s0 = ws_flat[3 * b + 0];
    const float s1 = ws_flat[3 * b + 1];
    const float s2 = ws_flat[3 * b + 2];
    const float m = fmaxf(s0, fmaxf(s1, s2));
    const float e0 = __expf(s0 - m), e1 = __expf(s1 - m), e2 = __expf(s2 - m);
    const float inv = 1.0f / (e0 + e1 + e2);
    const int u = user_input[b];
    const int it = item_input[b];
    const float uev = user_emb[(size_t)u * 64 + lane];
    const float itt = (e0 * item_emb[(size_t)it * 64 + lane] +
                       e1 * ws_ia[(size_t)b * 64 + lane] +
                       e2 * ws_img[(size_t)b * 64 + lane]) * inv;
    ue_s[wave][lane] = uev;
    itt_s[wave][lane] = itt;
    asm volatile("s_waitcnt lgkmcnt(0)" ::: "memory");
    const float4* u4 = reinterpret_cast<const float4*>(&ue_s[wave][0]);
    const float4* i4 = reinterpret_cast<const float4*>(&itt_s[wave][0]);
    float h = bb;
#pragma unroll
    for (int d0 = 0; d0 < 16; ++d0) {
      float4 uu = u4[d0];
      float4 ii = i4[d0];
      int d = d0 * 4;
      h = fmaf(uu.x, Wlds[(d + 0) * 64 + lane], h);
      h = fmaf(ii.x, Wlds[(64 + d + 0) * 64 + lane], h);
      h = fmaf(uu.x * ii.x, Wlds[(128 + d + 0) * 64 + lane], h);
      h = fmaf(uu.y, Wlds[(d + 1) * 64 + lane], h);
      h = fmaf(ii.y, Wlds[(64 + d + 1) * 64 + lane], h);
      h = fmaf(uu.y * ii.y, Wlds[(128 + d + 1) * 64 + lane], h);
      h = fmaf(uu.z, Wlds[(d + 2) * 64 + lane], h);
      h = fmaf(ii.z, Wlds[(64 + d + 2) * 64 + lane], h);
      h = fmaf(uu.z * ii.z, Wlds[(128 + d + 2) * 64 + lane], h);
      h = fmaf(uu.w, Wlds[(d + 3) * 64 + lane], h);
      h = fmaf(ii.w, Wlds[(64 + d + 3) * 64 + lane], h);
      h = fmaf(uu.w * ii.w, Wlds[(128 + d + 3) * 64 + lane], h);
    }
    h = fmaxf(h, 0.f) * hwl;
    float o = waveReduceSum(h);
    if (lane == 0) out[b] = o + hbv;
    asm volatile("s_waitcnt lgkmcnt(0)" ::: "memory");
  }
}

extern "C" void kernel_launch(void* const* d_in, const int* in_sizes, int n_in,
                              void* d_out, int out_size, void* d_ws, size_t ws_size,
                              hipStream_t stream) {
  (void)in_sizes; (void)n_in; (void)out_size; (void)ws_size;
  const int* user_input = (const int*)d_in[0];
  const int* item_input = (const int*)d_in[1];
  const int* ingre_input = (const int*)d_in[2];
  const float* image_input = (const float*)d_in[3];
  const int* ingre_num = (const int*)d_in[4];
  const float* user_emb = (const float*)d_in[5];
  const float* item_emb = (const float*)d_in[6];
  const float* ingre_emb = (const float*)d_in[7];
  const float* W_image_w = (const float*)d_in[8];
  const float* W_image_b = (const float*)d_in[9];
  const float* b_image = (const float*)d_in[10];
  const float* W_concat_w = (const float*)d_in[11];
  const float* W_concat_b = (const float*)d_in[12];
  const float* b_concat = (const float*)d_in[13];
  const float* h_w = (const float*)d_in[14];
  const float* h_b = (const float*)d_in[15];
  const float* W_att_ingre_w = (const float*)d_in[16];
  const float* W_att_ingre_b = (const float*)d_in[17];
  const float* b_att_ingre = (const float*)d_in[18];
  const float* v = (const float*)d_in[19];
  const float* W_att_com_w = (const float*)d_in[20];
  const float* W_att_com_b = (const float*)d_in[21];
  const float* b_att_com = (const float*)d_in[22];
  const float* v_c = (const float*)d_in[23];

  float* ws = (float*)d_ws;
  float* ws_img = ws;                              // [B*64] f32
  float* ws_ia = ws + (size_t)BB * 64;             // [B*64] f32
  float* ws_base = ws + (size_t)2 * BB * 64;       // [B*64] f32
  float* ws_flat = ws + (size_t)3 * BB * 64;       // [3B] f32
  short* Wt_hi = (short*)(ws + (size_t)3 * BB * 64 + 3 * BB);   // [64*2048] bf16
  short* Wt_lo = Wt_hi + (size_t)64 * IMGK;                     // [64*2048] bf16
  short* W1t = Wt_lo + (size_t)64 * IMGK;                       // [64*64] bf16
  float* pp = (float*)(W1t + 64 * 64);             // [8][B*64] f32 partials
  float* out = (float*)d_out;

  prep_kernel<<<(IMGK * 64 + 64 * 64 + 255) / 256, 256, 0, stream>>>(
      W_image_w, W_att_ingre_w, Wt_hi, Wt_lo, W1t);
  img_gemm_mfma<<<2048, 256, 0, stream>>>(image_input, Wt_hi, Wt_lo, pp);
  img_combine<<<BB * 64 / 4 / 256, 256, 0, stream>>>(pp, W_image_b, b_image, ws_img);
  base_kernel<<<BB / 16, 256, 0, stream>>>(user_input, user_emb, ws_img,
                                           W_att_ingre_w, W_att_ingre_b, b_att_ingre,
                                           ws_base);
  ingre_att_mfma<<<BB / 16, 256, 0, stream>>>(ingre_input, ingre_num, ingre_emb,
                                              W1t, v, ws_base, ws_ia);
  com_score_kernel<<<BB / 16, 256, 0, stream>>>(user_input, item_input, user_emb, item_emb,
                                                W_att_com_w, W_att_com_b, b_att_com, v_c,
                                                ws_img, ws_ia, ws_flat);
  head_kernel<<<BB / 16, 256, 0, stream>>>(user_input, item_input, user_emb, item_emb,
                                           W_concat_w, W_concat_b, b_concat, h_w, h_b,
                                           ws_img, ws_ia, ws_flat, out);
}

// Round 9
// 168.391 us; speedup vs baseline: 1.2213x; 1.0148x over previous
//
#include <hip/hip_runtime.h>

#define BB 16384
#define NN 20
#define DD 64
#define IMGK 2048

using bf16x8 = __attribute__((ext_vector_type(8))) short;
using f32x4  = __attribute__((ext_vector_type(4))) float;

__device__ __forceinline__ float waveReduceSum(float x) {
#pragma unroll
  for (int off = 32; off > 0; off >>= 1) x += __shfl_xor(x, off, 64);
  return x;
}

__device__ __forceinline__ float fast_tanh(float x) {
  float e = __expf(2.f * x);
  return 1.f - __fdividef(2.f, e + 1.f);
}

__device__ __forceinline__ short f2bf(float f) {
  union { float f; unsigned u; } c; c.f = f;
  unsigned r = c.u + 0x7fffu + ((c.u >> 16) & 1u);
  return (short)(r >> 16);
}
__device__ __forceinline__ float bf2f(short s) {
  union { unsigned u; float f; } c; c.u = ((unsigned)(unsigned short)s) << 16;
  return c.f;
}

__device__ __forceinline__ unsigned cvt_pk_bf16(float lo, float hi) {
  unsigned r;
  asm("v_cvt_pk_bf16_f32 %0, %1, %2" : "=v"(r) : "v"(lo), "v"(hi));
  return r;
}

__device__ __forceinline__ bf16x8 pack8(float4 a, float4 b) {
  union { unsigned u[4]; bf16x8 v; } r;
  r.u[0] = cvt_pk_bf16(a.x, a.y);
  r.u[1] = cvt_pk_bf16(a.z, a.w);
  r.u[2] = cvt_pk_bf16(b.x, b.y);
  r.u[3] = cvt_pk_bf16(b.z, b.w);
  return r.v;
}

// truncation pack: top 16 bits of (a,b) -> one u32. Pure VALU.
__device__ __forceinline__ unsigned pack_hi(float a, float b) {
  unsigned ua = __float_as_uint(a), ub = __float_as_uint(b);
  return (ub & 0xffff0000u) | (ua >> 16);
}
__device__ __forceinline__ float trunc_bf(float a) {
  return __uint_as_float(__float_as_uint(a) & 0xffff0000u);
}

// ---------------- prep: transpose + split weights to bf16 ----------------
__global__ __launch_bounds__(256)
void prep_kernel(const float* __restrict__ Wimg, const float* __restrict__ W1,
                 short* __restrict__ Wt_hi, short* __restrict__ Wt_lo,
                 short* __restrict__ W1t) {
  int i = blockIdx.x * 256 + threadIdx.x;
  if (i < IMGK * 64) {
    int k = i >> 6, n = i & 63;
    float f = Wimg[i];
    short h = f2bf(f);
    Wt_hi[n * IMGK + k] = h;
    Wt_lo[n * IMGK + k] = f2bf(f - bf2f(h));
  } else if (i < IMGK * 64 + 64 * 64) {
    int j = i - IMGK * 64;
    int k = j >> 6, n = j & 63;
    W1t[n * 64 + k] = f2bf(W1[j]);
  }
}

// ---------------- Kernel A: img GEMM, 16-way K-split, barrier-free ----------------
// 4096 waves: wave gw -> kq = gw&15 (fixed 128-wide K-slice, W hi+lo in 128 VGPR),
// row-block rgb = gw>>4 (64 rows, processed as 4 chunks of 16). No LDS, no barriers.
__global__ __launch_bounds__(256, 2)
void img_gemm_mfma(const float* __restrict__ img_in,
                   const short* __restrict__ Wt_hi,
                   const short* __restrict__ Wt_lo,
                   float* __restrict__ pp) {
  const int t = threadIdx.x;
  const int wave = t >> 6, lane = t & 63;
  const int lr = lane & 15, lk = lane >> 4;
  const int gw = blockIdx.x * 4 + wave;
  const int kq = gw & 15, rgb = gw >> 4;
  const int k0 = kq * 128;
  float* pout = pp + (size_t)kq * BB * 64;

  // W fragments: loop-invariant, register-resident (32 x b128 = 128 VGPR)
  bf16x8 wh[4][4], wl[4][4];
#pragma unroll
  for (int ks = 0; ks < 4; ++ks)
#pragma unroll
    for (int tt = 0; tt < 4; ++tt) {
      wh[ks][tt] = *reinterpret_cast<const bf16x8*>(
          Wt_hi + (size_t)(16 * tt + lr) * IMGK + k0 + ks * 32 + lk * 8);
      wl[ks][tt] = *reinterpret_cast<const bf16x8*>(
          Wt_lo + (size_t)(16 * tt + lr) * IMGK + k0 + ks * 32 + lk * 8);
    }

#pragma unroll 1
  for (int c = 0; c < 4; ++c) {
    const int r0 = rgb * 64 + c * 16;
    const float* ar = img_in + (size_t)(r0 + lr) * IMGK + k0 + lk * 8;
    // cluster all 8 A-loads of this chunk, pin them above the compute
    float4 A[4][2];
#pragma unroll
    for (int ks = 0; ks < 4; ++ks) {
      A[ks][0] = *reinterpret_cast<const float4*>(ar + ks * 32);
      A[ks][1] = *reinterpret_cast<const float4*>(ar + ks * 32 + 4);
    }
    __builtin_amdgcn_sched_barrier(0);
    f32x4 aHH[4], aER[4];
#pragma unroll
    for (int tt = 0; tt < 4; ++tt) {
      aHH[tt] = (f32x4){0.f, 0.f, 0.f, 0.f};
      aER[tt] = (f32x4){0.f, 0.f, 0.f, 0.f};
    }
#pragma unroll
    for (int ks = 0; ks < 4; ++ks) {
      float4 va = A[ks][0], vb = A[ks][1];
      union { unsigned u[4]; bf16x8 v; } hi, lo;
      hi.u[0] = pack_hi(va.x, va.y);
      hi.u[1] = pack_hi(va.z, va.w);
      hi.u[2] = pack_hi(vb.x, vb.y);
      hi.u[3] = pack_hi(vb.z, vb.w);
      lo.u[0] = pack_hi(va.x - trunc_bf(va.x), va.y - trunc_bf(va.y));
      lo.u[1] = pack_hi(va.z - trunc_bf(va.z), va.w - trunc_bf(va.w));
      lo.u[2] = pack_hi(vb.x - trunc_bf(vb.x), vb.y - trunc_bf(vb.y));
      lo.u[3] = pack_hi(vb.z - trunc_bf(vb.z), vb.w - trunc_bf(vb.w));
#pragma unroll
      for (int tt = 0; tt < 4; ++tt) {
        aHH[tt] = __builtin_amdgcn_mfma_f32_16x16x32_bf16(hi.v, wh[ks][tt], aHH[tt], 0, 0, 0);
        aER[tt] = __builtin_amdgcn_mfma_f32_16x16x32_bf16(hi.v, wl[ks][tt], aER[tt], 0, 0, 0);
        aER[tt] = __builtin_amdgcn_mfma_f32_16x16x32_bf16(lo.v, wh[ks][tt], aER[tt], 0, 0, 0);
      }
    }
    // direct partial store: rows r0+4lk+r, col 16tt+lr (lane-contiguous 64B segments)
#pragma unroll
    for (int tt = 0; tt < 4; ++tt)
#pragma unroll
      for (int r = 0; r < 4; ++r)
        pout[(size_t)(r0 + 4 * lk + r) * 64 + 16 * tt + lr] = aHH[tt][r] + aER[tt][r];
  }
}

// ---------------- combine 16 partials + bias, fused with base ----------------
// ws_img = sum(pp) + Wb + bimg ; ws_base = [ue|img] @ Wi[64:192] + Wib + bai
__global__ __launch_bounds__(256, 4)
void combine_base(const int* __restrict__ user_input,
                  const float* __restrict__ user_emb,
                  const float* __restrict__ pp,
                  const float* __restrict__ Wb, const float* __restrict__ bimg,
                  const float* __restrict__ Wi,    // [192][64]
                  const float* __restrict__ Wib,   // [64]
                  const float* __restrict__ bai,   // [64]
                  float* __restrict__ ws_img,
                  float* __restrict__ ws_base) {
  __shared__ float W_s[128 * 64];
  __shared__ float x_s[4][128];
  const int t = threadIdx.x;
  for (int i = t; i < 128 * 64 / 4; i += 256)
    reinterpret_cast<float4*>(W_s)[i] =
        reinterpret_cast<const float4*>(Wi + 64 * 64)[i];
  __syncthreads();
  const int wave = t >> 6, lane = t & 63;
  const float bbi = Wb[lane] + bimg[lane];
  const float bbb = Wib[lane] + bai[lane];
  const int b0 = blockIdx.x * 16 + wave * 4;
#pragma unroll 1
  for (int bi = 0; bi < 4; ++bi) {
    const int b = b0 + bi;
    float s = bbi;
#pragma unroll
    for (int kq = 0; kq < 16; ++kq)
      s += pp[(size_t)kq * BB * 64 + (size_t)b * 64 + lane];
    const int u = user_input[b];
    ws_img[(size_t)b * 64 + lane] = s;
    x_s[wave][lane] = user_emb[(size_t)u * 64 + lane];
    x_s[wave][64 + lane] = s;
    asm volatile("s_waitcnt lgkmcnt(0)" ::: "memory");
    float acc = bbb;
    const float4* x4 = reinterpret_cast<const float4*>(&x_s[wave][0]);
#pragma unroll
    for (int d0 = 0; d0 < 32; ++d0) {
      float4 q = x4[d0];
      int d = d0 * 4;
      acc = fmaf(q.x, W_s[(d + 0) * 64 + lane],
            fmaf(q.y, W_s[(d + 1) * 64 + lane],
            fmaf(q.z, W_s[(d + 2) * 64 + lane],
            fmaf(q.w, W_s[(d + 3) * 64 + lane], acc))));
    }
    ws_base[(size_t)b * 64 + lane] = acc;
    asm volatile("s_waitcnt lgkmcnt(0)" ::: "memory");
  }
}

// ---------------- Kernel B1: ingredient attention, 1 batch/wave, single gather ----------------
__global__ __launch_bounds__(256, 3)
void ingre_att_mfma(const int* __restrict__ ingre_input,
                    const int* __restrict__ ingre_num,
                    const float* __restrict__ ingre_emb,
                    const short* __restrict__ W1t,   // [64][64] bf16
                    const float* __restrict__ v,
                    const float* __restrict__ ws_base,
                    float* __restrict__ ws_ia) {
  __shared__ float qe_s[4][NN][68];
  __shared__ float sc_lds[4][32];
  const int t = threadIdx.x, wave = t >> 6, lane = t & 63;
  const int lr = lane & 15, lk = lane >> 4;
  bf16x8 wf[4][2];
#pragma unroll
  for (int wt = 0; wt < 4; ++wt)
#pragma unroll
    for (int ks = 0; ks < 2; ++ks)
      wf[wt][ks] = *reinterpret_cast<const bf16x8*>(
          W1t + (16 * wt + lr) * 64 + ks * 32 + lk * 8);
  float vv[4];
#pragma unroll
  for (int wt = 0; wt < 4; ++wt) vv[wt] = v[16 * wt + lr];
  const int b = blockIdx.x * 4 + wave;

  // single gather: 20 qe rows into wave-private LDS (col layout, padded)
#pragma unroll
  for (int n = 0; n < NN; ++n) {
    const int gi = ingre_input[b * NN + n];
    qe_s[wave][n][lane] = ingre_emb[(size_t)gi * 64 + lane];
  }
  asm volatile("s_waitcnt lgkmcnt(0)" ::: "memory");

  // A-frags from LDS (rows lr and 16+lr)
  const int r1 = (16 + lr < NN) ? 16 + lr : 0;
  bf16x8 a0[2], a1[2];
#pragma unroll
  for (int ks = 0; ks < 2; ++ks) {
    const float4* p0 = reinterpret_cast<const float4*>(&qe_s[wave][lr][ks * 32 + lk * 8]);
    a0[ks] = pack8(p0[0], p0[1]);
    const float4* p1 = reinterpret_cast<const float4*>(&qe_s[wave][r1][ks * 32 + lk * 8]);
    a1[ks] = pack8(p1[0], p1[1]);
  }
  f32x4 acc[2][4];
#pragma unroll
  for (int nt = 0; nt < 2; ++nt)
#pragma unroll
    for (int wt = 0; wt < 4; ++wt) acc[nt][wt] = (f32x4){0.f, 0.f, 0.f, 0.f};
#pragma unroll
  for (int ks = 0; ks < 2; ++ks)
#pragma unroll
    for (int wt = 0; wt < 4; ++wt) {
      acc[0][wt] = __builtin_amdgcn_mfma_f32_16x16x32_bf16(a0[ks], wf[wt][ks], acc[0][wt], 0, 0, 0);
      acc[1][wt] = __builtin_amdgcn_mfma_f32_16x16x32_bf16(a1[ks], wf[wt][ks], acc[1][wt], 0, 0, 0);
    }
  float basew[4];
#pragma unroll
  for (int wt = 0; wt < 4; ++wt) basew[wt] = ws_base[(size_t)b * 64 + 16 * wt + lr];
  float sp[2][4];
#pragma unroll
  for (int nt = 0; nt < 2; ++nt)
#pragma unroll
    for (int r = 0; r < 4; ++r) {
      float s = 0.f;
#pragma unroll
      for (int wt = 0; wt < 4; ++wt) {
        float x = acc[nt][wt][r] + basew[wt];
        s = fmaf(fast_tanh(x), vv[wt], s);
      }
      sp[nt][r] = s;
    }
#pragma unroll
  for (int off = 1; off < 16; off <<= 1)
#pragma unroll
    for (int nt = 0; nt < 2; ++nt)
#pragma unroll
      for (int r = 0; r < 4; ++r) sp[nt][r] += __shfl_xor(sp[nt][r], off, 64);
  if (lr == 0) {
#pragma unroll
    for (int r = 0; r < 4; ++r) {
      sc_lds[wave][4 * lk + r] = sp[0][r];
      sc_lds[wave][16 + 4 * lk + r] = sp[1][r];
    }
  }
  asm volatile("s_waitcnt lgkmcnt(0)" ::: "memory");
  float scn[NN];
#pragma unroll
  for (int q = 0; q < 5; ++q) {
    float4 s4 = *reinterpret_cast<const float4*>(&sc_lds[wave][4 * q]);
    scn[4 * q + 0] = s4.x; scn[4 * q + 1] = s4.y;
    scn[4 * q + 2] = s4.z; scn[4 * q + 3] = s4.w;
  }
  asm volatile("s_waitcnt lgkmcnt(0)" ::: "memory");
  const int num = ingre_num[b];
  float m = -3e38f;
#pragma unroll
  for (int n = 0; n < NN; ++n) {
    scn[n] = (n < num) ? scn[n] : -1e12f;
    m = fmaxf(m, scn[n]);
  }
  float ssum = 0.f;
#pragma unroll
  for (int n = 0; n < NN; ++n) {
    scn[n] = __expf(scn[n] - m);
    ssum += scn[n];
  }
  const float inv = __fdividef(1.f, ssum);
  float ia = 0.f;
#pragma unroll
  for (int n = 0; n < NN; ++n) ia = fmaf(scn[n], qe_s[wave][n][lane], ia);
  ws_ia[(size_t)b * 64 + lane] = ia * inv;
}

// ---------------- Kernel B2: component scores -> flat [3B] ----------------
__global__ __launch_bounds__(256, 4)
void com_score_kernel(const int* __restrict__ user_input,
                      const int* __restrict__ item_input,
                      const float* __restrict__ user_emb,
                      const float* __restrict__ item_emb,
                      const float* __restrict__ Wc,    // [128][64]
                      const float* __restrict__ Wcb,   // [64]
                      const float* __restrict__ bat,   // [64]
                      const float* __restrict__ vc,    // [64]
                      const float* __restrict__ ws_img,
                      const float* __restrict__ ws_ia,
                      float* __restrict__ ws_flat) {
  __shared__ float Wclds[128 * 64];
  __shared__ float x_s[4][4][64];
  const int t = threadIdx.x;
  for (int i = t; i < 128 * 64 / 4; i += 256)
    reinterpret_cast<float4*>(Wclds)[i] = reinterpret_cast<const float4*>(Wc)[i];
  __syncthreads();
  const int wave = t >> 6, lane = t & 63;
  const float bb = Wcb[lane] + bat[lane];
  const float vcl = vc[lane];
  const int b0 = blockIdx.x * 16 + wave * 4;
#pragma unroll 1
  for (int bi = 0; bi < 4; ++bi) {
    const int b = b0 + bi;
    const int u = user_input[b];
    const int it = item_input[b];
    x_s[wave][0][lane] = user_emb[(size_t)u * 64 + lane];
    x_s[wave][1][lane] = item_emb[(size_t)it * 64 + lane];
    x_s[wave][2][lane] = ws_ia[(size_t)b * 64 + lane];
    x_s[wave][3][lane] = ws_img[(size_t)b * 64 + lane];
    asm volatile("s_waitcnt lgkmcnt(0)" ::: "memory");
    const float4* u4 = reinterpret_cast<const float4*>(&x_s[wave][0][0]);
    float up = 0.f;
#pragma unroll
    for (int d0 = 0; d0 < 16; ++d0) {
      float4 q = u4[d0];
      int d = d0 * 4;
      up = fmaf(q.x, Wclds[(d + 0) * 64 + lane],
           fmaf(q.y, Wclds[(d + 1) * 64 + lane],
           fmaf(q.z, Wclds[(d + 2) * 64 + lane],
           fmaf(q.w, Wclds[(d + 3) * 64 + lane], up))));
    }
    float sc[3];
#pragma unroll
    for (int c = 0; c < 3; ++c) {
      const float4* y4 = reinterpret_cast<const float4*>(&x_s[wave][1 + c][0]);
      float s = bb + up;
#pragma unroll
      for (int d0 = 0; d0 < 16; ++d0) {
        float4 q = y4[d0];
        int d = 64 + d0 * 4;
        s = fmaf(q.x, Wclds[(d + 0) * 64 + lane],
            fmaf(q.y, Wclds[(d + 1) * 64 + lane],
            fmaf(q.z, Wclds[(d + 2) * 64 + lane],
            fmaf(q.w, Wclds[(d + 3) * 64 + lane], s))));
      }
      sc[c] = waveReduceSum(fast_tanh(s) * vcl);
    }
    if (lane == 0) {
      ws_flat[b] = sc[0];
      ws_flat[BB + b] = sc[1];
      ws_flat[2 * BB + b] = sc[2];
    }
    asm volatile("s_waitcnt lgkmcnt(0)" ::: "memory");
  }
}

// ---------------- Kernel C: head. scores[i][j] = flat[3i+j] ----------------
__global__ __launch_bounds__(256, 3)
void head_kernel(const int* __restrict__ user_input,
                 const int* __restrict__ item_input,
                 const float* __restrict__ user_emb,
                 const float* __restrict__ item_emb,
                 const float* __restrict__ Wcat,   // [192][64]
                 const float* __restrict__ Wcatb,  // [64]
                 const float* __restrict__ bcat,   // [64]
                 const float* __restrict__ hw,     // [64]
                 const float* __restrict__ hb,     // [1]
                 const float* __restrict__ ws_img,
                 const float* __restrict__ ws_ia,
                 const float* __restrict__ ws_flat,
                 float* __restrict__ out) {
  __shared__ float Wlds[192 * 64];
  __shared__ float ue_s[4][64];
  __shared__ float itt_s[4][64];
  const int t = threadIdx.x;
  for (int i = t; i < 192 * 64 / 4; i += 256)
    reinterpret_cast<float4*>(Wlds)[i] = reinterpret_cast<const float4*>(Wcat)[i];
  __syncthreads();
  const int wave = t >> 6, lane = t & 63;
  const float bb = Wcatb[lane] + bcat[lane];
  const float hwl = hw[lane];
  const float hbv = hb[0];
  const int b0 = blockIdx.x * 16 + wave * 4;
#pragma unroll 1
  for (int bi = 0; bi < 4; ++bi) {
    const int b = b0 + bi;
    const float s0 = ws_flat[3 * b + 0];
    const float s1 = ws_flat[3 * b + 1];
    const float s2 = ws_flat[3 * b + 2];
    const float m = fmaxf(s0, fmaxf(s1, s2));
    const float e0 = __expf(s0 - m), e1 = __expf(s1 - m), e2 = __expf(s2 - m);
    const float inv = 1.0f / (e0 + e1 + e2);
    const int u = user_input[b];
    const int it = item_input[b];
    const float uev = user_emb[(size_t)u * 64 + lane];
    const float itt = (e0 * item_emb[(size_t)it * 64 + lane] +
                       e1 * ws_ia[(size_t)b * 64 + lane] +
                       e2 * ws_img[(size_t)b * 64 + lane]) * inv;
    ue_s[wave][lane] = uev;
    itt_s[wave][lane] = itt;
    asm volatile("s_waitcnt lgkmcnt(0)" ::: "memory");
    const float4* u4 = reinterpret_cast<const float4*>(&ue_s[wave][0]);
    const float4* i4 = reinterpret_cast<const float4*>(&itt_s[wave][0]);
    float h = bb;
#pragma unroll
    for (int d0 = 0; d0 < 16; ++d0) {
      float4 uu = u4[d0];
      float4 ii = i4[d0];
      int d = d0 * 4;
      h = fmaf(uu.x, Wlds[(d + 0) * 64 + lane], h);
      h = fmaf(ii.x, Wlds[(64 + d + 0) * 64 + lane], h);
      h = fmaf(uu.x * ii.x, Wlds[(128 + d + 0) * 64 + lane], h);
      h = fmaf(uu.y, Wlds[(d + 1) * 64 + lane], h);
      h = fmaf(ii.y, Wlds[(64 + d + 1) * 64 + lane], h);
      h = fmaf(uu.y * ii.y, Wlds[(128 + d + 1) * 64 + lane], h);
      h = fmaf(uu.z, Wlds[(d + 2) * 64 + lane], h);
      h = fmaf(ii.z, Wlds[(64 + d + 2) * 64 + lane], h);
      h = fmaf(uu.z * ii.z, Wlds[(128 + d + 2) * 64 + lane], h);
      h = fmaf(uu.w, Wlds[(d + 3) * 64 + lane], h);
      h = fmaf(ii.w, Wlds[(64 + d + 3) * 64 + lane], h);
      h = fmaf(uu.w * ii.w, Wlds[(128 + d + 3) * 64 + lane], h);
    }
    h = fmaxf(h, 0.f) * hwl;
    float o = waveReduceSum(h);
    if (lane == 0) out[b] = o + hbv;
    asm volatile("s_waitcnt lgkmcnt(0)" ::: "memory");
  }
}

extern "C" void kernel_launch(void* const* d_in, const int* in_sizes, int n_in,
                              void* d_out, int out_size, void* d_ws, size_t ws_size,
                              hipStream_t stream) {
  (void)in_sizes; (void)n_in; (void)out_size; (void)ws_size;
  const int* user_input = (const int*)d_in[0];
  const int* item_input = (const int*)d_in[1];
  const int* ingre_input = (const int*)d_in[2];
  const float* image_input = (const float*)d_in[3];
  const int* ingre_num = (const int*)d_in[4];
  const float* user_emb = (const float*)d_in[5];
  const float* item_emb = (const float*)d_in[6];
  const float* ingre_emb = (const float*)d_in[7];
  const float* W_image_w = (const float*)d_in[8];
  const float* W_image_b = (const float*)d_in[9];
  const float* b_image = (const float*)d_in[10];
  const float* W_concat_w = (const float*)d_in[11];
  const float* W_concat_b = (const float*)d_in[12];
  const float* b_concat = (const float*)d_in[13];
  const float* h_w = (const float*)d_in[14];
  const float* h_b = (const float*)d_in[15];
  const float* W_att_ingre_w = (const float*)d_in[16];
  const float* W_att_ingre_b = (const float*)d_in[17];
  const float* b_att_ingre = (const float*)d_in[18];
  const float* v = (const float*)d_in[19];
  const float* W_att_com_w = (const float*)d_in[20];
  const float* W_att_com_b = (const float*)d_in[21];
  const float* b_att_com = (const float*)d_in[22];
  const float* v_c = (const float*)d_in[23];

  float* ws = (float*)d_ws;
  float* ws_img = ws;                              // [B*64] f32
  float* ws_ia = ws + (size_t)BB * 64;             // [B*64] f32
  float* ws_base = ws + (size_t)2 * BB * 64;       // [B*64] f32
  float* ws_flat = ws + (size_t)3 * BB * 64;       // [3B] f32
  short* Wt_hi = (short*)(ws + (size_t)3 * BB * 64 + 3 * BB);   // [64*2048] bf16
  short* Wt_lo = Wt_hi + (size_t)64 * IMGK;                     // [64*2048] bf16
  short* W1t = Wt_lo + (size_t)64 * IMGK;                       // [64*64] bf16
  float* pp = (float*)(W1t + 64 * 64);             // [16][B*64] f32 partials
  float* out = (float*)d_out;

  prep_kernel<<<(IMGK * 64 + 64 * 64 + 255) / 256, 256, 0, stream>>>(
      W_image_w, W_att_ingre_w, Wt_hi, Wt_lo, W1t);
  img_gemm_mfma<<<1024, 256, 0, stream>>>(image_input, Wt_hi, Wt_lo, pp);
  combine_base<<<BB / 16, 256, 0, stream>>>(user_input, user_emb, pp,
                                            W_image_b, b_image,
                                            W_att_ingre_w, W_att_ingre_b, b_att_ingre,
                                            ws_img, ws_base);
  ingre_att_mfma<<<BB / 4, 256, 0, stream>>>(ingre_input, ingre_num, ingre_emb,
                                             W1t, v, ws_base, ws_ia);
  com_score_kernel<<<BB / 16, 256, 0, stream>>>(user_input, item_input, user_emb, item_emb,
                                                W_att_com_w, W_att_com_b, b_att_com, v_c,
                                                ws_img, ws_ia, ws_flat);
  head_kernel<<<BB / 16, 256, 0, stream>>>(user_input, item_input, user_emb, item_emb,
                                           W_concat_w, W_concat_b, b_concat, h_w, h_b,
                                           ws_img, ws_ia, ws_flat, out);
}

// Round 10
// 159.494 us; speedup vs baseline: 1.2895x; 1.0558x over previous
//
#include <hip/hip_runtime.h>

#define BB 16384
#define NN 20
#define DD 64
#define IMGK 2048

using bf16x8 = __attribute__((ext_vector_type(8))) short;
using f32x4  = __attribute__((ext_vector_type(4))) float;

__device__ __forceinline__ float waveReduceSum(float x) {
#pragma unroll
  for (int off = 32; off > 0; off >>= 1) x += __shfl_xor(x, off, 64);
  return x;
}

__device__ __forceinline__ float fast_tanh(float x) {
  float e = __expf(2.f * x);
  return 1.f - __fdividef(2.f, e + 1.f);
}

__device__ __forceinline__ short f2bf(float f) {
  union { float f; unsigned u; } c; c.f = f;
  unsigned r = c.u + 0x7fffu + ((c.u >> 16) & 1u);
  return (short)(r >> 16);
}
__device__ __forceinline__ float bf2f(short s) {
  union { unsigned u; float f; } c; c.u = ((unsigned)(unsigned short)s) << 16;
  return c.f;
}

__device__ __forceinline__ unsigned cvt_pk_bf16(float lo, float hi) {
  unsigned r;
  asm("v_cvt_pk_bf16_f32 %0, %1, %2" : "=v"(r) : "v"(lo), "v"(hi));
  return r;
}

__device__ __forceinline__ bf16x8 pack8(float4 a, float4 b) {
  union { unsigned u[4]; bf16x8 v; } r;
  r.u[0] = cvt_pk_bf16(a.x, a.y);
  r.u[1] = cvt_pk_bf16(a.z, a.w);
  r.u[2] = cvt_pk_bf16(b.x, b.y);
  r.u[3] = cvt_pk_bf16(b.z, b.w);
  return r.v;
}

// truncation pack: top 16 bits of (a,b) -> one u32. Pure VALU.
__device__ __forceinline__ unsigned pack_hi(float a, float b) {
  unsigned ua = __float_as_uint(a), ub = __float_as_uint(b);
  return (ub & 0xffff0000u) | (ua >> 16);
}
__device__ __forceinline__ float trunc_bf(float a) {
  return __uint_as_float(__float_as_uint(a) & 0xffff0000u);
}

// ---------------- prep: W_image -> MFMA-fragment-ordered bf16 hi/lo; W1 -> W1t ----------------
// Wf short layout: [kq(16)][ks(4)][tt(4)][h(2)][lane(64)][j(8)]
//   value = {hi,lo}(W_image[k][n]),  k = kq*128+ks*32+(lane>>4)*8+j,  n = 16*tt+(lane&15)
__global__ __launch_bounds__(256)
void prep_kernel(const float* __restrict__ Wimg, const float* __restrict__ W1,
                 short* __restrict__ Wf, short* __restrict__ W1t) {
  int i = blockIdx.x * 256 + threadIdx.x;
  if (i < 32768) {
    const int lane = i & 63;
    const int h = (i >> 6) & 1;
    const int tt = (i >> 7) & 3;
    const int ks = (i >> 9) & 3;
    const int kq = i >> 11;
    const int n = 16 * tt + (lane & 15);
    const int kb = kq * 128 + ks * 32 + (lane >> 4) * 8;
    union { short s[8]; bf16x8 v; } o;
#pragma unroll
    for (int j = 0; j < 8; ++j) {
      float f = Wimg[(size_t)(kb + j) * 64 + n];
      short hi = f2bf(f);
      o.s[j] = h == 0 ? hi : f2bf(f - bf2f(hi));
    }
    reinterpret_cast<bf16x8*>(Wf)[i] = o.v;
  } else if (i < 32768 + 64 * 64) {
    int j = i - 32768;
    int k = j >> 6, n = j & 63;
    W1t[n * 64 + k] = f2bf(W1[j]);
  }
}

// ---------------- Kernel A: img GEMM — W slice in LDS (un-sinkable), A streamed ----------------
// grid 1024 = 64 row-groups(256 rows) x 16 kq. Block stages its kq's 32KB W-frag slice to LDS
// once; each wave: 4 chunks of 16 rows; per chunk 8 clustered A-float4s + 32 ds_read_b128 +
// 48 MFMA + 16 partial stores. No W in registers -> scheduler can't reload it.
__global__ __launch_bounds__(256, 3)
void img_gemm_mfma(const float* __restrict__ img_in,
                   const short* __restrict__ Wf,
                   float* __restrict__ pp) {
  __shared__ short wlds[16384];   // 32 KB: [ks][tt][h][lane][8]
  const int t = threadIdx.x;
  const int wave = t >> 6, lane = t & 63;
  const int lr = lane & 15, lk = lane >> 4;
  const int kq = blockIdx.x & 15, rg = blockIdx.x >> 4;
  float* pout = pp + (size_t)kq * BB * 64;

  {
    const bf16x8* src = reinterpret_cast<const bf16x8*>(Wf + (size_t)kq * 16384);
    bf16x8* dst = reinterpret_cast<bf16x8*>(wlds);
    for (int i = t; i < 2048; i += 256) dst[i] = src[i];
  }
  __syncthreads();
  const bf16x8* wp = reinterpret_cast<const bf16x8*>(wlds);

#pragma unroll 1
  for (int c = 0; c < 4; ++c) {
    const int r0 = rg * 256 + wave * 64 + c * 16;
    const float* ar = img_in + (size_t)(r0 + lr) * IMGK + kq * 128 + lk * 8;
    // cluster the chunk's 8 A-loads (the only global reads), pin above compute
    float4 A[4][2];
#pragma unroll
    for (int ks = 0; ks < 4; ++ks) {
      A[ks][0] = *reinterpret_cast<const float4*>(ar + ks * 32);
      A[ks][1] = *reinterpret_cast<const float4*>(ar + ks * 32 + 4);
    }
    __builtin_amdgcn_sched_barrier(0);
    f32x4 aHH[4], aER[4];
#pragma unroll
    for (int tt = 0; tt < 4; ++tt) {
      aHH[tt] = (f32x4){0.f, 0.f, 0.f, 0.f};
      aER[tt] = (f32x4){0.f, 0.f, 0.f, 0.f};
    }
#pragma unroll
    for (int ks = 0; ks < 4; ++ks) {
      float4 va = A[ks][0], vb = A[ks][1];
      union { unsigned u[4]; bf16x8 v; } hi, lo;
      hi.u[0] = pack_hi(va.x, va.y);
      hi.u[1] = pack_hi(va.z, va.w);
      hi.u[2] = pack_hi(vb.x, vb.y);
      hi.u[3] = pack_hi(vb.z, vb.w);
      lo.u[0] = pack_hi(va.x - trunc_bf(va.x), va.y - trunc_bf(va.y));
      lo.u[1] = pack_hi(va.z - trunc_bf(va.z), va.w - trunc_bf(va.w));
      lo.u[2] = pack_hi(vb.x - trunc_bf(vb.x), vb.y - trunc_bf(vb.y));
      lo.u[3] = pack_hi(vb.z - trunc_bf(vb.z), vb.w - trunc_bf(vb.w));
#pragma unroll
      for (int tt = 0; tt < 4; ++tt) {
        bf16x8 wh = wp[((ks * 4 + tt) * 2 + 0) * 64 + lane];
        bf16x8 wl = wp[((ks * 4 + tt) * 2 + 1) * 64 + lane];
        aHH[tt] = __builtin_amdgcn_mfma_f32_16x16x32_bf16(hi.v, wh, aHH[tt], 0, 0, 0);
        aER[tt] = __builtin_amdgcn_mfma_f32_16x16x32_bf16(hi.v, wl, aER[tt], 0, 0, 0);
        aER[tt] = __builtin_amdgcn_mfma_f32_16x16x32_bf16(lo.v, wh, aER[tt], 0, 0, 0);
      }
    }
#pragma unroll
    for (int tt = 0; tt < 4; ++tt)
#pragma unroll
      for (int r = 0; r < 4; ++r)
        pout[(size_t)(r0 + 4 * lk + r) * 64 + 16 * tt + lr] = aHH[tt][r] + aER[tt][r];
  }
}

// ---------------- combine 16 partials + bias, fused with base ----------------
__global__ __launch_bounds__(256, 4)
void combine_base(const int* __restrict__ user_input,
                  const float* __restrict__ user_emb,
                  const float* __restrict__ pp,
                  const float* __restrict__ Wb, const float* __restrict__ bimg,
                  const float* __restrict__ Wi,    // [192][64]
                  const float* __restrict__ Wib,   // [64]
                  const float* __restrict__ bai,   // [64]
                  float* __restrict__ ws_img,
                  float* __restrict__ ws_base) {
  __shared__ float W_s[128 * 64];
  __shared__ float x_s[4][128];
  const int t = threadIdx.x;
  for (int i = t; i < 128 * 64 / 4; i += 256)
    reinterpret_cast<float4*>(W_s)[i] =
        reinterpret_cast<const float4*>(Wi + 64 * 64)[i];
  __syncthreads();
  const int wave = t >> 6, lane = t & 63;
  const float bbi = Wb[lane] + bimg[lane];
  const float bbb = Wib[lane] + bai[lane];
  const int b0 = blockIdx.x * 16 + wave * 4;
#pragma unroll 1
  for (int bi = 0; bi < 4; ++bi) {
    const int b = b0 + bi;
    float s = bbi;
#pragma unroll
    for (int kq = 0; kq < 16; ++kq)
      s += pp[(size_t)kq * BB * 64 + (size_t)b * 64 + lane];
    const int u = user_input[b];
    ws_img[(size_t)b * 64 + lane] = s;
    x_s[wave][lane] = user_emb[(size_t)u * 64 + lane];
    x_s[wave][64 + lane] = s;
    asm volatile("s_waitcnt lgkmcnt(0)" ::: "memory");
    float acc = bbb;
    const float4* x4 = reinterpret_cast<const float4*>(&x_s[wave][0]);
#pragma unroll
    for (int d0 = 0; d0 < 32; ++d0) {
      float4 q = x4[d0];
      int d = d0 * 4;
      acc = fmaf(q.x, W_s[(d + 0) * 64 + lane],
            fmaf(q.y, W_s[(d + 1) * 64 + lane],
            fmaf(q.z, W_s[(d + 2) * 64 + lane],
            fmaf(q.w, W_s[(d + 3) * 64 + lane], acc))));
    }
    ws_base[(size_t)b * 64 + lane] = acc;
    asm volatile("s_waitcnt lgkmcnt(0)" ::: "memory");
  }
}

// ---------------- Kernel B1: ingredient attention, 1 batch/wave, single gather ----------------
__global__ __launch_bounds__(256, 3)
void ingre_att_mfma(const int* __restrict__ ingre_input,
                    const int* __restrict__ ingre_num,
                    const float* __restrict__ ingre_emb,
                    const short* __restrict__ W1t,   // [64][64] bf16
                    const float* __restrict__ v,
                    const float* __restrict__ ws_base,
                    float* __restrict__ ws_ia) {
  __shared__ float qe_s[4][NN][68];
  __shared__ float sc_lds[4][32];
  const int t = threadIdx.x, wave = t >> 6, lane = t & 63;
  const int lr = lane & 15, lk = lane >> 4;
  bf16x8 wf[4][2];
#pragma unroll
  for (int wt = 0; wt < 4; ++wt)
#pragma unroll
    for (int ks = 0; ks < 2; ++ks)
      wf[wt][ks] = *reinterpret_cast<const bf16x8*>(
          W1t + (16 * wt + lr) * 64 + ks * 32 + lk * 8);
  float vv[4];
#pragma unroll
  for (int wt = 0; wt < 4; ++wt) vv[wt] = v[16 * wt + lr];
  const int b = blockIdx.x * 4 + wave;

#pragma unroll
  for (int n = 0; n < NN; ++n) {
    const int gi = ingre_input[b * NN + n];
    qe_s[wave][n][lane] = ingre_emb[(size_t)gi * 64 + lane];
  }
  asm volatile("s_waitcnt lgkmcnt(0)" ::: "memory");

  const int r1 = (16 + lr < NN) ? 16 + lr : 0;
  bf16x8 a0[2], a1[2];
#pragma unroll
  for (int ks = 0; ks < 2; ++ks) {
    const float4* p0 = reinterpret_cast<const float4*>(&qe_s[wave][lr][ks * 32 + lk * 8]);
    a0[ks] = pack8(p0[0], p0[1]);
    const float4* p1 = reinterpret_cast<const float4*>(&qe_s[wave][r1][ks * 32 + lk * 8]);
    a1[ks] = pack8(p1[0], p1[1]);
  }
  f32x4 acc[2][4];
#pragma unroll
  for (int nt = 0; nt < 2; ++nt)
#pragma unroll
    for (int wt = 0; wt < 4; ++wt) acc[nt][wt] = (f32x4){0.f, 0.f, 0.f, 0.f};
#pragma unroll
  for (int ks = 0; ks < 2; ++ks)
#pragma unroll
    for (int wt = 0; wt < 4; ++wt) {
      acc[0][wt] = __builtin_amdgcn_mfma_f32_16x16x32_bf16(a0[ks], wf[wt][ks], acc[0][wt], 0, 0, 0);
      acc[1][wt] = __builtin_amdgcn_mfma_f32_16x16x32_bf16(a1[ks], wf[wt][ks], acc[1][wt], 0, 0, 0);
    }
  float basew[4];
#pragma unroll
  for (int wt = 0; wt < 4; ++wt) basew[wt] = ws_base[(size_t)b * 64 + 16 * wt + lr];
  float sp[2][4];
#pragma unroll
  for (int nt = 0; nt < 2; ++nt)
#pragma unroll
    for (int r = 0; r < 4; ++r) {
      float s = 0.f;
#pragma unroll
      for (int wt = 0; wt < 4; ++wt) {
        float x = acc[nt][wt][r] + basew[wt];
        s = fmaf(fast_tanh(x), vv[wt], s);
      }
      sp[nt][r] = s;
    }
#pragma unroll
  for (int off = 1; off < 16; off <<= 1)
#pragma unroll
    for (int nt = 0; nt < 2; ++nt)
#pragma unroll
      for (int r = 0; r < 4; ++r) sp[nt][r] += __shfl_xor(sp[nt][r], off, 64);
  if (lr == 0) {
#pragma unroll
    for (int r = 0; r < 4; ++r) {
      sc_lds[wave][4 * lk + r] = sp[0][r];
      sc_lds[wave][16 + 4 * lk + r] = sp[1][r];
    }
  }
  asm volatile("s_waitcnt lgkmcnt(0)" ::: "memory");
  float scn[NN];
#pragma unroll
  for (int q = 0; q < 5; ++q) {
    float4 s4 = *reinterpret_cast<const float4*>(&sc_lds[wave][4 * q]);
    scn[4 * q + 0] = s4.x; scn[4 * q + 1] = s4.y;
    scn[4 * q + 2] = s4.z; scn[4 * q + 3] = s4.w;
  }
  asm volatile("s_waitcnt lgkmcnt(0)" ::: "memory");
  const int num = ingre_num[b];
  float m = -3e38f;
#pragma unroll
  for (int n = 0; n < NN; ++n) {
    scn[n] = (n < num) ? scn[n] : -1e12f;
    m = fmaxf(m, scn[n]);
  }
  float ssum = 0.f;
#pragma unroll
  for (int n = 0; n < NN; ++n) {
    scn[n] = __expf(scn[n] - m);
    ssum += scn[n];
  }
  const float inv = __fdividef(1.f, ssum);
  float ia = 0.f;
#pragma unroll
  for (int n = 0; n < NN; ++n) ia = fmaf(scn[n], qe_s[wave][n][lane], ia);
  ws_ia[(size_t)b * 64 + lane] = ia * inv;
}

// ---------------- Kernel B2: component scores -> flat [3B] ----------------
__global__ __launch_bounds__(256, 4)
void com_score_kernel(const int* __restrict__ user_input,
                      const int* __restrict__ item_input,
                      const float* __restrict__ user_emb,
                      const float* __restrict__ item_emb,
                      const float* __restrict__ Wc,    // [128][64]
                      const float* __restrict__ Wcb,   // [64]
                      const float* __restrict__ bat,   // [64]
                      const float* __restrict__ vc,    // [64]
                      const float* __restrict__ ws_img,
                      const float* __restrict__ ws_ia,
                      float* __restrict__ ws_flat) {
  __shared__ float Wclds[128 * 64];
  __shared__ float x_s[4][4][64];
  const int t = threadIdx.x;
  for (int i = t; i < 128 * 64 / 4; i += 256)
    reinterpret_cast<float4*>(Wclds)[i] = reinterpret_cast<const float4*>(Wc)[i];
  __syncthreads();
  const int wave = t >> 6, lane = t & 63;
  const float bb = Wcb[lane] + bat[lane];
  const float vcl = vc[lane];
  const int b0 = blockIdx.x * 16 + wave * 4;
#pragma unroll 1
  for (int bi = 0; bi < 4; ++bi) {
    const int b = b0 + bi;
    const int u = user_input[b];
    const int it = item_input[b];
    x_s[wave][0][lane] = user_emb[(size_t)u * 64 + lane];
    x_s[wave][1][lane] = item_emb[(size_t)it * 64 + lane];
    x_s[wave][2][lane] = ws_ia[(size_t)b * 64 + lane];
    x_s[wave][3][lane] = ws_img[(size_t)b * 64 + lane];
    asm volatile("s_waitcnt lgkmcnt(0)" ::: "memory");
    const float4* u4 = reinterpret_cast<const float4*>(&x_s[wave][0][0]);
    float up = 0.f;
#pragma unroll
    for (int d0 = 0; d0 < 16; ++d0) {
      float4 q = u4[d0];
      int d = d0 * 4;
      up = fmaf(q.x, Wclds[(d + 0) * 64 + lane],
           fmaf(q.y, Wclds[(d + 1) * 64 + lane],
           fmaf(q.z, Wclds[(d + 2) * 64 + lane],
           fmaf(q.w, Wclds[(d + 3) * 64 + lane], up))));
    }
    float sc[3];
#pragma unroll
    for (int c = 0; c < 3; ++c) {
      const float4* y4 = reinterpret_cast<const float4*>(&x_s[wave][1 + c][0]);
      float s = bb + up;
#pragma unroll
      for (int d0 = 0; d0 < 16; ++d0) {
        float4 q = y4[d0];
        int d = 64 + d0 * 4;
        s = fmaf(q.x, Wclds[(d + 0) * 64 + lane],
            fmaf(q.y, Wclds[(d + 1) * 64 + lane],
            fmaf(q.z, Wclds[(d + 2) * 64 + lane],
            fmaf(q.w, Wclds[(d + 3) * 64 + lane], s))));
      }
      sc[c] = waveReduceSum(fast_tanh(s) * vcl);
    }
    if (lane == 0) {
      ws_flat[b] = sc[0];
      ws_flat[BB + b] = sc[1];
      ws_flat[2 * BB + b] = sc[2];
    }
    asm volatile("s_waitcnt lgkmcnt(0)" ::: "memory");
  }
}

// ---------------- Kernel C: head. scores[i][j] = flat[3i+j] ----------------
__global__ __launch_bounds__(256, 3)
void head_kernel(const int* __restrict__ user_input,
                 const int* __restrict__ item_input,
                 const float* __restrict__ user_emb,
                 const float* __restrict__ item_emb,
                 const float* __restrict__ Wcat,   // [192][64]
                 const float* __restrict__ Wcatb,  // [64]
                 const float* __restrict__ bcat,   // [64]
                 const float* __restrict__ hw,     // [64]
                 const float* __restrict__ hb,     // [1]
                 const float* __restrict__ ws_img,
                 const float* __restrict__ ws_ia,
                 const float* __restrict__ ws_flat,
                 float* __restrict__ out) {
  __shared__ float Wlds[192 * 64];
  __shared__ float ue_s[4][64];
  __shared__ float itt_s[4][64];
  const int t = threadIdx.x;
  for (int i = t; i < 192 * 64 / 4; i += 256)
    reinterpret_cast<float4*>(Wlds)[i] = reinterpret_cast<const float4*>(Wcat)[i];
  __syncthreads();
  const int wave = t >> 6, lane = t & 63;
  const float bb = Wcatb[lane] + bcat[lane];
  const float hwl = hw[lane];
  const float hbv = hb[0];
  const int b0 = blockIdx.x * 16 + wave * 4;
#pragma unroll 1
  for (int bi = 0; bi < 4; ++bi) {
    const int b = b0 + bi;
    const float s0 = ws_flat[3 * b + 0];
    const float s1 = ws_flat[3 * b + 1];
    const float s2 = ws_flat[3 * b + 2];
    const float m = fmaxf(s0, fmaxf(s1, s2));
    const float e0 = __expf(s0 - m), e1 = __expf(s1 - m), e2 = __expf(s2 - m);
    const float inv = 1.0f / (e0 + e1 + e2);
    const int u = user_input[b];
    const int it = item_input[b];
    const float uev = user_emb[(size_t)u * 64 + lane];
    const float itt = (e0 * item_emb[(size_t)it * 64 + lane] +
                       e1 * ws_ia[(size_t)b * 64 + lane] +
                       e2 * ws_img[(size_t)b * 64 + lane]) * inv;
    ue_s[wave][lane] = uev;
    itt_s[wave][lane] = itt;
    asm volatile("s_waitcnt lgkmcnt(0)" ::: "memory");
    const float4* u4 = reinterpret_cast<const float4*>(&ue_s[wave][0]);
    const float4* i4 = reinterpret_cast<const float4*>(&itt_s[wave][0]);
    float h = bb;
#pragma unroll
    for (int d0 = 0; d0 < 16; ++d0) {
      float4 uu = u4[d0];
      float4 ii = i4[d0];
      int d = d0 * 4;
      h = fmaf(uu.x, Wlds[(d + 0) * 64 + lane], h);
      h = fmaf(ii.x, Wlds[(64 + d + 0) * 64 + lane], h);
      h = fmaf(uu.x * ii.x, Wlds[(128 + d + 0) * 64 + lane], h);
      h = fmaf(uu.y, Wlds[(d + 1) * 64 + lane], h);
      h = fmaf(ii.y, Wlds[(64 + d + 1) * 64 + lane], h);
      h = fmaf(uu.y * ii.y, Wlds[(128 + d + 1) * 64 + lane], h);
      h = fmaf(uu.z, Wlds[(d + 2) * 64 + lane], h);
      h = fmaf(ii.z, Wlds[(64 + d + 2) * 64 + lane], h);
      h = fmaf(uu.z * ii.z, Wlds[(128 + d + 2) * 64 + lane], h);
      h = fmaf(uu.w, Wlds[(d + 3) * 64 + lane], h);
      h = fmaf(ii.w, Wlds[(64 + d + 3) * 64 + lane], h);
      h = fmaf(uu.w * ii.w, Wlds[(128 + d + 3) * 64 + lane], h);
    }
    h = fmaxf(h, 0.f) * hwl;
    float o = waveReduceSum(h);
    if (lane == 0) out[b] = o + hbv;
    asm volatile("s_waitcnt lgkmcnt(0)" ::: "memory");
  }
}

extern "C" void kernel_launch(void* const* d_in, const int* in_sizes, int n_in,
                              void* d_out, int out_size, void* d_ws, size_t ws_size,
                              hipStream_t stream) {
  (void)in_sizes; (void)n_in; (void)out_size; (void)ws_size;
  const int* user_input = (const int*)d_in[0];
  const int* item_input = (const int*)d_in[1];
  const int* ingre_input = (const int*)d_in[2];
  const float* image_input = (const float*)d_in[3];
  const int* ingre_num = (const int*)d_in[4];
  const float* user_emb = (const float*)d_in[5];
  const float* item_emb = (const float*)d_in[6];
  const float* ingre_emb = (const float*)d_in[7];
  const float* W_image_w = (const float*)d_in[8];
  const float* W_image_b = (const float*)d_in[9];
  const float* b_image = (const float*)d_in[10];
  const float* W_concat_w = (const float*)d_in[11];
  const float* W_concat_b = (const float*)d_in[12];
  const float* b_concat = (const float*)d_in[13];
  const float* h_w = (const float*)d_in[14];
  const float* h_b = (const float*)d_in[15];
  const float* W_att_ingre_w = (const float*)d_in[16];
  const float* W_att_ingre_b = (const float*)d_in[17];
  const float* b_att_ingre = (const float*)d_in[18];
  const float* v = (const float*)d_in[19];
  const float* W_att_com_w = (const float*)d_in[20];
  const float* W_att_com_b = (const float*)d_in[21];
  const float* b_att_com = (const float*)d_in[22];
  const float* v_c = (const float*)d_in[23];

  float* ws = (float*)d_ws;
  float* ws_img = ws;                              // [B*64] f32
  float* ws_ia = ws + (size_t)BB * 64;             // [B*64] f32
  float* ws_base = ws + (size_t)2 * BB * 64;       // [B*64] f32
  float* ws_flat = ws + (size_t)3 * BB * 64;       // [3B] f32
  short* Wf = (short*)(ws + (size_t)3 * BB * 64 + 3 * BB);      // [16*16384] bf16 frag-ordered
  short* W1t = Wf + (size_t)16 * 16384;                         // [64*64] bf16
  float* pp = (float*)(W1t + 64 * 64);             // [16][B*64] f32 partials
  float* out = (float*)d_out;

  prep_kernel<<<(32768 + 64 * 64 + 255) / 256, 256, 0, stream>>>(
      W_image_w, W_att_ingre_w, Wf, W1t);
  img_gemm_mfma<<<1024, 256, 0, stream>>>(image_input, Wf, pp);
  combine_base<<<BB / 16, 256, 0, stream>>>(user_input, user_emb, pp,
                                            W_image_b, b_image,
                                            W_att_ingre_w, W_att_ingre_b, b_att_ingre,
                                            ws_img, ws_base);
  ingre_att_mfma<<<BB / 4, 256, 0, stream>>>(ingre_input, ingre_num, ingre_emb,
                                             W1t, v, ws_base, ws_ia);
  com_score_kernel<<<BB / 16, 256, 0, stream>>>(user_input, item_input, user_emb, item_emb,
                                                W_att_com_w, W_att_com_b, b_att_com, v_c,
                                                ws_img, ws_ia, ws_flat);
  head_kernel<<<BB / 16, 256, 0, stream>>>(user_input, item_input, user_emb, item_emb,
                                           W_concat_w, W_concat_b, b_concat, h_w, h_b,
                                           ws_img, ws_ia, ws_flat, out);
}

// Round 11
// 155.659 us; speedup vs baseline: 1.3212x; 1.0246x over previous
//
#include <hip/hip_runtime.h>
#include <hip/hip_fp16.h>

#define BB 16384
#define NN 20
#define DD 64
#define IMGK 2048

using bf16x8 = __attribute__((ext_vector_type(8))) short;
using f32x4  = __attribute__((ext_vector_type(4))) float;

__device__ __forceinline__ float waveReduceSum(float x) {
#pragma unroll
  for (int off = 32; off > 0; off >>= 1) x += __shfl_xor(x, off, 64);
  return x;
}

__device__ __forceinline__ float fast_tanh(float x) {
  float e = __expf(2.f * x);
  return 1.f - __fdividef(2.f, e + 1.f);
}

__device__ __forceinline__ short f2bf(float f) {
  union { float f; unsigned u; } c; c.f = f;
  unsigned r = c.u + 0x7fffu + ((c.u >> 16) & 1u);
  return (short)(r >> 16);
}
__device__ __forceinline__ float bf2f(short s) {
  union { unsigned u; float f; } c; c.u = ((unsigned)(unsigned short)s) << 16;
  return c.f;
}

__device__ __forceinline__ unsigned cvt_pk_bf16(float lo, float hi) {
  unsigned r;
  asm("v_cvt_pk_bf16_f32 %0, %1, %2" : "=v"(r) : "v"(lo), "v"(hi));
  return r;
}

__device__ __forceinline__ bf16x8 pack8(float4 a, float4 b) {
  union { unsigned u[4]; bf16x8 v; } r;
  r.u[0] = cvt_pk_bf16(a.x, a.y);
  r.u[1] = cvt_pk_bf16(a.z, a.w);
  r.u[2] = cvt_pk_bf16(b.x, b.y);
  r.u[3] = cvt_pk_bf16(b.z, b.w);
  return r.v;
}

// truncation pack: top 16 bits of (a,b) -> one u32. Pure VALU.
__device__ __forceinline__ unsigned pack_hi(float a, float b) {
  unsigned ua = __float_as_uint(a), ub = __float_as_uint(b);
  return (ub & 0xffff0000u) | (ua >> 16);
}
__device__ __forceinline__ float trunc_bf(float a) {
  return __uint_as_float(__float_as_uint(a) & 0xffff0000u);
}

// ---------------- prep: W_image -> MFMA-fragment-ordered bf16 hi/lo; W1 -> W1t ----------------
__global__ __launch_bounds__(256)
void prep_kernel(const float* __restrict__ Wimg, const float* __restrict__ W1,
                 short* __restrict__ Wf, short* __restrict__ W1t) {
  int i = blockIdx.x * 256 + threadIdx.x;
  if (i < 32768) {
    const int lane = i & 63;
    const int h = (i >> 6) & 1;
    const int tt = (i >> 7) & 3;
    const int ks = (i >> 9) & 3;
    const int kq = i >> 11;
    const int n = 16 * tt + (lane & 15);
    const int kb = kq * 128 + ks * 32 + (lane >> 4) * 8;
    union { short s[8]; bf16x8 v; } o;
#pragma unroll
    for (int j = 0; j < 8; ++j) {
      float f = Wimg[(size_t)(kb + j) * 64 + n];
      short hi = f2bf(f);
      o.s[j] = h == 0 ? hi : f2bf(f - bf2f(hi));
    }
    reinterpret_cast<bf16x8*>(Wf)[i] = o.v;
  } else if (i < 32768 + 64 * 64) {
    int j = i - 32768;
    int k = j >> 6, n = j & 63;
    W1t[n * 64 + k] = f2bf(W1[j]);
  }
}

// ---------------- Kernel A: img GEMM — W slice in LDS, fp16 partials ----------------
__global__ __launch_bounds__(256, 3)
void img_gemm_mfma(const float* __restrict__ img_in,
                   const short* __restrict__ Wf,
                   __half* __restrict__ pp) {
  __shared__ short wlds[16384];   // 32 KB
  const int t = threadIdx.x;
  const int wave = t >> 6, lane = t & 63;
  const int lr = lane & 15, lk = lane >> 4;
  const int kq = blockIdx.x & 15, rg = blockIdx.x >> 4;
  __half* pout = pp + (size_t)kq * BB * 64;

  {
    const bf16x8* src = reinterpret_cast<const bf16x8*>(Wf + (size_t)kq * 16384);
    bf16x8* dst = reinterpret_cast<bf16x8*>(wlds);
    for (int i = t; i < 2048; i += 256) dst[i] = src[i];
  }
  __syncthreads();
  const bf16x8* wp = reinterpret_cast<const bf16x8*>(wlds);

#pragma unroll 1
  for (int c = 0; c < 4; ++c) {
    const int r0 = rg * 256 + wave * 64 + c * 16;
    const float* ar = img_in + (size_t)(r0 + lr) * IMGK + kq * 128 + lk * 8;
    float4 A[4][2];
#pragma unroll
    for (int ks = 0; ks < 4; ++ks) {
      A[ks][0] = *reinterpret_cast<const float4*>(ar + ks * 32);
      A[ks][1] = *reinterpret_cast<const float4*>(ar + ks * 32 + 4);
    }
    __builtin_amdgcn_sched_barrier(0);
    f32x4 aHH[4], aER[4];
#pragma unroll
    for (int tt = 0; tt < 4; ++tt) {
      aHH[tt] = (f32x4){0.f, 0.f, 0.f, 0.f};
      aER[tt] = (f32x4){0.f, 0.f, 0.f, 0.f};
    }
#pragma unroll
    for (int ks = 0; ks < 4; ++ks) {
      float4 va = A[ks][0], vb = A[ks][1];
      union { unsigned u[4]; bf16x8 v; } hi, lo;
      hi.u[0] = pack_hi(va.x, va.y);
      hi.u[1] = pack_hi(va.z, va.w);
      hi.u[2] = pack_hi(vb.x, vb.y);
      hi.u[3] = pack_hi(vb.z, vb.w);
      lo.u[0] = pack_hi(va.x - trunc_bf(va.x), va.y - trunc_bf(va.y));
      lo.u[1] = pack_hi(va.z - trunc_bf(va.z), va.w - trunc_bf(va.w));
      lo.u[2] = pack_hi(vb.x - trunc_bf(vb.x), vb.y - trunc_bf(vb.y));
      lo.u[3] = pack_hi(vb.z - trunc_bf(vb.z), vb.w - trunc_bf(vb.w));
#pragma unroll
      for (int tt = 0; tt < 4; ++tt) {
        bf16x8 wh = wp[((ks * 4 + tt) * 2 + 0) * 64 + lane];
        bf16x8 wl = wp[((ks * 4 + tt) * 2 + 1) * 64 + lane];
        aHH[tt] = __builtin_amdgcn_mfma_f32_16x16x32_bf16(hi.v, wh, aHH[tt], 0, 0, 0);
        aER[tt] = __builtin_amdgcn_mfma_f32_16x16x32_bf16(hi.v, wl, aER[tt], 0, 0, 0);
        aER[tt] = __builtin_amdgcn_mfma_f32_16x16x32_bf16(lo.v, wh, aER[tt], 0, 0, 0);
      }
    }
#pragma unroll
    for (int tt = 0; tt < 4; ++tt)
#pragma unroll
      for (int r = 0; r < 4; ++r)
        pout[(size_t)(r0 + 4 * lk + r) * 64 + 16 * tt + lr] =
            __float2half(aHH[tt][r] + aER[tt][r]);
  }
}

// ---------------- mid: combine(img) + base + ingredient attention, fused ----------------
// 1 batch/wave, grid BB/4. base passes wave-privately through LDS (no ws_base buffer).
__global__ __launch_bounds__(256, 2)
void mid_kernel(const int* __restrict__ user_input,
                const int* __restrict__ ingre_input,
                const int* __restrict__ ingre_num,
                const float* __restrict__ user_emb,
                const float* __restrict__ ingre_emb,
                const __half* __restrict__ pp,
                const float* __restrict__ Wb, const float* __restrict__ bimg,
                const float* __restrict__ Wi,    // [192][64]
                const float* __restrict__ Wib, const float* __restrict__ bai,
                const short* __restrict__ W1t,   // [64][64] bf16
                const float* __restrict__ v,
                float* __restrict__ ws_img,
                float* __restrict__ ws_ia) {
  __shared__ float W1s[128 * 64];        // 32 KB: Wi rows 64..191
  __shared__ float qe_s[4][NN][68];      // 21.25 KB
  __shared__ float xb_s[4][128];         // 2 KB
  __shared__ float base_s[4][64];        // 1 KB
  __shared__ float sc_s[4][32];          // 0.5 KB
  const int t = threadIdx.x;
  for (int i = t; i < 128 * 64 / 4; i += 256)
    reinterpret_cast<float4*>(W1s)[i] =
        reinterpret_cast<const float4*>(Wi + 64 * 64)[i];
  const int wave = t >> 6, lane = t & 63;
  const int lr = lane & 15, lk = lane >> 4;
  const int b = blockIdx.x * 4 + wave;

  bf16x8 wf[4][2];
#pragma unroll
  for (int wt = 0; wt < 4; ++wt)
#pragma unroll
    for (int ks = 0; ks < 2; ++ks)
      wf[wt][ks] = *reinterpret_cast<const bf16x8*>(
          W1t + (16 * wt + lr) * 64 + ks * 32 + lk * 8);
  float vv[4];
#pragma unroll
  for (int wt = 0; wt < 4; ++wt) vv[wt] = v[16 * wt + lr];
  const float bbi = Wb[lane] + bimg[lane];
  const float bbb = Wib[lane] + bai[lane];

  // gather qe rows (latency overlaps following phases)
  float qv[NN];
#pragma unroll
  for (int n = 0; n < NN; ++n) {
    const int gi = ingre_input[b * NN + n];
    qv[n] = ingre_emb[(size_t)gi * 64 + lane];
  }
  // img = sum of 16 fp16 partials + bias
  float s = bbi;
#pragma unroll
  for (int kq = 0; kq < 16; ++kq)
    s += __half2float(pp[(size_t)kq * BB * 64 + (size_t)b * 64 + lane]);
  const int u = user_input[b];
  const float ue = user_emb[(size_t)u * 64 + lane];
  ws_img[(size_t)b * 64 + lane] = s;
  __syncthreads();   // W1s staged

  xb_s[wave][lane] = ue;
  xb_s[wave][64 + lane] = s;
#pragma unroll
  for (int n = 0; n < NN; ++n) qe_s[wave][n][lane] = qv[n];
  asm volatile("s_waitcnt lgkmcnt(0)" ::: "memory");

  // base[w=lane] = [ue|img] . W1s[:, lane] + bbb
  float base = bbb;
  const float4* x4 = reinterpret_cast<const float4*>(&xb_s[wave][0]);
#pragma unroll
  for (int d0 = 0; d0 < 32; ++d0) {
    float4 q = x4[d0];
    int d = d0 * 4;
    base = fmaf(q.x, W1s[(d + 0) * 64 + lane],
           fmaf(q.y, W1s[(d + 1) * 64 + lane],
           fmaf(q.z, W1s[(d + 2) * 64 + lane],
           fmaf(q.w, W1s[(d + 3) * 64 + lane], base))));
  }
  base_s[wave][lane] = base;

  // MFMA attention
  const int r1 = (16 + lr < NN) ? 16 + lr : 0;
  bf16x8 a0[2], a1[2];
#pragma unroll
  for (int ks = 0; ks < 2; ++ks) {
    const float4* p0 = reinterpret_cast<const float4*>(&qe_s[wave][lr][ks * 32 + lk * 8]);
    a0[ks] = pack8(p0[0], p0[1]);
    const float4* p1 = reinterpret_cast<const float4*>(&qe_s[wave][r1][ks * 32 + lk * 8]);
    a1[ks] = pack8(p1[0], p1[1]);
  }
  asm volatile("s_waitcnt lgkmcnt(0)" ::: "memory");
  f32x4 acc[2][4];
#pragma unroll
  for (int nt = 0; nt < 2; ++nt)
#pragma unroll
    for (int wt = 0; wt < 4; ++wt) acc[nt][wt] = (f32x4){0.f, 0.f, 0.f, 0.f};
#pragma unroll
  for (int ks = 0; ks < 2; ++ks)
#pragma unroll
    for (int wt = 0; wt < 4; ++wt) {
      acc[0][wt] = __builtin_amdgcn_mfma_f32_16x16x32_bf16(a0[ks], wf[wt][ks], acc[0][wt], 0, 0, 0);
      acc[1][wt] = __builtin_amdgcn_mfma_f32_16x16x32_bf16(a1[ks], wf[wt][ks], acc[1][wt], 0, 0, 0);
    }
  float basew[4];
#pragma unroll
  for (int wt = 0; wt < 4; ++wt) basew[wt] = base_s[wave][16 * wt + lr];
  float sp[2][4];
#pragma unroll
  for (int nt = 0; nt < 2; ++nt)
#pragma unroll
    for (int r = 0; r < 4; ++r) {
      float sv = 0.f;
#pragma unroll
      for (int wt = 0; wt < 4; ++wt) {
        float x = acc[nt][wt][r] + basew[wt];
        sv = fmaf(fast_tanh(x), vv[wt], sv);
      }
      sp[nt][r] = sv;
    }
#pragma unroll
  for (int off = 1; off < 16; off <<= 1)
#pragma unroll
    for (int nt = 0; nt < 2; ++nt)
#pragma unroll
      for (int r = 0; r < 4; ++r) sp[nt][r] += __shfl_xor(sp[nt][r], off, 64);
  if (lr == 0) {
#pragma unroll
    for (int r = 0; r < 4; ++r) {
      sc_s[wave][4 * lk + r] = sp[0][r];
      sc_s[wave][16 + 4 * lk + r] = sp[1][r];
    }
  }
  asm volatile("s_waitcnt lgkmcnt(0)" ::: "memory");
  float scn[NN];
#pragma unroll
  for (int q = 0; q < 5; ++q) {
    float4 s4 = *reinterpret_cast<const float4*>(&sc_s[wave][4 * q]);
    scn[4 * q + 0] = s4.x; scn[4 * q + 1] = s4.y;
    scn[4 * q + 2] = s4.z; scn[4 * q + 3] = s4.w;
  }
  asm volatile("s_waitcnt lgkmcnt(0)" ::: "memory");
  const int num = ingre_num[b];
  float m = -3e38f;
#pragma unroll
  for (int n = 0; n < NN; ++n) {
    scn[n] = (n < num) ? scn[n] : -1e12f;
    m = fmaxf(m, scn[n]);
  }
  float ssum = 0.f;
#pragma unroll
  for (int n = 0; n < NN; ++n) {
    scn[n] = __expf(scn[n] - m);
    ssum += scn[n];
  }
  const float inv = __fdividef(1.f, ssum);
  float ia = 0.f;
#pragma unroll
  for (int n = 0; n < NN; ++n) ia = fmaf(scn[n], qe_s[wave][n][lane], ia);
  ws_ia[(size_t)b * 64 + lane] = ia * inv;
}

// ---------------- Kernel B2: component scores -> flat [3B] ----------------
__global__ __launch_bounds__(256, 4)
void com_score_kernel(const int* __restrict__ user_input,
                      const int* __restrict__ item_input,
                      const float* __restrict__ user_emb,
                      const float* __restrict__ item_emb,
                      const float* __restrict__ Wc,    // [128][64]
                      const float* __restrict__ Wcb,   // [64]
                      const float* __restrict__ bat,   // [64]
                      const float* __restrict__ vc,    // [64]
                      const float* __restrict__ ws_img,
                      const float* __restrict__ ws_ia,
                      float* __restrict__ ws_flat) {
  __shared__ float Wclds[128 * 64];
  __shared__ float x_s[4][4][64];
  const int t = threadIdx.x;
  for (int i = t; i < 128 * 64 / 4; i += 256)
    reinterpret_cast<float4*>(Wclds)[i] = reinterpret_cast<const float4*>(Wc)[i];
  __syncthreads();
  const int wave = t >> 6, lane = t & 63;
  const float bb = Wcb[lane] + bat[lane];
  const float vcl = vc[lane];
  const int b0 = blockIdx.x * 16 + wave * 4;
#pragma unroll 1
  for (int bi = 0; bi < 4; ++bi) {
    const int b = b0 + bi;
    const int u = user_input[b];
    const int it = item_input[b];
    x_s[wave][0][lane] = user_emb[(size_t)u * 64 + lane];
    x_s[wave][1][lane] = item_emb[(size_t)it * 64 + lane];
    x_s[wave][2][lane] = ws_ia[(size_t)b * 64 + lane];
    x_s[wave][3][lane] = ws_img[(size_t)b * 64 + lane];
    asm volatile("s_waitcnt lgkmcnt(0)" ::: "memory");
    const float4* u4 = reinterpret_cast<const float4*>(&x_s[wave][0][0]);
    float up = 0.f;
#pragma unroll
    for (int d0 = 0; d0 < 16; ++d0) {
      float4 q = u4[d0];
      int d = d0 * 4;
      up = fmaf(q.x, Wclds[(d + 0) * 64 + lane],
           fmaf(q.y, Wclds[(d + 1) * 64 + lane],
           fmaf(q.z, Wclds[(d + 2) * 64 + lane],
           fmaf(q.w, Wclds[(d + 3) * 64 + lane], up))));
    }
    float sc[3];
#pragma unroll
    for (int c = 0; c < 3; ++c) {
      const float4* y4 = reinterpret_cast<const float4*>(&x_s[wave][1 + c][0]);
      float s = bb + up;
#pragma unroll
      for (int d0 = 0; d0 < 16; ++d0) {
        float4 q = y4[d0];
        int d = 64 + d0 * 4;
        s = fmaf(q.x, Wclds[(d + 0) * 64 + lane],
            fmaf(q.y, Wclds[(d + 1) * 64 + lane],
            fmaf(q.z, Wclds[(d + 2) * 64 + lane],
            fmaf(q.w, Wclds[(d + 3) * 64 + lane], s))));
      }
      sc[c] = waveReduceSum(fast_tanh(s) * vcl);
    }
    if (lane == 0) {
      ws_flat[b] = sc[0];
      ws_flat[BB + b] = sc[1];
      ws_flat[2 * BB + b] = sc[2];
    }
    asm volatile("s_waitcnt lgkmcnt(0)" ::: "memory");
  }
}

// ---------------- Kernel C: head. scores[i][j] = flat[3i+j] ----------------
__global__ __launch_bounds__(256, 3)
void head_kernel(const int* __restrict__ user_input,
                 const int* __restrict__ item_input,
                 const float* __restrict__ user_emb,
                 const float* __restrict__ item_emb,
                 const float* __restrict__ Wcat,   // [192][64]
                 const float* __restrict__ Wcatb,  // [64]
                 const float* __restrict__ bcat,   // [64]
                 const float* __restrict__ hw,     // [64]
                 const float* __restrict__ hb,     // [1]
                 const float* __restrict__ ws_img,
                 const float* __restrict__ ws_ia,
                 const float* __restrict__ ws_flat,
                 float* __restrict__ out) {
  __shared__ float Wlds[192 * 64];
  __shared__ float ue_s[4][64];
  __shared__ float itt_s[4][64];
  const int t = threadIdx.x;
  for (int i = t; i < 192 * 64 / 4; i += 256)
    reinterpret_cast<float4*>(Wlds)[i] = reinterpret_cast<const float4*>(Wcat)[i];
  __syncthreads();
  const int wave = t >> 6, lane = t & 63;
  const float bb = Wcatb[lane] + bcat[lane];
  const float hwl = hw[lane];
  const float hbv = hb[0];
  const int b0 = blockIdx.x * 16 + wave * 4;
#pragma unroll 1
  for (int bi = 0; bi < 4; ++bi) {
    const int b = b0 + bi;
    const float s0 = ws_flat[3 * b + 0];
    const float s1 = ws_flat[3 * b + 1];
    const float s2 = ws_flat[3 * b + 2];
    const float m = fmaxf(s0, fmaxf(s1, s2));
    const float e0 = __expf(s0 - m), e1 = __expf(s1 - m), e2 = __expf(s2 - m);
    const float inv = 1.0f / (e0 + e1 + e2);
    const int u = user_input[b];
    const int it = item_input[b];
    const float uev = user_emb[(size_t)u * 64 + lane];
    const float itt = (e0 * item_emb[(size_t)it * 64 + lane] +
                       e1 * ws_ia[(size_t)b * 64 + lane] +
                       e2 * ws_img[(size_t)b * 64 + lane]) * inv;
    ue_s[wave][lane] = uev;
    itt_s[wave][lane] = itt;
    asm volatile("s_waitcnt lgkmcnt(0)" ::: "memory");
    const float4* u4 = reinterpret_cast<const float4*>(&ue_s[wave][0]);
    const float4* i4 = reinterpret_cast<const float4*>(&itt_s[wave][0]);
    float h = bb;
#pragma unroll
    for (int d0 = 0; d0 < 16; ++d0) {
      float4 uu = u4[d0];
      float4 ii = i4[d0];
      int d = d0 * 4;
      h = fmaf(uu.x, Wlds[(d + 0) * 64 + lane], h);
      h = fmaf(ii.x, Wlds[(64 + d + 0) * 64 + lane], h);
      h = fmaf(uu.x * ii.x, Wlds[(128 + d + 0) * 64 + lane], h);
      h = fmaf(uu.y, Wlds[(d + 1) * 64 + lane], h);
      h = fmaf(ii.y, Wlds[(64 + d + 1) * 64 + lane], h);
      h = fmaf(uu.y * ii.y, Wlds[(128 + d + 1) * 64 + lane], h);
      h = fmaf(uu.z, Wlds[(d + 2) * 64 + lane], h);
      h = fmaf(ii.z, Wlds[(64 + d + 2) * 64 + lane], h);
      h = fmaf(uu.z * ii.z, Wlds[(128 + d + 2) * 64 + lane], h);
      h = fmaf(uu.w, Wlds[(d + 3) * 64 + lane], h);
      h = fmaf(ii.w, Wlds[(64 + d + 3) * 64 + lane], h);
      h = fmaf(uu.w * ii.w, Wlds[(128 + d + 3) * 64 + lane], h);
    }
    h = fmaxf(h, 0.f) * hwl;
    float o = waveReduceSum(h);
    if (lane == 0) out[b] = o + hbv;
    asm volatile("s_waitcnt lgkmcnt(0)" ::: "memory");
  }
}

extern "C" void kernel_launch(void* const* d_in, const int* in_sizes, int n_in,
                              void* d_out, int out_size, void* d_ws, size_t ws_size,
                              hipStream_t stream) {
  (void)in_sizes; (void)n_in; (void)out_size; (void)ws_size;
  const int* user_input = (const int*)d_in[0];
  const int* item_input = (const int*)d_in[1];
  const int* ingre_input = (const int*)d_in[2];
  const float* image_input = (const float*)d_in[3];
  const int* ingre_num = (const int*)d_in[4];
  const float* user_emb = (const float*)d_in[5];
  const float* item_emb = (const float*)d_in[6];
  const float* ingre_emb = (const float*)d_in[7];
  const float* W_image_w = (const float*)d_in[8];
  const float* W_image_b = (const float*)d_in[9];
  const float* b_image = (const float*)d_in[10];
  const float* W_concat_w = (const float*)d_in[11];
  const float* W_concat_b = (const float*)d_in[12];
  const float* b_concat = (const float*)d_in[13];
  const float* h_w = (const float*)d_in[14];
  const float* h_b = (const float*)d_in[15];
  const float* W_att_ingre_w = (const float*)d_in[16];
  const float* W_att_ingre_b = (const float*)d_in[17];
  const float* b_att_ingre = (const float*)d_in[18];
  const float* v = (const float*)d_in[19];
  const float* W_att_com_w = (const float*)d_in[20];
  const float* W_att_com_b = (const float*)d_in[21];
  const float* b_att_com = (const float*)d_in[22];
  const float* v_c = (const float*)d_in[23];

  float* ws = (float*)d_ws;
  float* ws_img = ws;                              // [B*64] f32
  float* ws_ia = ws + (size_t)BB * 64;             // [B*64] f32
  float* ws_flat = ws + (size_t)2 * BB * 64;       // [3B] f32
  short* Wf = (short*)(ws + (size_t)2 * BB * 64 + 3 * BB);      // [16*16384] bf16
  short* W1t = Wf + (size_t)16 * 16384;                         // [64*64] bf16
  __half* pp = (__half*)(W1t + 64 * 64);           // [16][B*64] fp16 partials
  float* out = (float*)d_out;

  prep_kernel<<<(32768 + 64 * 64 + 255) / 256, 256, 0, stream>>>(
      W_image_w, W_att_ingre_w, Wf, W1t);
  img_gemm_mfma<<<1024, 256, 0, stream>>>(image_input, Wf, pp);
  mid_kernel<<<BB / 4, 256, 0, stream>>>(user_input, ingre_input, ingre_num,
                                         user_emb, ingre_emb, pp,
                                         W_image_b, b_image,
                                         W_att_ingre_w, W_att_ingre_b, b_att_ingre,
                                         W1t, v, ws_img, ws_ia);
  com_score_kernel<<<BB / 16, 256, 0, stream>>>(user_input, item_input, user_emb, item_emb,
                                                W_att_com_w, W_att_com_b, b_att_com, v_c,
                                                ws_img, ws_ia, ws_flat);
  head_kernel<<<BB / 16, 256, 0, stream>>>(user_input, item_input, user_emb, item_emb,
                                           W_concat_w, W_concat_b, b_concat, h_w, h_b,
                                           ws_img, ws_ia, ws_flat, out);
}

// Round 12
// 139.935 us; speedup vs baseline: 1.4697x; 1.1124x over previous
//
#include <hip/hip_runtime.h>
#include <hip/hip_fp16.h>

#define BB 16384
#define NN 20
#define DD 64
#define IMGK 2048

using bf16x8 = __attribute__((ext_vector_type(8))) short;
using f32x4  = __attribute__((ext_vector_type(4))) float;

__device__ __forceinline__ float waveReduceSum(float x) {
#pragma unroll
  for (int off = 32; off > 0; off >>= 1) x += __shfl_xor(x, off, 64);
  return x;
}

__device__ __forceinline__ float fast_tanh(float x) {
  float e = __expf(2.f * x);
  return 1.f - __fdividef(2.f, e + 1.f);
}

__device__ __forceinline__ short f2bf(float f) {
  union { float f; unsigned u; } c; c.f = f;
  unsigned r = c.u + 0x7fffu + ((c.u >> 16) & 1u);
  return (short)(r >> 16);
}
__device__ __forceinline__ float bf2f(short s) {
  union { unsigned u; float f; } c; c.u = ((unsigned)(unsigned short)s) << 16;
  return c.f;
}

// truncation pack: top 16 bits of (a,b) -> one u32. Pure VALU.
__device__ __forceinline__ unsigned pack_hi(float a, float b) {
  unsigned ua = __float_as_uint(a), ub = __float_as_uint(b);
  return (ub & 0xffff0000u) | (ua >> 16);
}
__device__ __forceinline__ float trunc_bf(float a) {
  return __uint_as_float(__float_as_uint(a) & 0xffff0000u);
}

// ---------------- prep: Wf (img weights, frag-ordered hi/lo) + W1f (attention, frag-ordered, K=192) ----------------
__global__ __launch_bounds__(256)
void prep_kernel(const float* __restrict__ Wimg, const float* __restrict__ W1,
                 short* __restrict__ Wf, short* __restrict__ W1f) {
  int i = blockIdx.x * 256 + threadIdx.x;
  if (i < 32768) {
    const int lane = i & 63;
    const int h = (i >> 6) & 1;
    const int tt = (i >> 7) & 3;
    const int ks = (i >> 9) & 3;
    const int kq = i >> 11;
    const int n = 16 * tt + (lane & 15);
    const int kb = kq * 128 + ks * 32 + (lane >> 4) * 8;
    union { short s[8]; bf16x8 v; } o;
#pragma unroll
    for (int j = 0; j < 8; ++j) {
      float f = Wimg[(size_t)(kb + j) * 64 + n];
      short hi = f2bf(f);
      o.s[j] = h == 0 ? hi : f2bf(f - bf2f(hi));
    }
    reinterpret_cast<bf16x8*>(Wf)[i] = o.v;
  } else if (i < 32768 + 1536) {
    // W1f: [ks(6)][wt(4)][lane(64)][8] bf16 from W_att_ingre [192][64]
    const int j = i - 32768;
    const int lane = j & 63;
    const int wt = (j >> 6) & 3;
    const int ks = j >> 8;
    const int n = 16 * wt + (lane & 15);
    const int kb = ks * 32 + (lane >> 4) * 8;
    union { short s[8]; bf16x8 v; } o;
#pragma unroll
    for (int jj = 0; jj < 8; ++jj)
      o.s[jj] = f2bf(W1[(size_t)(kb + jj) * 64 + n]);
    reinterpret_cast<bf16x8*>(W1f)[j] = o.v;
  }
}

// ---------------- Kernel A: img GEMM — W slice in LDS, fp16 partials ----------------
__global__ __launch_bounds__(256, 3)
void img_gemm_mfma(const float* __restrict__ img_in,
                   const short* __restrict__ Wf,
                   __half* __restrict__ pp) {
  __shared__ short wlds[16384];   // 32 KB
  const int t = threadIdx.x;
  const int wave = t >> 6, lane = t & 63;
  const int lr = lane & 15, lk = lane >> 4;
  const int kq = blockIdx.x & 15, rg = blockIdx.x >> 4;
  __half* pout = pp + (size_t)kq * BB * 64;

  {
    const bf16x8* src = reinterpret_cast<const bf16x8*>(Wf + (size_t)kq * 16384);
    bf16x8* dst = reinterpret_cast<bf16x8*>(wlds);
    for (int i = t; i < 2048; i += 256) dst[i] = src[i];
  }
  __syncthreads();
  const bf16x8* wp = reinterpret_cast<const bf16x8*>(wlds);

#pragma unroll 1
  for (int c = 0; c < 4; ++c) {
    const int r0 = rg * 256 + wave * 64 + c * 16;
    const float* ar = img_in + (size_t)(r0 + lr) * IMGK + kq * 128 + lk * 8;
    float4 A[4][2];
#pragma unroll
    for (int ks = 0; ks < 4; ++ks) {
      A[ks][0] = *reinterpret_cast<const float4*>(ar + ks * 32);
      A[ks][1] = *reinterpret_cast<const float4*>(ar + ks * 32 + 4);
    }
    __builtin_amdgcn_sched_barrier(0);
    f32x4 aHH[4], aER[4];
#pragma unroll
    for (int tt = 0; tt < 4; ++tt) {
      aHH[tt] = (f32x4){0.f, 0.f, 0.f, 0.f};
      aER[tt] = (f32x4){0.f, 0.f, 0.f, 0.f};
    }
#pragma unroll
    for (int ks = 0; ks < 4; ++ks) {
      float4 va = A[ks][0], vb = A[ks][1];
      union { unsigned u[4]; bf16x8 v; } hi, lo;
      hi.u[0] = pack_hi(va.x, va.y);
      hi.u[1] = pack_hi(va.z, va.w);
      hi.u[2] = pack_hi(vb.x, vb.y);
      hi.u[3] = pack_hi(vb.z, vb.w);
      lo.u[0] = pack_hi(va.x - trunc_bf(va.x), va.y - trunc_bf(va.y));
      lo.u[1] = pack_hi(va.z - trunc_bf(va.z), va.w - trunc_bf(va.w));
      lo.u[2] = pack_hi(vb.x - trunc_bf(vb.x), vb.y - trunc_bf(vb.y));
      lo.u[3] = pack_hi(vb.z - trunc_bf(vb.z), vb.w - trunc_bf(vb.w));
#pragma unroll
      for (int tt = 0; tt < 4; ++tt) {
        bf16x8 wh = wp[((ks * 4 + tt) * 2 + 0) * 64 + lane];
        bf16x8 wl = wp[((ks * 4 + tt) * 2 + 1) * 64 + lane];
        aHH[tt] = __builtin_amdgcn_mfma_f32_16x16x32_bf16(hi.v, wh, aHH[tt], 0, 0, 0);
        aER[tt] = __builtin_amdgcn_mfma_f32_16x16x32_bf16(hi.v, wl, aER[tt], 0, 0, 0);
        aER[tt] = __builtin_amdgcn_mfma_f32_16x16x32_bf16(lo.v, wh, aER[tt], 0, 0, 0);
      }
    }
#pragma unroll
    for (int tt = 0; tt < 4; ++tt)
#pragma unroll
      for (int r = 0; r < 4; ++r)
        pout[(size_t)(r0 + 4 * lk + r) * 64 + 16 * tt + lr] =
            __float2half(aHH[tt][r] + aER[tt][r]);
  }
}

// ---------------- mid v2: combine(img) + K-extended MFMA attention (no VALU base) ----------------
// 1 batch/wave, grid BB/4. Score P[n][w] = [qe_n|ue|img] @ W_att_ingre via MFMA:
// qe part (ks 0,1): 16 MFMAs; ue/img part (ks 2..5): rows-identical A -> 16 MFMAs give base[w].
__global__ __launch_bounds__(256, 3)
void mid_kernel(const int* __restrict__ user_input,
                const int* __restrict__ ingre_input,
                const int* __restrict__ ingre_num,
                const float* __restrict__ user_emb,
                const float* __restrict__ ingre_emb,
                const __half* __restrict__ pp,
                const float* __restrict__ Wb, const float* __restrict__ bimg,
                const short* __restrict__ W1f,   // [6][4][64][8] bf16
                const float* __restrict__ Wib, const float* __restrict__ bai,
                const float* __restrict__ v,
                float* __restrict__ ws_img,
                float* __restrict__ ws_ia) {
  __shared__ short wflds[12288];        // 24 KB
  __shared__ short qe_s[4][32][88];     // 22 KB (176B rows: 16B-aligned, 2-way banks)
  __shared__ short ui_s[4][128];        // [ue(64)|img(64)] bf16, 1 KB
  __shared__ float sc_s[4][32];         // 0.5 KB
  const int t = threadIdx.x;
  const int wave = t >> 6, lane = t & 63;
  const int lr = lane & 15, lk = lane >> 4;
  const int b = blockIdx.x * 4 + wave;

  for (int i = t; i < 1536; i += 256)
    reinterpret_cast<bf16x8*>(wflds)[i] = reinterpret_cast<const bf16x8*>(W1f)[i];

  // per-lane gathers (latency overlaps staging)
  float qv[NN];
#pragma unroll
  for (int n = 0; n < NN; ++n) {
    const int gi = ingre_input[b * NN + n];
    qv[n] = ingre_emb[(size_t)gi * 64 + lane];
  }
  float s = Wb[lane] + bimg[lane];
#pragma unroll
  for (int kq = 0; kq < 16; ++kq)
    s += __half2float(pp[(size_t)kq * BB * 64 + (size_t)b * 64 + lane]);
  const int u = user_input[b];
  const float ue = user_emb[(size_t)u * 64 + lane];
  ws_img[(size_t)b * 64 + lane] = s;
  float vv[4], biasw[4];
#pragma unroll
  for (int wt = 0; wt < 4; ++wt) {
    vv[wt] = v[16 * wt + lr];
    biasw[wt] = Wib[16 * wt + lr] + bai[16 * wt + lr];
  }

  // LDS writes (wave-private) then block barrier (also covers wflds staging)
#pragma unroll
  for (int n = 0; n < NN; ++n) qe_s[wave][n][lane] = f2bf(qv[n]);
#pragma unroll
  for (int n = NN; n < 32; ++n) qe_s[wave][n][lane] = 0;
  ui_s[wave][lane] = f2bf(ue);
  ui_s[wave][64 + lane] = f2bf(s);
  __syncthreads();

  // A-fragments
  bf16x8 aq0[2], aq1[2], au[4];
#pragma unroll
  for (int ks = 0; ks < 2; ++ks) {
    aq0[ks] = *reinterpret_cast<const bf16x8*>(&qe_s[wave][lr][ks * 32 + lk * 8]);
    aq1[ks] = *reinterpret_cast<const bf16x8*>(&qe_s[wave][16 + lr][ks * 32 + lk * 8]);
  }
#pragma unroll
  for (int ks = 0; ks < 4; ++ks)
    au[ks] = *reinterpret_cast<const bf16x8*>(&ui_s[wave][ks * 32 + lk * 8]);

  const bf16x8* wp = reinterpret_cast<const bf16x8*>(wflds);
  f32x4 accq[2][4], accb[4];
#pragma unroll
  for (int wt = 0; wt < 4; ++wt) {
    accq[0][wt] = (f32x4){0.f, 0.f, 0.f, 0.f};
    accq[1][wt] = (f32x4){0.f, 0.f, 0.f, 0.f};
    accb[wt] = (f32x4){0.f, 0.f, 0.f, 0.f};
  }
#pragma unroll
  for (int ks = 0; ks < 2; ++ks)
#pragma unroll
    for (int wt = 0; wt < 4; ++wt) {
      bf16x8 w = wp[(ks * 4 + wt) * 64 + lane];
      accq[0][wt] = __builtin_amdgcn_mfma_f32_16x16x32_bf16(aq0[ks], w, accq[0][wt], 0, 0, 0);
      accq[1][wt] = __builtin_amdgcn_mfma_f32_16x16x32_bf16(aq1[ks], w, accq[1][wt], 0, 0, 0);
    }
#pragma unroll
  for (int ks = 2; ks < 6; ++ks)
#pragma unroll
    for (int wt = 0; wt < 4; ++wt) {
      bf16x8 w = wp[(ks * 4 + wt) * 64 + lane];
      accb[wt] = __builtin_amdgcn_mfma_f32_16x16x32_bf16(au[ks - 2], w, accb[wt], 0, 0, 0);
    }
  float basew[4];
#pragma unroll
  for (int wt = 0; wt < 4; ++wt) basew[wt] = accb[wt][0] + biasw[wt];

  float sp[2][4];
#pragma unroll
  for (int nt = 0; nt < 2; ++nt)
#pragma unroll
    for (int r = 0; r < 4; ++r) {
      float sv = 0.f;
#pragma unroll
      for (int wt = 0; wt < 4; ++wt) {
        float x = accq[nt][wt][r] + basew[wt];
        sv = fmaf(fast_tanh(x), vv[wt], sv);
      }
      sp[nt][r] = sv;
    }
#pragma unroll
  for (int off = 1; off < 16; off <<= 1)
#pragma unroll
    for (int nt = 0; nt < 2; ++nt)
#pragma unroll
      for (int r = 0; r < 4; ++r) sp[nt][r] += __shfl_xor(sp[nt][r], off, 64);
  if (lr == 0) {
#pragma unroll
    for (int r = 0; r < 4; ++r) {
      sc_s[wave][4 * lk + r] = sp[0][r];
      sc_s[wave][16 + 4 * lk + r] = sp[1][r];
    }
  }
  asm volatile("s_waitcnt lgkmcnt(0)" ::: "memory");
  float scn[NN];
#pragma unroll
  for (int q = 0; q < 5; ++q) {
    float4 s4 = *reinterpret_cast<const float4*>(&sc_s[wave][4 * q]);
    scn[4 * q + 0] = s4.x; scn[4 * q + 1] = s4.y;
    scn[4 * q + 2] = s4.z; scn[4 * q + 3] = s4.w;
  }
  asm volatile("s_waitcnt lgkmcnt(0)" ::: "memory");
  const int num = ingre_num[b];
  float m = -3e38f;
#pragma unroll
  for (int n = 0; n < NN; ++n) {
    scn[n] = (n < num) ? scn[n] : -1e12f;
    m = fmaxf(m, scn[n]);
  }
  float ssum = 0.f;
#pragma unroll
  for (int n = 0; n < NN; ++n) {
    scn[n] = __expf(scn[n] - m);
    ssum += scn[n];
  }
  const float inv = __fdividef(1.f, ssum);
  float ia = 0.f;
#pragma unroll
  for (int n = 0; n < NN; ++n) ia = fmaf(scn[n], qv[n], ia);
  ws_ia[(size_t)b * 64 + lane] = ia * inv;
}

// ---------------- Kernel B2: component scores -> flat [3B] ----------------
__global__ __launch_bounds__(256, 4)
void com_score_kernel(const int* __restrict__ user_input,
                      const int* __restrict__ item_input,
                      const float* __restrict__ user_emb,
                      const float* __restrict__ item_emb,
                      const float* __restrict__ Wc,    // [128][64]
                      const float* __restrict__ Wcb,   // [64]
                      const float* __restrict__ bat,   // [64]
                      const float* __restrict__ vc,    // [64]
                      const float* __restrict__ ws_img,
                      const float* __restrict__ ws_ia,
                      float* __restrict__ ws_flat) {
  __shared__ float Wclds[128 * 64];
  __shared__ float x_s[4][4][64];
  const int t = threadIdx.x;
  for (int i = t; i < 128 * 64 / 4; i += 256)
    reinterpret_cast<float4*>(Wclds)[i] = reinterpret_cast<const float4*>(Wc)[i];
  __syncthreads();
  const int wave = t >> 6, lane = t & 63;
  const float bb = Wcb[lane] + bat[lane];
  const float vcl = vc[lane];
  const int b0 = blockIdx.x * 16 + wave * 4;
#pragma unroll 1
  for (int bi = 0; bi < 4; ++bi) {
    const int b = b0 + bi;
    const int u = user_input[b];
    const int it = item_input[b];
    x_s[wave][0][lane] = user_emb[(size_t)u * 64 + lane];
    x_s[wave][1][lane] = item_emb[(size_t)it * 64 + lane];
    x_s[wave][2][lane] = ws_ia[(size_t)b * 64 + lane];
    x_s[wave][3][lane] = ws_img[(size_t)b * 64 + lane];
    asm volatile("s_waitcnt lgkmcnt(0)" ::: "memory");
    const float4* u4 = reinterpret_cast<const float4*>(&x_s[wave][0][0]);
    float up = 0.f;
#pragma unroll
    for (int d0 = 0; d0 < 16; ++d0) {
      float4 q = u4[d0];
      int d = d0 * 4;
      up = fmaf(q.x, Wclds[(d + 0) * 64 + lane],
           fmaf(q.y, Wclds[(d + 1) * 64 + lane],
           fmaf(q.z, Wclds[(d + 2) * 64 + lane],
           fmaf(q.w, Wclds[(d + 3) * 64 + lane], up))));
    }
    float sc[3];
#pragma unroll
    for (int c = 0; c < 3; ++c) {
      const float4* y4 = reinterpret_cast<const float4*>(&x_s[wave][1 + c][0]);
      float s = bb + up;
#pragma unroll
      for (int d0 = 0; d0 < 16; ++d0) {
        float4 q = y4[d0];
        int d = 64 + d0 * 4;
        s = fmaf(q.x, Wclds[(d + 0) * 64 + lane],
            fmaf(q.y, Wclds[(d + 1) * 64 + lane],
            fmaf(q.z, Wclds[(d + 2) * 64 + lane],
            fmaf(q.w, Wclds[(d + 3) * 64 + lane], s))));
      }
      sc[c] = waveReduceSum(fast_tanh(s) * vcl);
    }
    if (lane == 0) {
      ws_flat[b] = sc[0];
      ws_flat[BB + b] = sc[1];
      ws_flat[2 * BB + b] = sc[2];
    }
    asm volatile("s_waitcnt lgkmcnt(0)" ::: "memory");
  }
}

// ---------------- Kernel C: head. scores[i][j] = flat[3i+j] ----------------
__global__ __launch_bounds__(256, 3)
void head_kernel(const int* __restrict__ user_input,
                 const int* __restrict__ item_input,
                 const float* __restrict__ user_emb,
                 const float* __restrict__ item_emb,
                 const float* __restrict__ Wcat,   // [192][64]
                 const float* __restrict__ Wcatb,  // [64]
                 const float* __restrict__ bcat,   // [64]
                 const float* __restrict__ hw,     // [64]
                 const float* __restrict__ hb,     // [1]
                 const float* __restrict__ ws_img,
                 const float* __restrict__ ws_ia,
                 const float* __restrict__ ws_flat,
                 float* __restrict__ out) {
  __shared__ float Wlds[192 * 64];
  __shared__ float ue_s[4][64];
  __shared__ float itt_s[4][64];
  const int t = threadIdx.x;
  for (int i = t; i < 192 * 64 / 4; i += 256)
    reinterpret_cast<float4*>(Wlds)[i] = reinterpret_cast<const float4*>(Wcat)[i];
  __syncthreads();
  const int wave = t >> 6, lane = t & 63;
  const float bb = Wcatb[lane] + bcat[lane];
  const float hwl = hw[lane];
  const float hbv = hb[0];
  const int b0 = blockIdx.x * 16 + wave * 4;
#pragma unroll 1
  for (int bi = 0; bi < 4; ++bi) {
    const int b = b0 + bi;
    const float s0 = ws_flat[3 * b + 0];
    const float s1 = ws_flat[3 * b + 1];
    const float s2 = ws_flat[3 * b + 2];
    const float m = fmaxf(s0, fmaxf(s1, s2));
    const float e0 = __expf(s0 - m), e1 = __expf(s1 - m), e2 = __expf(s2 - m);
    const float inv = 1.0f / (e0 + e1 + e2);
    const int u = user_input[b];
    const int it = item_input[b];
    const float uev = user_emb[(size_t)u * 64 + lane];
    const float itt = (e0 * item_emb[(size_t)it * 64 + lane] +
                       e1 * ws_ia[(size_t)b * 64 + lane] +
                       e2 * ws_img[(size_t)b * 64 + lane]) * inv;
    ue_s[wave][lane] = uev;
    itt_s[wave][lane] = itt;
    asm volatile("s_waitcnt lgkmcnt(0)" ::: "memory");
    const float4* u4 = reinterpret_cast<const float4*>(&ue_s[wave][0]);
    const float4* i4 = reinterpret_cast<const float4*>(&itt_s[wave][0]);
    float h = bb;
#pragma unroll
    for (int d0 = 0; d0 < 16; ++d0) {
      float4 uu = u4[d0];
      float4 ii = i4[d0];
      int d = d0 * 4;
      h = fmaf(uu.x, Wlds[(d + 0) * 64 + lane], h);
      h = fmaf(ii.x, Wlds[(64 + d + 0) * 64 + lane], h);
      h = fmaf(uu.x * ii.x, Wlds[(128 + d + 0) * 64 + lane], h);
      h = fmaf(uu.y, Wlds[(d + 1) * 64 + lane], h);
      h = fmaf(ii.y, Wlds[(64 + d + 1) * 64 + lane], h);
      h = fmaf(uu.y * ii.y, Wlds[(128 + d + 1) * 64 + lane], h);
      h = fmaf(uu.z, Wlds[(d + 2) * 64 + lane], h);
      h = fmaf(ii.z, Wlds[(64 + d + 2) * 64 + lane], h);
      h = fmaf(uu.z * ii.z, Wlds[(128 + d + 2) * 64 + lane], h);
      h = fmaf(uu.w, Wlds[(d + 3) * 64 + lane], h);
      h = fmaf(ii.w, Wlds[(64 + d + 3) * 64 + lane], h);
      h = fmaf(uu.w * ii.w, Wlds[(128 + d + 3) * 64 + lane], h);
    }
    h = fmaxf(h, 0.f) * hwl;
    float o = waveReduceSum(h);
    if (lane == 0) out[b] = o + hbv;
    asm volatile("s_waitcnt lgkmcnt(0)" ::: "memory");
  }
}

extern "C" void kernel_launch(void* const* d_in, const int* in_sizes, int n_in,
                              void* d_out, int out_size, void* d_ws, size_t ws_size,
                              hipStream_t stream) {
  (void)in_sizes; (void)n_in; (void)out_size; (void)ws_size;
  const int* user_input = (const int*)d_in[0];
  const int* item_input = (const int*)d_in[1];
  const int* ingre_input = (const int*)d_in[2];
  const float* image_input = (const float*)d_in[3];
  const int* ingre_num = (const int*)d_in[4];
  const float* user_emb = (const float*)d_in[5];
  const float* item_emb = (const float*)d_in[6];
  const float* ingre_emb = (const float*)d_in[7];
  const float* W_image_w = (const float*)d_in[8];
  const float* W_image_b = (const float*)d_in[9];
  const float* b_image = (const float*)d_in[10];
  const float* W_concat_w = (const float*)d_in[11];
  const float* W_concat_b = (const float*)d_in[12];
  const float* b_concat = (const float*)d_in[13];
  const float* h_w = (const float*)d_in[14];
  const float* h_b = (const float*)d_in[15];
  const float* W_att_ingre_w = (const float*)d_in[16];
  const float* W_att_ingre_b = (const float*)d_in[17];
  const float* b_att_ingre = (const float*)d_in[18];
  const float* v = (const float*)d_in[19];
  const float* W_att_com_w = (const float*)d_in[20];
  const float* W_att_com_b = (const float*)d_in[21];
  const float* b_att_com = (const float*)d_in[22];
  const float* v_c = (const float*)d_in[23];

  float* ws = (float*)d_ws;
  float* ws_img = ws;                              // [B*64] f32
  float* ws_ia = ws + (size_t)BB * 64;             // [B*64] f32
  float* ws_flat = ws + (size_t)2 * BB * 64;       // [3B] f32
  short* Wf = (short*)(ws + (size_t)2 * BB * 64 + 3 * BB);      // [16*16384] bf16
  short* W1f = Wf + (size_t)16 * 16384;                         // [12288] bf16
  __half* pp = (__half*)(W1f + 12288);             // [16][B*64] fp16 partials
  float* out = (float*)d_out;

  prep_kernel<<<(32768 + 1536 + 255) / 256, 256, 0, stream>>>(
      W_image_w, W_att_ingre_w, Wf, W1f);
  img_gemm_mfma<<<1024, 256, 0, stream>>>(image_input, Wf, pp);
  mid_kernel<<<BB / 4, 256, 0, stream>>>(user_input, ingre_input, ingre_num,
                                         user_emb, ingre_emb, pp,
                                         W_image_b, b_image, W1f,
                                         W_att_ingre_b, b_att_ingre, v,
                                         ws_img, ws_ia);
  com_score_kernel<<<BB / 16, 256, 0, stream>>>(user_input, item_input, user_emb, item_emb,
                                                W_att_com_w, W_att_com_b, b_att_com, v_c,
                                                ws_img, ws_ia, ws_flat);
  head_kernel<<<BB / 16, 256, 0, stream>>>(user_input, item_input, user_emb, item_emb,
                                           W_concat_w, W_concat_b, b_concat, h_w, h_b,
                                           ws_img, ws_ia, ws_flat, out);
}